// Round 8
// baseline (630.612 us; speedup 1.0000x reference)
//
#include <hip/hip_runtime.h>

// ---------------------------------------------------------------------------
// AsymmetricAttention fused pipeline for MI355X (gfx950), bf16 MFMA throughout.
// R8: unbundle R7 — KEEP V-swizzle fix ((row>>1)&3, 2-way free) + exp2-folded
//     softmax + hoisted edge mask; REVERT all inline-asm cvt_pk (m240: hand-
//     written cvt_pk defeats compiler scheduling, was the R7 VALU regression).
// ---------------------------------------------------------------------------

typedef short short8 __attribute__((ext_vector_type(8)));
typedef float f32x4 __attribute__((ext_vector_type(4)));
typedef unsigned short ushort4v __attribute__((ext_vector_type(4)));

#define MFMA_BF16(a,b,c) __builtin_amdgcn_mfma_f32_16x16x32_bf16((a),(b),(c),0,0,0)

#define NH 24
#define SPAD 3328   // padded token count (104*32)
#define SVAL 3272   // valid tokens (3072 x + 200 y)

__device__ __forceinline__ unsigned short bf16_rne(float f){
  unsigned int u = __builtin_bit_cast(unsigned int, f);
  u += 0x7FFFu + ((u >> 16) & 1u);
  return (unsigned short)(u >> 16);
}
__device__ __forceinline__ float bf2f(unsigned short h){
  unsigned int u = ((unsigned int)h) << 16;
  return __builtin_bit_cast(float, u);
}
__device__ __forceinline__ void gload16(const void* g, void* l){
  __builtin_amdgcn_global_load_lds(
      (const __attribute__((address_space(1))) unsigned int*)g,
      (__attribute__((address_space(3))) unsigned int*)l, 16, 0, 0);
}

// ---------------------------------------------------------------------------
// W (K x N) fp32 row-major -> Wt (N x K) bf16 row-major. 64x64 tiles.
// ---------------------------------------------------------------------------
__global__ __launch_bounds__(256) void transpose_w(
    const float* __restrict__ W, unsigned short* __restrict__ Wt, int K, int N)
{
  __shared__ unsigned short t[64][66];
  int n0 = blockIdx.x*64, k0 = blockIdx.y*64;
  int tid = threadIdx.x;
  int kr = tid >> 4, nc = (tid & 15) * 4;
  #pragma unroll
  for (int pass=0; pass<4; pass++){
    int k = kr + pass*16;
    float4 v = *(const float4*)(W + (size_t)(k0+k)*N + n0 + nc);
    ushort4v o;
    o.x = bf16_rne(v.x); o.y = bf16_rne(v.y);
    o.z = bf16_rne(v.z); o.w = bf16_rne(v.w);
    *(ushort4v*)&t[k][nc] = o;
  }
  __syncthreads();
  int nr = tid >> 3, kc = (tid & 7) * 8;
  #pragma unroll
  for (int pass=0; pass<2; pass++){
    int n = nr + pass*32;
    unsigned short buf[8];
    #pragma unroll
    for (int j=0;j<8;j++) buf[j] = t[kc+j][n];
    *(short8*)(Wt + (size_t)(n0+n)*K + k0 + kc) = *(short8*)&buf[0];
  }
}

// ---------------------------------------------------------------------------
// mod-rmsnorm: out = bf16( x * rsqrt(mean(x^2)+1e-6) * (1+scale[col]) )
// ---------------------------------------------------------------------------
template<int D>
__global__ __launch_bounds__(256) void modnorm(
    const float* __restrict__ X, const float* __restrict__ scale,
    unsigned short* __restrict__ out)
{
  int row = blockIdx.x;
  const float4* xv = (const float4*)(X + (size_t)row*D);
  float ss = 0.f;
  for (int i = threadIdx.x; i < D/4; i += 256){
    float4 v = xv[i];
    ss += v.x*v.x + v.y*v.y + v.z*v.z + v.w*v.w;
  }
  #pragma unroll
  for (int d=1; d<64; d<<=1) ss += __shfl_xor(ss, d);
  __shared__ float wsum[4];
  if ((threadIdx.x & 63) == 0) wsum[threadIdx.x >> 6] = ss;
  __syncthreads();
  float tot = wsum[0] + wsum[1] + wsum[2] + wsum[3];
  float rn = rsqrtf(tot*(1.0f/(float)D) + 1e-6f);
  const float4* sv = (const float4*)scale;
  for (int i = threadIdx.x; i < D/4; i += 256){
    float4 v = xv[i]; float4 s4 = sv[i];
    ushort4v o;
    o.x = bf16_rne(v.x*rn*(1.f+s4.x));
    o.y = bf16_rne(v.y*rn*(1.f+s4.y));
    o.z = bf16_rne(v.z*rn*(1.f+s4.z));
    o.w = bf16_rne(v.w*rn*(1.f+s4.w));
    *(ushort4v*)(out + (size_t)row*D + i*4) = o;
  }
}

// ---------------------------------------------------------------------------
// 128^2-tile GEMM (m97 structure) with optional split-K via blockIdx.z.
// ---------------------------------------------------------------------------
template<typename CT, bool BIAS>
__global__ __launch_bounds__(256, 3) void gemm_bt(
    const unsigned short* __restrict__ A, const unsigned short* __restrict__ BT,
    const float* __restrict__ bias, CT* __restrict__ C,
    int M, int N, int K, int ldc, int klen)
{
  __shared__ unsigned short lA[128*32];
  __shared__ unsigned short lB[128*32];
  int tid = threadIdx.x, wave = tid>>6, lane = tid&63;
  int l16 = lane&15, g = lane>>4;
  int wr = wave>>1, wc = wave&1;

  int nwg = gridDim.x*gridDim.y;
  int orig = blockIdx.y*gridDim.x + blockIdx.x;
  int neo = orig;
  if ((nwg & 7) == 0){
    int q8 = nwg >> 3;
    neo = (orig & 7)*q8 + (orig >> 3);
  }
  int bx = neo / gridDim.y;
  int by = neo % gridDim.y;
  int bm = by*128, bn = bx*128;
  int kof = blockIdx.z * klen;
  CT* Cp = C + (size_t)blockIdx.z * M * (size_t)ldc;

  f32x4 acc[4][4] = {};

  for (int k0 = kof; k0 < kof + klen; k0 += 32){
    #pragma unroll
    for (int i=0;i<2;i++){
      int off = i*4096 + wave*1024 + lane*16;
      int row = off>>6;
      int sp  = (off>>4)&3;
      int sk  = (sp ^ (row&3))*8;
      gload16(A + (size_t)(bm+row)*K + k0 + sk, (char*)lA + i*4096 + wave*1024);
    }
    #pragma unroll
    for (int i=0;i<2;i++){
      int off = i*4096 + wave*1024 + lane*16;
      int row = off>>6;
      int sp  = (off>>4)&3;
      int sk  = (sp ^ (row&3))*8;
      gload16(BT + (size_t)(bn+row)*K + k0 + sk, (char*)lB + i*4096 + wave*1024);
    }
    __syncthreads();

    short8 a[4], b[4];
    #pragma unroll
    for (int m=0;m<4;m++){
      int row = wr*64 + m*16 + l16;
      int slot = g ^ (row&3);
      a[m] = *(const short8*)((const char*)lA + row*64 + slot*16);
    }
    #pragma unroll
    for (int n=0;n<4;n++){
      int row = wc*64 + n*16 + l16;
      int slot = g ^ (row&3);
      b[n] = *(const short8*)((const char*)lB + row*64 + slot*16);
    }
    __builtin_amdgcn_s_setprio(1);
    #pragma unroll
    for (int m=0;m<4;m++)
      #pragma unroll
      for (int n=0;n<4;n++)
        acc[m][n] = MFMA_BF16(a[m], b[n], acc[m][n]);
    __builtin_amdgcn_s_setprio(0);
    __syncthreads();
  }

  #pragma unroll
  for (int n=0;n<4;n++){
    int col = bn + wc*64 + n*16 + l16;
    float bv = BIAS ? bias[col] : 0.f;
    #pragma unroll
    for (int m=0;m<4;m++){
      int row0 = bm + wr*64 + m*16 + g*4;
      #pragma unroll
      for (int r=0;r<4;r++){
        float v = acc[m][n][r] + bv;
        if constexpr (sizeof(CT) == 4) Cp[(size_t)(row0+r)*ldc + col] = v;
        else                           Cp[(size_t)(row0+r)*ldc + col] = bf16_rne(v);
      }
    }
  }
}

// ---------------------------------------------------------------------------
// 256^2-tile 8-phase GEMM (m201/HK schedule in plain HIP). BK=64, 8 waves.
// ---------------------------------------------------------------------------
__global__ __launch_bounds__(512, 2) void gemm_8ph(
    const unsigned short* __restrict__ A, const unsigned short* __restrict__ BT,
    const float* __restrict__ bias, unsigned short* __restrict__ C,
    int M, int N, int K, int ldc)
{
  __shared__ unsigned short lds[8][8192];

  int tid = threadIdx.x, wave = tid>>6, lane = tid&63;
  int l16 = lane&15, g = lane>>4;
  int wr = wave>>2, wc = wave&3;

  int nwg = gridDim.x*gridDim.y;
  int orig = blockIdx.y*gridDim.x + blockIdx.x;
  int neo = orig;
  if ((nwg & 7) == 0) neo = (orig & 7)*(nwg>>3) + (orig>>3);
  int bx = neo / gridDim.y, by = neo % gridDim.y;
  int bm = by*256, bn = bx*256;

  const int NT = K >> 6;

  auto STAGE = [&](int t, int op, int half, int b){
    int tc = t < NT ? t : NT-1;
    const unsigned short* src = op ? BT : A;
    int base_row = (op ? bn : bm) + half*128;
    int k0 = tc << 6;
    #pragma unroll
    for (int j=0;j<2;j++){
      int o = (j*8 + wave)*1024 + lane*16;
      int row = o>>7, slot = (o>>4)&7;
      int sk = (slot ^ (row&7))*8;
      gload16(src + (size_t)(base_row+row)*K + k0 + sk,
              (char*)&lds[(b<<2)|(op<<1)|half][0] + (j*8+wave)*1024);
    }
  };

  short8 afr[4], bfr[8];
  auto LDA = [&](int b, int p){
    const char* basep = (const char*)&lds[(b<<2)|wr][0];
    #pragma unroll
    for (int mm=0;mm<2;mm++){
      int row = (p*2+mm)*16 + l16;
      #pragma unroll
      for (int kk=0;kk<2;kk++)
        afr[mm*2+kk] = *(const short8*)(basep + row*128 + (((kk*4+g) ^ (row&7))<<4));
    }
  };
  auto LDB = [&](int b){
    const char* basep = (const char*)&lds[(b<<2)|2|(wc>>1)][0];
    int rbase = (wc&1)*64;
    #pragma unroll
    for (int n=0;n<4;n++){
      int row = rbase + n*16 + l16;
      #pragma unroll
      for (int kk=0;kk<2;kk++)
        bfr[n*2+kk] = *(const short8*)(basep + row*128 + (((kk*4+g) ^ (row&7))<<4));
    }
  };

  f32x4 acc[8][4] = {};

  STAGE(0,1,0,0); STAGE(0,1,1,0); STAGE(0,0,0,0); STAGE(0,0,1,0);
  STAGE(1,1,0,1); STAGE(1,1,1,1); STAGE(1,0,0,1);
  asm volatile("s_waitcnt vmcnt(6)" ::: "memory");
  __builtin_amdgcn_s_barrier();

  int NIT = NT >> 1;
  for (int i=0;i<NIT;i++){
    int T = 2*i;
    #pragma unroll
    for (int p=0;p<4;p++){
      if (p==0) LDB(0);
      LDA(0, p);
      if (p==0)      STAGE(T+1,0,1,1);
      else if (p==1) STAGE(T+2,1,0,0);
      else if (p==2) STAGE(T+2,1,1,0);
      else           STAGE(T+2,0,0,0);
      if (p==0) asm volatile("s_waitcnt lgkmcnt(8)" ::: "memory");
      __builtin_amdgcn_s_barrier();
      asm volatile("s_waitcnt lgkmcnt(0)" ::: "memory");
      __builtin_amdgcn_sched_barrier(0);
      __builtin_amdgcn_s_setprio(1);
      #pragma unroll
      for (int mm=0;mm<2;mm++)
        #pragma unroll
        for (int n=0;n<4;n++)
          #pragma unroll
          for (int kk=0;kk<2;kk++)
            acc[p*2+mm][n] = MFMA_BF16(afr[mm*2+kk], bfr[n*2+kk], acc[p*2+mm][n]);
      __builtin_amdgcn_s_setprio(0);
      if (p==3) asm volatile("s_waitcnt vmcnt(6)" ::: "memory");
      __builtin_amdgcn_s_barrier();
    }
    #pragma unroll
    for (int p=0;p<4;p++){
      if (p==0) LDB(1);
      LDA(1, p);
      if (p==0)      STAGE(T+2,0,1,0);
      else if (p==1) STAGE(T+3,1,0,1);
      else if (p==2) STAGE(T+3,1,1,1);
      else           STAGE(T+3,0,0,1);
      if (p==0) asm volatile("s_waitcnt lgkmcnt(8)" ::: "memory");
      __builtin_amdgcn_s_barrier();
      asm volatile("s_waitcnt lgkmcnt(0)" ::: "memory");
      __builtin_amdgcn_sched_barrier(0);
      __builtin_amdgcn_s_setprio(1);
      #pragma unroll
      for (int mm=0;mm<2;mm++)
        #pragma unroll
        for (int n=0;n<4;n++)
          #pragma unroll
          for (int kk=0;kk<2;kk++)
            acc[p*2+mm][n] = MFMA_BF16(afr[mm*2+kk], bfr[n*2+kk], acc[p*2+mm][n]);
      __builtin_amdgcn_s_setprio(0);
      if (p==3) asm volatile("s_waitcnt vmcnt(6)" ::: "memory");
      __builtin_amdgcn_s_barrier();
    }
  }

  #pragma unroll
  for (int n=0;n<4;n++){
    int col = bn + wc*64 + n*16 + l16;
    float bv = bias[col];
    #pragma unroll
    for (int m=0;m<8;m++){
      int row0 = bm + wr*128 + m*16 + g*4;
      #pragma unroll
      for (int r=0;r<4;r++)
        C[(size_t)(row0+r)*ldc + col] = bf16_rne(acc[m][n][r] + bv);
    }
  }
}

// ---------------------------------------------------------------------------
// split-K reduces
// ---------------------------------------------------------------------------
__global__ __launch_bounds__(256) void reduce2_bias_bf16(
    const float* __restrict__ part, const float* __restrict__ bias,
    unsigned short* __restrict__ out, int N, size_t tot)
{
  size_t idx = ((size_t)blockIdx.x*256 + threadIdx.x)*4;
  if (idx >= tot) return;
  float4 a = *(const float4*)(part + idx);
  float4 b = *(const float4*)(part + tot + idx);
  int col = (int)(idx % N);
  float4 bv = *(const float4*)(bias + col);
  ushort4v o;
  o.x = bf16_rne(a.x+b.x+bv.x);
  o.y = bf16_rne(a.y+b.y+bv.y);
  o.z = bf16_rne(a.z+b.z+bv.z);
  o.w = bf16_rne(a.w+b.w+bv.w);
  *(ushort4v*)(out + idx) = o;
}

__global__ __launch_bounds__(256) void reduce8_bias_f32(
    const float* __restrict__ part, const float* __restrict__ bias,
    float* __restrict__ out, int N, size_t tot)
{
  size_t idx = ((size_t)blockIdx.x*256 + threadIdx.x)*4;
  if (idx >= tot) return;
  int col = (int)(idx % N);
  float4 s = *(const float4*)(bias + col);
  #pragma unroll
  for (int c=0;c<8;c++){
    float4 a = *(const float4*)(part + (size_t)c*tot + idx);
    s.x += a.x; s.y += a.y; s.z += a.z; s.w += a.w;
  }
  *(float4*)(out + idx) = s;
}

// ---------------------------------------------------------------------------
// qk fixup: 4 waves/block, one (token,head) per wave.
// ---------------------------------------------------------------------------
__global__ __launch_bounds__(256) void fixup_qk(
    const unsigned short* __restrict__ QKV,
    const float* __restrict__ cosT, const float* __restrict__ sinT,
    const float* __restrict__ wqx, const float* __restrict__ wkx,
    const float* __restrict__ wqy, const float* __restrict__ wky,
    unsigned short* __restrict__ Qo, unsigned short* __restrict__ Ko)
{
  int wave = threadIdx.x >> 6, lane = threadIdx.x & 63;
  int bid = blockIdx.x*4 + wave;
  int t = bid / NH, h = bid % NH;
  bool isx = (t < 3072);

  const unsigned short* base = QKV + (size_t)t*9216 + h*128;
  unsigned int qraw = *(const unsigned int*)(base + 2*lane);
  unsigned int kraw = *(const unsigned int*)(base + 3072 + 2*lane);
  float q0 = bf2f((unsigned short)(qraw & 0xffff)), q1 = bf2f((unsigned short)(qraw >> 16));
  float k0 = bf2f((unsigned short)(kraw & 0xffff)), k1 = bf2f((unsigned short)(kraw >> 16));

  float sq = q0*q0 + q1*q1, sk = k0*k0 + k1*k1;
  #pragma unroll
  for (int d=1; d<64; d<<=1){ sq += __shfl_xor(sq, d); sk += __shfl_xor(sk, d); }
  float rq = rsqrtf(sq*(1.0f/128.0f) + 1e-5f);
  float rk = rsqrtf(sk*(1.0f/128.0f) + 1e-5f);

  const float* wq = isx ? wqx : wqy;
  const float* wk = isx ? wkx : wky;
  float a0 = q0*rq*wq[2*lane], a1 = q1*rq*wq[2*lane+1];
  float b0 = k0*rk*wk[2*lane], b1 = k1*rk*wk[2*lane+1];

  if (isx){
    size_t ci = ((size_t)t*NH + h)*64 + lane;
    float c = cosT[ci], s = sinT[ci];
    float t0 = a0*c - a1*s, t1 = a0*s + a1*c; a0 = t0; a1 = t1;
    t0 = b0*c - b1*s; t1 = b0*s + b1*c; b0 = t0; b1 = t1;
  }
  size_t oi = ((size_t)h*SPAD + t)*128 + 2*lane;
  *(unsigned int*)(Qo + oi) = (unsigned int)bf16_rne(a0) | ((unsigned int)bf16_rne(a1) << 16);
  *(unsigned int*)(Ko + oi) = (unsigned int)bf16_rne(b0) | ((unsigned int)bf16_rne(b1) << 16);
}

// ---------------------------------------------------------------------------
// V transpose: qkv v-section (token,128) -> VT (H, 128, SPAD) bf16
// ---------------------------------------------------------------------------
__global__ __launch_bounds__(256) void v_transpose(
    const unsigned short* __restrict__ QKV, unsigned short* __restrict__ VT)
{
  __shared__ unsigned short t[64][136];
  int h = blockIdx.x;
  int t0 = blockIdx.y*64;
  int tid = threadIdx.x;
  #pragma unroll
  for (int it=0; it<4; it++){
    int chunk = it*256 + tid;
    int r = chunk >> 4, c = chunk & 15;
    short8 v = *(const short8*)(QKV + (size_t)(t0 + r)*9216 + 6144 + h*128 + c*8);
    *(short8*)&t[r][c*8] = v;
  }
  __syncthreads();
  int d = tid >> 1, half = tid & 1;
  size_t ob = (size_t)(h*128 + d)*SPAD + t0 + half*32;
  #pragma unroll
  for (int j=0;j<32;j+=2){
    unsigned int v = (unsigned int)t[half*32 + j][d] | ((unsigned int)t[half*32 + j + 1][d] << 16);
    *(unsigned int*)(VT + ob + j) = v;
  }
}

// ---------------------------------------------------------------------------
// Flash attention, fixed-max softmax. QBLK=128 (4 waves x 32 q-rows),
// KVBLK=32, K/V double-buffered (counted vmcnt(4), raw s_barrier).
// ---------------------------------------------------------------------------
__global__ __launch_bounds__(256, 3) void attn_fwd(
    const unsigned short* __restrict__ Q, const unsigned short* __restrict__ Kb,
    const unsigned short* __restrict__ VT, unsigned short* __restrict__ O)
{
  __shared__ unsigned short lK[2][32*128];   // 2 x 8KB
  __shared__ unsigned short lV[2][128*32];   // 2 x 8KB
  __shared__ unsigned short lP[4][32*72];    // 18KB

  int tid = threadIdx.x, wave = tid>>6, lane = tid&63;
  int l16 = lane&15, g = lane>>4;
  int h = blockIdx.x, qt = blockIdx.y;
  int q0 = qt*128 + wave*32;

  // stage K (8KB) + V (8KB) of 32-key tile kt into buffer b: 4 issues/thread
  auto STAGE = [&](int kt, int b){
    #pragma unroll
    for (int i=0;i<2;i++){
      int off = (i*4 + wave)*1024 + lane*16;
      int row = off>>8;                       // 0..31 (256B K rows)
      int sp  = (off>>4)&15;
      int ssp = sp ^ (row&7);
      gload16(Kb + ((size_t)h*SPAD + kt*32 + row)*128 + ssp*8,
              (char*)&lK[b][0] + (i*4 + wave)*1024);
    }
    #pragma unroll
    for (int i=0;i<2;i++){
      int off = (i*4 + wave)*1024 + lane*16;
      int row = off>>6;                       // 0..127 (64B VT rows)
      int sp  = (off>>4)&3;
      int ssp = sp ^ ((row>>1)&3);            // 2-way-free swizzle (R7 fix)
      gload16(VT + ((size_t)(h*128 + row))*SPAD + kt*32 + ssp*8,
              (char*)&lV[b][0] + (i*4 + wave)*1024);
    }
  };

  short8 qf[2][4];
  const unsigned short* qbase = Q + (size_t)h*SPAD*128;
  #pragma unroll
  for (int mt=0;mt<2;mt++){
    int row = q0 + mt*16 + l16;
    #pragma unroll
    for (int ks=0;ks<4;ks++)
      qf[mt][ks] = *(const short8*)(qbase + (size_t)row*128 + ks*32 + g*8);
  }

  f32x4 oacc[2][8] = {};
  float lsum[2][4] = {};

  unsigned short* lPw = &lP[wave][0];
  const float sc2 = 0.08838834764831845f * 1.4426950408889634f; // sc*log2(e)
  const float C2  = -12.0f * 1.4426950408889634f;

  STAGE(0, 0);                            // prologue: tile 0 -> buf0

  for (int kt=0; kt<104; kt++){
    int cur = kt & 1;
    int nxt = (kt+1 < 104) ? kt+1 : 103;  // clamp keeps vmcnt arithmetic exact
    STAGE(nxt, cur ^ 1);
    asm volatile("s_waitcnt vmcnt(4)" ::: "memory");  // tile kt's 4 loads done
    __builtin_amdgcn_s_barrier();

    const char* lKc = (const char*)&lK[cur][0];
    const char* lVc = (const char*)&lV[cur][0];

    // ---- QK^T (32 keys: nt = 0,1) ----
    f32x4 s[2][2] = {};
    #pragma unroll
    for (int ks=0;ks<4;ks++){
      short8 bfrag[2];
      #pragma unroll
      for (int nt=0;nt<2;nt++){
        int row = nt*16 + l16;
        int slot = (ks*4 + g) ^ (row&7);
        bfrag[nt] = *(const short8*)(lKc + row*256 + slot*16);
      }
      __builtin_amdgcn_s_setprio(1);
      #pragma unroll
      for (int mt=0;mt<2;mt++)
        #pragma unroll
        for (int nt=0;nt<2;nt++)
          s[mt][nt] = MFMA_BF16(qf[mt][ks], bfrag[nt], s[mt][nt]);
      __builtin_amdgcn_s_setprio(0);
    }

    // ---- fixed-max softmax: p = exp2(s*sc2 + C2) == exp(s*sc - 12) ----
    bool edge = (kt >= 102);
    #pragma unroll
    for (int mt=0;mt<2;mt++)
      #pragma unroll
      for (int nt=0;nt<2;nt++){
        #pragma unroll
        for (int r=0;r<4;r++){
          float p = exp2f(fmaf(s[mt][nt][r], sc2, C2));
          if (edge){
            int key = kt*32 + nt*16 + l16;
            if (key >= SVAL) p = 0.f;
          }
          lsum[mt][r] += p;
          lPw[(mt*16 + g*4 + r)*72 + nt*16 + l16] = bf16_rne(p);
        }
      }

    asm volatile("s_waitcnt lgkmcnt(0)" ::: "memory"); // P writes -> P reads

    // ---- PV (single 32-key slab) ----
    {
      short8 pa[2];
      #pragma unroll
      for (int mt=0;mt<2;mt++)
        pa[mt] = *(const short8*)(lPw + (mt*16 + l16)*72 + g*8);
      __builtin_amdgcn_s_setprio(1);
      #pragma unroll
      for (int dt=0;dt<8;dt++){
        int row = dt*16 + l16;
        int slot = g ^ ((row>>1)&3);          // match stage swizzle
        short8 vb = *(const short8*)(lVc + row*64 + slot*16);
        #pragma unroll
        for (int mt=0;mt<2;mt++)
          oacc[mt][dt] = MFMA_BF16(pa[mt], vb, oacc[mt][dt]);
      }
      __builtin_amdgcn_s_setprio(0);
    }
    __builtin_amdgcn_s_barrier();         // all waves done reading buf[cur]
  }

  #pragma unroll
  for (int mt=0;mt<2;mt++){
    float inv[4];
    #pragma unroll
    for (int r=0;r<4;r++){
      float v = lsum[mt][r];
      v += __shfl_xor(v, 1); v += __shfl_xor(v, 2);
      v += __shfl_xor(v, 4); v += __shfl_xor(v, 8);
      inv[r] = 1.0f / v;
    }
    #pragma unroll
    for (int dt=0;dt<8;dt++)
      #pragma unroll
      for (int r=0;r<4;r++){
        int row = q0 + mt*16 + g*4 + r;
        if (row < SVAL)
          O[(size_t)row*3072 + h*128 + dt*16 + l16] = bf16_rne(oacc[mt][dt][r]*inv[r]);
      }
  }
}

// ---------------------------------------------------------------------------
// Workspace layout (bytes).
// ---------------------------------------------------------------------------
static const size_t OFF_WT_QKV_X  = 0;                 // 9216*3072*2
static const size_t OFF_WT_QKV_Y  = 56623104;          // 9216*1536*2
static const size_t OFF_WT_PROJ_X = 84934656;          // 3072*3072*2
static const size_t OFF_WT_PROJ_Y = 103809024;         // 1536*3072*2
static const size_t OFF_XM        = 113246208;         // 3072*3072*2 (alias: qkv_y partials)
static const size_t OFF_YM        = 132120576;         // 256*1536*2
static const size_t OFF_QKV       = 132907008;         // 3328*9216*2
static const size_t OFF_Q         = 194248704;         // 24*3328*128*2 (alias: proj_y partials)
static const size_t OFF_K         = 214695936;
static const size_t OFF_VT        = 235143168;
static const size_t WS_NEEDED     = 255590400;
static const size_t OFF_AO        = 0;                 // 3328*3072*2 (alias Wt_qkv_x)

extern "C" void kernel_launch(void* const* d_in, const int* in_sizes, int n_in,
                              void* d_out, int out_size, void* d_ws, size_t ws_size,
                              hipStream_t stream) {
  if (ws_size < WS_NEEDED) return;

  const float* x        = (const float*)d_in[0];
  const float* y        = (const float*)d_in[1];
  const float* scale_x  = (const float*)d_in[2];
  const float* scale_y  = (const float*)d_in[3];
  const float* rope_cos = (const float*)d_in[4];
  const float* rope_sin = (const float*)d_in[5];
  const float* W_qkv_x  = (const float*)d_in[6];
  const float* b_qkv_x  = (const float*)d_in[7];
  const float* W_qkv_y  = (const float*)d_in[8];
  const float* b_qkv_y  = (const float*)d_in[9];
  const float* w_qn_x   = (const float*)d_in[10];
  const float* w_kn_x   = (const float*)d_in[11];
  const float* w_qn_y   = (const float*)d_in[12];
  const float* w_kn_y   = (const float*)d_in[13];
  const float* W_proj_x = (const float*)d_in[14];
  const float* b_proj_x = (const float*)d_in[15];
  const float* W_proj_y = (const float*)d_in[16];
  const float* b_proj_y = (const float*)d_in[17];

  float* out_x = (float*)d_out;
  float* out_y = out_x + (size_t)3072*3072;

  char* ws = (char*)d_ws;
  unsigned short* Wt_qkv_x  = (unsigned short*)(ws + OFF_WT_QKV_X);
  unsigned short* Wt_qkv_y  = (unsigned short*)(ws + OFF_WT_QKV_Y);
  unsigned short* Wt_proj_x = (unsigned short*)(ws + OFF_WT_PROJ_X);
  unsigned short* Wt_proj_y = (unsigned short*)(ws + OFF_WT_PROJ_Y);
  unsigned short* xm        = (unsigned short*)(ws + OFF_XM);
  unsigned short* ym        = (unsigned short*)(ws + OFF_YM);
  unsigned short* qkv       = (unsigned short*)(ws + OFF_QKV);
  unsigned short* Qb        = (unsigned short*)(ws + OFF_Q);
  unsigned short* Kb        = (unsigned short*)(ws + OFF_K);
  unsigned short* VTb       = (unsigned short*)(ws + OFF_VT);
  unsigned short* attnout   = (unsigned short*)(ws + OFF_AO);
  float* part_qkv_y         = (float*)(ws + OFF_XM);
  float* part_proj_y        = (float*)(ws + OFF_Q);

  transpose_w<<<dim3(9216/64, 3072/64), 256, 0, stream>>>(W_qkv_x,  Wt_qkv_x,  3072, 9216);
  transpose_w<<<dim3(9216/64, 1536/64), 256, 0, stream>>>(W_qkv_y,  Wt_qkv_y,  1536, 9216);
  transpose_w<<<dim3(3072/64, 3072/64), 256, 0, stream>>>(W_proj_x, Wt_proj_x, 3072, 3072);
  transpose_w<<<dim3(1536/64, 3072/64), 256, 0, stream>>>(W_proj_y, Wt_proj_y, 3072, 1536);

  modnorm<3072><<<3072, 256, 0, stream>>>(x, scale_x, xm);
  modnorm<1536><<<256,  256, 0, stream>>>(y, scale_y, ym);

  gemm_8ph<<<dim3(36, 12), 512, 0, stream>>>(
      xm, Wt_qkv_x, b_qkv_x, qkv, 3072, 9216, 3072, 9216);

  gemm_bt<float, false><<<dim3(72, 2, 2), 256, 0, stream>>>(
      ym, Wt_qkv_y, nullptr, part_qkv_y, 256, 9216, 1536, 9216, 768);
  reduce2_bias_bf16<<<2304, 256, 0, stream>>>(
      part_qkv_y, b_qkv_y, qkv + (size_t)3072*9216, 9216, (size_t)256*9216);

  fixup_qk<<<SVAL*NH/4, 256, 0, stream>>>(qkv, rope_cos, rope_sin,
                                          w_qn_x, w_kn_x, w_qn_y, w_kn_y, Qb, Kb);
  v_transpose<<<dim3(NH, SPAD/64), 256, 0, stream>>>(qkv, VTb);

  (void)hipMemsetAsync(attnout + (size_t)SVAL*3072, 0,
                       (size_t)(SPAD - SVAL)*3072*2, stream);

  attn_fwd<<<dim3(NH, SPAD/128), 256, 0, stream>>>(Qb, Kb, VTb, attnout);

  gemm_bt<float, true><<<dim3(24, 24, 1), 256, 0, stream>>>(
      attnout, Wt_proj_x, b_proj_x, out_x, 3072, 3072, 3072, 3072, 3072);

  gemm_bt<float, false><<<dim3(12, 2, 8), 256, 0, stream>>>(
      attnout + (size_t)3072*3072, Wt_proj_y, nullptr, part_proj_y,
      256, 1536, 3072, 1536, 384);
  reduce8_bias_f32<<<384, 256, 0, stream>>>(
      part_proj_y, b_proj_y, out_y, 1536, (size_t)256*1536);
}

// Round 9
// 602.825 us; speedup vs baseline: 1.0461x; 1.0461x over previous
//
#include <hip/hip_runtime.h>

// ---------------------------------------------------------------------------
// AsymmetricAttention fused pipeline for MI355X (gfx950), bf16 MFMA throughout.
// R9: exp2f (OCML wrapper w/ range checks = R7/R8's VALU regression) ->
//     __builtin_amdgcn_exp2f (raw v_exp_f32). Keeps R8's V-swizzle fix,
//     fma-folded scale, hoisted edge mask. Everything else unchanged.
// ---------------------------------------------------------------------------

typedef short short8 __attribute__((ext_vector_type(8)));
typedef float f32x4 __attribute__((ext_vector_type(4)));
typedef unsigned short ushort4v __attribute__((ext_vector_type(4)));

#define MFMA_BF16(a,b,c) __builtin_amdgcn_mfma_f32_16x16x32_bf16((a),(b),(c),0,0,0)

#define NH 24
#define SPAD 3328   // padded token count (104*32)
#define SVAL 3272   // valid tokens (3072 x + 200 y)

__device__ __forceinline__ unsigned short bf16_rne(float f){
  unsigned int u = __builtin_bit_cast(unsigned int, f);
  u += 0x7FFFu + ((u >> 16) & 1u);
  return (unsigned short)(u >> 16);
}
__device__ __forceinline__ float bf2f(unsigned short h){
  unsigned int u = ((unsigned int)h) << 16;
  return __builtin_bit_cast(float, u);
}
__device__ __forceinline__ void gload16(const void* g, void* l){
  __builtin_amdgcn_global_load_lds(
      (const __attribute__((address_space(1))) unsigned int*)g,
      (__attribute__((address_space(3))) unsigned int*)l, 16, 0, 0);
}

// ---------------------------------------------------------------------------
// W (K x N) fp32 row-major -> Wt (N x K) bf16 row-major. 64x64 tiles.
// ---------------------------------------------------------------------------
__global__ __launch_bounds__(256) void transpose_w(
    const float* __restrict__ W, unsigned short* __restrict__ Wt, int K, int N)
{
  __shared__ unsigned short t[64][66];
  int n0 = blockIdx.x*64, k0 = blockIdx.y*64;
  int tid = threadIdx.x;
  int kr = tid >> 4, nc = (tid & 15) * 4;
  #pragma unroll
  for (int pass=0; pass<4; pass++){
    int k = kr + pass*16;
    float4 v = *(const float4*)(W + (size_t)(k0+k)*N + n0 + nc);
    ushort4v o;
    o.x = bf16_rne(v.x); o.y = bf16_rne(v.y);
    o.z = bf16_rne(v.z); o.w = bf16_rne(v.w);
    *(ushort4v*)&t[k][nc] = o;
  }
  __syncthreads();
  int nr = tid >> 3, kc = (tid & 7) * 8;
  #pragma unroll
  for (int pass=0; pass<2; pass++){
    int n = nr + pass*32;
    unsigned short buf[8];
    #pragma unroll
    for (int j=0;j<8;j++) buf[j] = t[kc+j][n];
    *(short8*)(Wt + (size_t)(n0+n)*K + k0 + kc) = *(short8*)&buf[0];
  }
}

// ---------------------------------------------------------------------------
// mod-rmsnorm: out = bf16( x * rsqrt(mean(x^2)+1e-6) * (1+scale[col]) )
// ---------------------------------------------------------------------------
template<int D>
__global__ __launch_bounds__(256) void modnorm(
    const float* __restrict__ X, const float* __restrict__ scale,
    unsigned short* __restrict__ out)
{
  int row = blockIdx.x;
  const float4* xv = (const float4*)(X + (size_t)row*D);
  float ss = 0.f;
  for (int i = threadIdx.x; i < D/4; i += 256){
    float4 v = xv[i];
    ss += v.x*v.x + v.y*v.y + v.z*v.z + v.w*v.w;
  }
  #pragma unroll
  for (int d=1; d<64; d<<=1) ss += __shfl_xor(ss, d);
  __shared__ float wsum[4];
  if ((threadIdx.x & 63) == 0) wsum[threadIdx.x >> 6] = ss;
  __syncthreads();
  float tot = wsum[0] + wsum[1] + wsum[2] + wsum[3];
  float rn = rsqrtf(tot*(1.0f/(float)D) + 1e-6f);
  const float4* sv = (const float4*)scale;
  for (int i = threadIdx.x; i < D/4; i += 256){
    float4 v = xv[i]; float4 s4 = sv[i];
    ushort4v o;
    o.x = bf16_rne(v.x*rn*(1.f+s4.x));
    o.y = bf16_rne(v.y*rn*(1.f+s4.y));
    o.z = bf16_rne(v.z*rn*(1.f+s4.z));
    o.w = bf16_rne(v.w*rn*(1.f+s4.w));
    *(ushort4v*)(out + (size_t)row*D + i*4) = o;
  }
}

// ---------------------------------------------------------------------------
// 128^2-tile GEMM (m97 structure) with optional split-K via blockIdx.z.
// ---------------------------------------------------------------------------
template<typename CT, bool BIAS>
__global__ __launch_bounds__(256, 3) void gemm_bt(
    const unsigned short* __restrict__ A, const unsigned short* __restrict__ BT,
    const float* __restrict__ bias, CT* __restrict__ C,
    int M, int N, int K, int ldc, int klen)
{
  __shared__ unsigned short lA[128*32];
  __shared__ unsigned short lB[128*32];
  int tid = threadIdx.x, wave = tid>>6, lane = tid&63;
  int l16 = lane&15, g = lane>>4;
  int wr = wave>>1, wc = wave&1;

  int nwg = gridDim.x*gridDim.y;
  int orig = blockIdx.y*gridDim.x + blockIdx.x;
  int neo = orig;
  if ((nwg & 7) == 0){
    int q8 = nwg >> 3;
    neo = (orig & 7)*q8 + (orig >> 3);
  }
  int bx = neo / gridDim.y;
  int by = neo % gridDim.y;
  int bm = by*128, bn = bx*128;
  int kof = blockIdx.z * klen;
  CT* Cp = C + (size_t)blockIdx.z * M * (size_t)ldc;

  f32x4 acc[4][4] = {};

  for (int k0 = kof; k0 < kof + klen; k0 += 32){
    #pragma unroll
    for (int i=0;i<2;i++){
      int off = i*4096 + wave*1024 + lane*16;
      int row = off>>6;
      int sp  = (off>>4)&3;
      int sk  = (sp ^ (row&3))*8;
      gload16(A + (size_t)(bm+row)*K + k0 + sk, (char*)lA + i*4096 + wave*1024);
    }
    #pragma unroll
    for (int i=0;i<2;i++){
      int off = i*4096 + wave*1024 + lane*16;
      int row = off>>6;
      int sp  = (off>>4)&3;
      int sk  = (sp ^ (row&3))*8;
      gload16(BT + (size_t)(bn+row)*K + k0 + sk, (char*)lB + i*4096 + wave*1024);
    }
    __syncthreads();

    short8 a[4], b[4];
    #pragma unroll
    for (int m=0;m<4;m++){
      int row = wr*64 + m*16 + l16;
      int slot = g ^ (row&3);
      a[m] = *(const short8*)((const char*)lA + row*64 + slot*16);
    }
    #pragma unroll
    for (int n=0;n<4;n++){
      int row = wc*64 + n*16 + l16;
      int slot = g ^ (row&3);
      b[n] = *(const short8*)((const char*)lB + row*64 + slot*16);
    }
    __builtin_amdgcn_s_setprio(1);
    #pragma unroll
    for (int m=0;m<4;m++)
      #pragma unroll
      for (int n=0;n<4;n++)
        acc[m][n] = MFMA_BF16(a[m], b[n], acc[m][n]);
    __builtin_amdgcn_s_setprio(0);
    __syncthreads();
  }

  #pragma unroll
  for (int n=0;n<4;n++){
    int col = bn + wc*64 + n*16 + l16;
    float bv = BIAS ? bias[col] : 0.f;
    #pragma unroll
    for (int m=0;m<4;m++){
      int row0 = bm + wr*64 + m*16 + g*4;
      #pragma unroll
      for (int r=0;r<4;r++){
        float v = acc[m][n][r] + bv;
        if constexpr (sizeof(CT) == 4) Cp[(size_t)(row0+r)*ldc + col] = v;
        else                           Cp[(size_t)(row0+r)*ldc + col] = bf16_rne(v);
      }
    }
  }
}

// ---------------------------------------------------------------------------
// 256^2-tile 8-phase GEMM (m201/HK schedule in plain HIP). BK=64, 8 waves.
// ---------------------------------------------------------------------------
__global__ __launch_bounds__(512, 2) void gemm_8ph(
    const unsigned short* __restrict__ A, const unsigned short* __restrict__ BT,
    const float* __restrict__ bias, unsigned short* __restrict__ C,
    int M, int N, int K, int ldc)
{
  __shared__ unsigned short lds[8][8192];

  int tid = threadIdx.x, wave = tid>>6, lane = tid&63;
  int l16 = lane&15, g = lane>>4;
  int wr = wave>>2, wc = wave&3;

  int nwg = gridDim.x*gridDim.y;
  int orig = blockIdx.y*gridDim.x + blockIdx.x;
  int neo = orig;
  if ((nwg & 7) == 0) neo = (orig & 7)*(nwg>>3) + (orig>>3);
  int bx = neo / gridDim.y, by = neo % gridDim.y;
  int bm = by*256, bn = bx*256;

  const int NT = K >> 6;

  auto STAGE = [&](int t, int op, int half, int b){
    int tc = t < NT ? t : NT-1;
    const unsigned short* src = op ? BT : A;
    int base_row = (op ? bn : bm) + half*128;
    int k0 = tc << 6;
    #pragma unroll
    for (int j=0;j<2;j++){
      int o = (j*8 + wave)*1024 + lane*16;
      int row = o>>7, slot = (o>>4)&7;
      int sk = (slot ^ (row&7))*8;
      gload16(src + (size_t)(base_row+row)*K + k0 + sk,
              (char*)&lds[(b<<2)|(op<<1)|half][0] + (j*8+wave)*1024);
    }
  };

  short8 afr[4], bfr[8];
  auto LDA = [&](int b, int p){
    const char* basep = (const char*)&lds[(b<<2)|wr][0];
    #pragma unroll
    for (int mm=0;mm<2;mm++){
      int row = (p*2+mm)*16 + l16;
      #pragma unroll
      for (int kk=0;kk<2;kk++)
        afr[mm*2+kk] = *(const short8*)(basep + row*128 + (((kk*4+g) ^ (row&7))<<4));
    }
  };
  auto LDB = [&](int b){
    const char* basep = (const char*)&lds[(b<<2)|2|(wc>>1)][0];
    int rbase = (wc&1)*64;
    #pragma unroll
    for (int n=0;n<4;n++){
      int row = rbase + n*16 + l16;
      #pragma unroll
      for (int kk=0;kk<2;kk++)
        bfr[n*2+kk] = *(const short8*)(basep + row*128 + (((kk*4+g) ^ (row&7))<<4));
    }
  };

  f32x4 acc[8][4] = {};

  STAGE(0,1,0,0); STAGE(0,1,1,0); STAGE(0,0,0,0); STAGE(0,0,1,0);
  STAGE(1,1,0,1); STAGE(1,1,1,1); STAGE(1,0,0,1);
  asm volatile("s_waitcnt vmcnt(6)" ::: "memory");
  __builtin_amdgcn_s_barrier();

  int NIT = NT >> 1;
  for (int i=0;i<NIT;i++){
    int T = 2*i;
    #pragma unroll
    for (int p=0;p<4;p++){
      if (p==0) LDB(0);
      LDA(0, p);
      if (p==0)      STAGE(T+1,0,1,1);
      else if (p==1) STAGE(T+2,1,0,0);
      else if (p==2) STAGE(T+2,1,1,0);
      else           STAGE(T+2,0,0,0);
      if (p==0) asm volatile("s_waitcnt lgkmcnt(8)" ::: "memory");
      __builtin_amdgcn_s_barrier();
      asm volatile("s_waitcnt lgkmcnt(0)" ::: "memory");
      __builtin_amdgcn_sched_barrier(0);
      __builtin_amdgcn_s_setprio(1);
      #pragma unroll
      for (int mm=0;mm<2;mm++)
        #pragma unroll
        for (int n=0;n<4;n++)
          #pragma unroll
          for (int kk=0;kk<2;kk++)
            acc[p*2+mm][n] = MFMA_BF16(afr[mm*2+kk], bfr[n*2+kk], acc[p*2+mm][n]);
      __builtin_amdgcn_s_setprio(0);
      if (p==3) asm volatile("s_waitcnt vmcnt(6)" ::: "memory");
      __builtin_amdgcn_s_barrier();
    }
    #pragma unroll
    for (int p=0;p<4;p++){
      if (p==0) LDB(1);
      LDA(1, p);
      if (p==0)      STAGE(T+2,0,1,0);
      else if (p==1) STAGE(T+3,1,0,1);
      else if (p==2) STAGE(T+3,1,1,1);
      else           STAGE(T+3,0,0,1);
      if (p==0) asm volatile("s_waitcnt lgkmcnt(8)" ::: "memory");
      __builtin_amdgcn_s_barrier();
      asm volatile("s_waitcnt lgkmcnt(0)" ::: "memory");
      __builtin_amdgcn_sched_barrier(0);
      __builtin_amdgcn_s_setprio(1);
      #pragma unroll
      for (int mm=0;mm<2;mm++)
        #pragma unroll
        for (int n=0;n<4;n++)
          #pragma unroll
          for (int kk=0;kk<2;kk++)
            acc[p*2+mm][n] = MFMA_BF16(afr[mm*2+kk], bfr[n*2+kk], acc[p*2+mm][n]);
      __builtin_amdgcn_s_setprio(0);
      if (p==3) asm volatile("s_waitcnt vmcnt(6)" ::: "memory");
      __builtin_amdgcn_s_barrier();
    }
  }

  #pragma unroll
  for (int n=0;n<4;n++){
    int col = bn + wc*64 + n*16 + l16;
    float bv = bias[col];
    #pragma unroll
    for (int m=0;m<8;m++){
      int row0 = bm + wr*128 + m*16 + g*4;
      #pragma unroll
      for (int r=0;r<4;r++)
        C[(size_t)(row0+r)*ldc + col] = bf16_rne(acc[m][n][r] + bv);
    }
  }
}

// ---------------------------------------------------------------------------
// split-K reduces
// ---------------------------------------------------------------------------
__global__ __launch_bounds__(256) void reduce2_bias_bf16(
    const float* __restrict__ part, const float* __restrict__ bias,
    unsigned short* __restrict__ out, int N, size_t tot)
{
  size_t idx = ((size_t)blockIdx.x*256 + threadIdx.x)*4;
  if (idx >= tot) return;
  float4 a = *(const float4*)(part + idx);
  float4 b = *(const float4*)(part + tot + idx);
  int col = (int)(idx % N);
  float4 bv = *(const float4*)(bias + col);
  ushort4v o;
  o.x = bf16_rne(a.x+b.x+bv.x);
  o.y = bf16_rne(a.y+b.y+bv.y);
  o.z = bf16_rne(a.z+b.z+bv.z);
  o.w = bf16_rne(a.w+b.w+bv.w);
  *(ushort4v*)(out + idx) = o;
}

__global__ __launch_bounds__(256) void reduce8_bias_f32(
    const float* __restrict__ part, const float* __restrict__ bias,
    float* __restrict__ out, int N, size_t tot)
{
  size_t idx = ((size_t)blockIdx.x*256 + threadIdx.x)*4;
  if (idx >= tot) return;
  int col = (int)(idx % N);
  float4 s = *(const float4*)(bias + col);
  #pragma unroll
  for (int c=0;c<8;c++){
    float4 a = *(const float4*)(part + (size_t)c*tot + idx);
    s.x += a.x; s.y += a.y; s.z += a.z; s.w += a.w;
  }
  *(float4*)(out + idx) = s;
}

// ---------------------------------------------------------------------------
// qk fixup: 4 waves/block, one (token,head) per wave.
// ---------------------------------------------------------------------------
__global__ __launch_bounds__(256) void fixup_qk(
    const unsigned short* __restrict__ QKV,
    const float* __restrict__ cosT, const float* __restrict__ sinT,
    const float* __restrict__ wqx, const float* __restrict__ wkx,
    const float* __restrict__ wqy, const float* __restrict__ wky,
    unsigned short* __restrict__ Qo, unsigned short* __restrict__ Ko)
{
  int wave = threadIdx.x >> 6, lane = threadIdx.x & 63;
  int bid = blockIdx.x*4 + wave;
  int t = bid / NH, h = bid % NH;
  bool isx = (t < 3072);

  const unsigned short* base = QKV + (size_t)t*9216 + h*128;
  unsigned int qraw = *(const unsigned int*)(base + 2*lane);
  unsigned int kraw = *(const unsigned int*)(base + 3072 + 2*lane);
  float q0 = bf2f((unsigned short)(qraw & 0xffff)), q1 = bf2f((unsigned short)(qraw >> 16));
  float k0 = bf2f((unsigned short)(kraw & 0xffff)), k1 = bf2f((unsigned short)(kraw >> 16));

  float sq = q0*q0 + q1*q1, sk = k0*k0 + k1*k1;
  #pragma unroll
  for (int d=1; d<64; d<<=1){ sq += __shfl_xor(sq, d); sk += __shfl_xor(sk, d); }
  float rq = rsqrtf(sq*(1.0f/128.0f) + 1e-5f);
  float rk = rsqrtf(sk*(1.0f/128.0f) + 1e-5f);

  const float* wq = isx ? wqx : wqy;
  const float* wk = isx ? wkx : wky;
  float a0 = q0*rq*wq[2*lane], a1 = q1*rq*wq[2*lane+1];
  float b0 = k0*rk*wk[2*lane], b1 = k1*rk*wk[2*lane+1];

  if (isx){
    size_t ci = ((size_t)t*NH + h)*64 + lane;
    float c = cosT[ci], s = sinT[ci];
    float t0 = a0*c - a1*s, t1 = a0*s + a1*c; a0 = t0; a1 = t1;
    t0 = b0*c - b1*s; t1 = b0*s + b1*c; b0 = t0; b1 = t1;
  }
  size_t oi = ((size_t)h*SPAD + t)*128 + 2*lane;
  *(unsigned int*)(Qo + oi) = (unsigned int)bf16_rne(a0) | ((unsigned int)bf16_rne(a1) << 16);
  *(unsigned int*)(Ko + oi) = (unsigned int)bf16_rne(b0) | ((unsigned int)bf16_rne(b1) << 16);
}

// ---------------------------------------------------------------------------
// V transpose: qkv v-section (token,128) -> VT (H, 128, SPAD) bf16
// ---------------------------------------------------------------------------
__global__ __launch_bounds__(256) void v_transpose(
    const unsigned short* __restrict__ QKV, unsigned short* __restrict__ VT)
{
  __shared__ unsigned short t[64][136];
  int h = blockIdx.x;
  int t0 = blockIdx.y*64;
  int tid = threadIdx.x;
  #pragma unroll
  for (int it=0; it<4; it++){
    int chunk = it*256 + tid;
    int r = chunk >> 4, c = chunk & 15;
    short8 v = *(const short8*)(QKV + (size_t)(t0 + r)*9216 + 6144 + h*128 + c*8);
    *(short8*)&t[r][c*8] = v;
  }
  __syncthreads();
  int d = tid >> 1, half = tid & 1;
  size_t ob = (size_t)(h*128 + d)*SPAD + t0 + half*32;
  #pragma unroll
  for (int j=0;j<32;j+=2){
    unsigned int v = (unsigned int)t[half*32 + j][d] | ((unsigned int)t[half*32 + j + 1][d] << 16);
    *(unsigned int*)(VT + ob + j) = v;
  }
}

// ---------------------------------------------------------------------------
// Flash attention, fixed-max softmax. QBLK=128 (4 waves x 32 q-rows),
// KVBLK=32, K/V double-buffered (counted vmcnt(4), raw s_barrier).
// ---------------------------------------------------------------------------
__global__ __launch_bounds__(256, 3) void attn_fwd(
    const unsigned short* __restrict__ Q, const unsigned short* __restrict__ Kb,
    const unsigned short* __restrict__ VT, unsigned short* __restrict__ O)
{
  __shared__ unsigned short lK[2][32*128];   // 2 x 8KB
  __shared__ unsigned short lV[2][128*32];   // 2 x 8KB
  __shared__ unsigned short lP[4][32*72];    // 18KB

  int tid = threadIdx.x, wave = tid>>6, lane = tid&63;
  int l16 = lane&15, g = lane>>4;
  int h = blockIdx.x, qt = blockIdx.y;
  int q0 = qt*128 + wave*32;

  // stage K (8KB) + V (8KB) of 32-key tile kt into buffer b: 4 issues/thread
  auto STAGE = [&](int kt, int b){
    #pragma unroll
    for (int i=0;i<2;i++){
      int off = (i*4 + wave)*1024 + lane*16;
      int row = off>>8;                       // 0..31 (256B K rows)
      int sp  = (off>>4)&15;
      int ssp = sp ^ (row&7);
      gload16(Kb + ((size_t)h*SPAD + kt*32 + row)*128 + ssp*8,
              (char*)&lK[b][0] + (i*4 + wave)*1024);
    }
    #pragma unroll
    for (int i=0;i<2;i++){
      int off = (i*4 + wave)*1024 + lane*16;
      int row = off>>6;                       // 0..127 (64B VT rows)
      int sp  = (off>>4)&3;
      int ssp = sp ^ ((row>>1)&3);            // 2-way-free swizzle
      gload16(VT + ((size_t)(h*128 + row))*SPAD + kt*32 + ssp*8,
              (char*)&lV[b][0] + (i*4 + wave)*1024);
    }
  };

  short8 qf[2][4];
  const unsigned short* qbase = Q + (size_t)h*SPAD*128;
  #pragma unroll
  for (int mt=0;mt<2;mt++){
    int row = q0 + mt*16 + l16;
    #pragma unroll
    for (int ks=0;ks<4;ks++)
      qf[mt][ks] = *(const short8*)(qbase + (size_t)row*128 + ks*32 + g*8);
  }

  f32x4 oacc[2][8] = {};
  float lsum[2][4] = {};

  unsigned short* lPw = &lP[wave][0];
  const float sc2 = 0.08838834764831845f * 1.4426950408889634f; // sc*log2(e)
  const float C2  = -12.0f * 1.4426950408889634f;

  STAGE(0, 0);                            // prologue: tile 0 -> buf0

  for (int kt=0; kt<104; kt++){
    int cur = kt & 1;
    int nxt = (kt+1 < 104) ? kt+1 : 103;  // clamp keeps vmcnt arithmetic exact
    STAGE(nxt, cur ^ 1);
    asm volatile("s_waitcnt vmcnt(4)" ::: "memory");  // tile kt's 4 loads done
    __builtin_amdgcn_s_barrier();

    const char* lKc = (const char*)&lK[cur][0];
    const char* lVc = (const char*)&lV[cur][0];

    // ---- QK^T (32 keys: nt = 0,1) ----
    f32x4 s[2][2] = {};
    #pragma unroll
    for (int ks=0;ks<4;ks++){
      short8 bfrag[2];
      #pragma unroll
      for (int nt=0;nt<2;nt++){
        int row = nt*16 + l16;
        int slot = (ks*4 + g) ^ (row&7);
        bfrag[nt] = *(const short8*)(lKc + row*256 + slot*16);
      }
      __builtin_amdgcn_s_setprio(1);
      #pragma unroll
      for (int mt=0;mt<2;mt++)
        #pragma unroll
        for (int nt=0;nt<2;nt++)
          s[mt][nt] = MFMA_BF16(qf[mt][ks], bfrag[nt], s[mt][nt]);
      __builtin_amdgcn_s_setprio(0);
    }

    // ---- fixed-max softmax: p = exp2(s*sc2 + C2) == exp(s*sc - 12) ----
    // raw v_exp_f32: arg in [-25,-0.8], no range-check wrapper needed
    bool edge = (kt >= 102);
    #pragma unroll
    for (int mt=0;mt<2;mt++)
      #pragma unroll
      for (int nt=0;nt<2;nt++){
        #pragma unroll
        for (int r=0;r<4;r++){
          float p = __builtin_amdgcn_exp2f(fmaf(s[mt][nt][r], sc2, C2));
          if (edge){
            int key = kt*32 + nt*16 + l16;
            if (key >= SVAL) p = 0.f;
          }
          lsum[mt][r] += p;
          lPw[(mt*16 + g*4 + r)*72 + nt*16 + l16] = bf16_rne(p);
        }
      }

    asm volatile("s_waitcnt lgkmcnt(0)" ::: "memory"); // P writes -> P reads

    // ---- PV (single 32-key slab) ----
    {
      short8 pa[2];
      #pragma unroll
      for (int mt=0;mt<2;mt++)
        pa[mt] = *(const short8*)(lPw + (mt*16 + l16)*72 + g*8);
      __builtin_amdgcn_s_setprio(1);
      #pragma unroll
      for (int dt=0;dt<8;dt++){
        int row = dt*16 + l16;
        int slot = g ^ ((row>>1)&3);          // match stage swizzle
        short8 vb = *(const short8*)(lVc + row*64 + slot*16);
        #pragma unroll
        for (int mt=0;mt<2;mt++)
          oacc[mt][dt] = MFMA_BF16(pa[mt], vb, oacc[mt][dt]);
      }
      __builtin_amdgcn_s_setprio(0);
    }
    __builtin_amdgcn_s_barrier();         // all waves done reading buf[cur]
  }

  #pragma unroll
  for (int mt=0;mt<2;mt++){
    float inv[4];
    #pragma unroll
    for (int r=0;r<4;r++){
      float v = lsum[mt][r];
      v += __shfl_xor(v, 1); v += __shfl_xor(v, 2);
      v += __shfl_xor(v, 4); v += __shfl_xor(v, 8);
      inv[r] = 1.0f / v;
    }
    #pragma unroll
    for (int dt=0;dt<8;dt++)
      #pragma unroll
      for (int r=0;r<4;r++){
        int row = q0 + mt*16 + g*4 + r;
        if (row < SVAL)
          O[(size_t)row*3072 + h*128 + dt*16 + l16] = bf16_rne(oacc[mt][dt][r]*inv[r]);
      }
  }
}

// ---------------------------------------------------------------------------
// Workspace layout (bytes).
// ---------------------------------------------------------------------------
static const size_t OFF_WT_QKV_X  = 0;                 // 9216*3072*2
static const size_t OFF_WT_QKV_Y  = 56623104;          // 9216*1536*2
static const size_t OFF_WT_PROJ_X = 84934656;          // 3072*3072*2
static const size_t OFF_WT_PROJ_Y = 103809024;         // 1536*3072*2
static const size_t OFF_XM        = 113246208;         // 3072*3072*2 (alias: qkv_y partials)
static const size_t OFF_YM        = 132120576;         // 256*1536*2
static const size_t OFF_QKV       = 132907008;         // 3328*9216*2
static const size_t OFF_Q         = 194248704;         // 24*3328*128*2 (alias: proj_y partials)
static const size_t OFF_K         = 214695936;
static const size_t OFF_VT        = 235143168;
static const size_t WS_NEEDED     = 255590400;
static const size_t OFF_AO        = 0;                 // 3328*3072*2 (alias Wt_qkv_x)

extern "C" void kernel_launch(void* const* d_in, const int* in_sizes, int n_in,
                              void* d_out, int out_size, void* d_ws, size_t ws_size,
                              hipStream_t stream) {
  if (ws_size < WS_NEEDED) return;

  const float* x        = (const float*)d_in[0];
  const float* y        = (const float*)d_in[1];
  const float* scale_x  = (const float*)d_in[2];
  const float* scale_y  = (const float*)d_in[3];
  const float* rope_cos = (const float*)d_in[4];
  const float* rope_sin = (const float*)d_in[5];
  const float* W_qkv_x  = (const float*)d_in[6];
  const float* b_qkv_x  = (const float*)d_in[7];
  const float* W_qkv_y  = (const float*)d_in[8];
  const float* b_qkv_y  = (const float*)d_in[9];
  const float* w_qn_x   = (const float*)d_in[10];
  const float* w_kn_x   = (const float*)d_in[11];
  const float* w_qn_y   = (const float*)d_in[12];
  const float* w_kn_y   = (const float*)d_in[13];
  const float* W_proj_x = (const float*)d_in[14];
  const float* b_proj_x = (const float*)d_in[15];
  const float* W_proj_y = (const float*)d_in[16];
  const float* b_proj_y = (const float*)d_in[17];

  float* out_x = (float*)d_out;
  float* out_y = out_x + (size_t)3072*3072;

  char* ws = (char*)d_ws;
  unsigned short* Wt_qkv_x  = (unsigned short*)(ws + OFF_WT_QKV_X);
  unsigned short* Wt_qkv_y  = (unsigned short*)(ws + OFF_WT_QKV_Y);
  unsigned short* Wt_proj_x = (unsigned short*)(ws + OFF_WT_PROJ_X);
  unsigned short* Wt_proj_y = (unsigned short*)(ws + OFF_WT_PROJ_Y);
  unsigned short* xm        = (unsigned short*)(ws + OFF_XM);
  unsigned short* ym        = (unsigned short*)(ws + OFF_YM);
  unsigned short* qkv       = (unsigned short*)(ws + OFF_QKV);
  unsigned short* Qb        = (unsigned short*)(ws + OFF_Q);
  unsigned short* Kb        = (unsigned short*)(ws + OFF_K);
  unsigned short* VTb       = (unsigned short*)(ws + OFF_VT);
  unsigned short* attnout   = (unsigned short*)(ws + OFF_AO);
  float* part_qkv_y         = (float*)(ws + OFF_XM);
  float* part_proj_y        = (float*)(ws + OFF_Q);

  transpose_w<<<dim3(9216/64, 3072/64), 256, 0, stream>>>(W_qkv_x,  Wt_qkv_x,  3072, 9216);
  transpose_w<<<dim3(9216/64, 1536/64), 256, 0, stream>>>(W_qkv_y,  Wt_qkv_y,  1536, 9216);
  transpose_w<<<dim3(3072/64, 3072/64), 256, 0, stream>>>(W_proj_x, Wt_proj_x, 3072, 3072);
  transpose_w<<<dim3(1536/64, 3072/64), 256, 0, stream>>>(W_proj_y, Wt_proj_y, 3072, 1536);

  modnorm<3072><<<3072, 256, 0, stream>>>(x, scale_x, xm);
  modnorm<1536><<<256,  256, 0, stream>>>(y, scale_y, ym);

  gemm_8ph<<<dim3(36, 12), 512, 0, stream>>>(
      xm, Wt_qkv_x, b_qkv_x, qkv, 3072, 9216, 3072, 9216);

  gemm_bt<float, false><<<dim3(72, 2, 2), 256, 0, stream>>>(
      ym, Wt_qkv_y, nullptr, part_qkv_y, 256, 9216, 1536, 9216, 768);
  reduce2_bias_bf16<<<2304, 256, 0, stream>>>(
      part_qkv_y, b_qkv_y, qkv + (size_t)3072*9216, 9216, (size_t)256*9216);

  fixup_qk<<<SVAL*NH/4, 256, 0, stream>>>(qkv, rope_cos, rope_sin,
                                          w_qn_x, w_kn_x, w_qn_y, w_kn_y, Qb, Kb);
  v_transpose<<<dim3(NH, SPAD/64), 256, 0, stream>>>(qkv, VTb);

  (void)hipMemsetAsync(attnout + (size_t)SVAL*3072, 0,
                       (size_t)(SPAD - SVAL)*3072*2, stream);

  attn_fwd<<<dim3(NH, SPAD/128), 256, 0, stream>>>(Qb, Kb, VTb, attnout);

  gemm_bt<float, true><<<dim3(24, 24, 1), 256, 0, stream>>>(
      attnout, Wt_proj_x, b_proj_x, out_x, 3072, 3072, 3072, 3072, 3072);

  gemm_bt<float, false><<<dim3(12, 2, 8), 256, 0, stream>>>(
      attnout + (size_t)3072*3072, Wt_proj_y, nullptr, part_proj_y,
      256, 1536, 3072, 1536, 384);
  reduce8_bias_f32<<<384, 256, 0, stream>>>(
      part_proj_y, b_proj_y, out_y, 1536, (size_t)256*1536);
}

// Round 10
// 551.922 us; speedup vs baseline: 1.1426x; 1.0922x over previous
//
#include <hip/hip_runtime.h>

// ---------------------------------------------------------------------------
// AsymmetricAttention fused pipeline for MI355X (gfx950), bf16 MFMA throughout.
// R10: fold qkv_y into gemm_8ph (extra grid row, K=1536) and proj_y into the
//      proj GEMM (extra grid row) — the under-occupied y-GEMMs become tail
//      fillers instead of serial dispatches. Split-K + reduces deleted.
//      attn unchanged from R9 (native exp2).
// ---------------------------------------------------------------------------

typedef short short8 __attribute__((ext_vector_type(8)));
typedef float f32x4 __attribute__((ext_vector_type(4)));
typedef unsigned short ushort4v __attribute__((ext_vector_type(4)));

#define MFMA_BF16(a,b,c) __builtin_amdgcn_mfma_f32_16x16x32_bf16((a),(b),(c),0,0,0)

#define NH 24
#define SPAD 3328   // padded token count (104*32)
#define SVAL 3272   // valid tokens (3072 x + 200 y)

__device__ __forceinline__ unsigned short bf16_rne(float f){
  unsigned int u = __builtin_bit_cast(unsigned int, f);
  u += 0x7FFFu + ((u >> 16) & 1u);
  return (unsigned short)(u >> 16);
}
__device__ __forceinline__ float bf2f(unsigned short h){
  unsigned int u = ((unsigned int)h) << 16;
  return __builtin_bit_cast(float, u);
}
__device__ __forceinline__ void gload16(const void* g, void* l){
  __builtin_amdgcn_global_load_lds(
      (const __attribute__((address_space(1))) unsigned int*)g,
      (__attribute__((address_space(3))) unsigned int*)l, 16, 0, 0);
}
// m204 bijective XCD swizzle (works for any nwg)
__device__ __forceinline__ int xcd_swizzle(int orig, int nwg){
  int q = nwg >> 3, r = nwg & 7;
  int xcd = orig & 7, loc = orig >> 3;
  return (xcd < r ? xcd*(q+1) : r*(q+1) + (xcd-r)*q) + loc;
}

// ---------------------------------------------------------------------------
// W (K x N) fp32 row-major -> Wt (N x K) bf16 row-major. 64x64 tiles.
// ---------------------------------------------------------------------------
__global__ __launch_bounds__(256) void transpose_w(
    const float* __restrict__ W, unsigned short* __restrict__ Wt, int K, int N)
{
  __shared__ unsigned short t[64][66];
  int n0 = blockIdx.x*64, k0 = blockIdx.y*64;
  int tid = threadIdx.x;
  int kr = tid >> 4, nc = (tid & 15) * 4;
  #pragma unroll
  for (int pass=0; pass<4; pass++){
    int k = kr + pass*16;
    float4 v = *(const float4*)(W + (size_t)(k0+k)*N + n0 + nc);
    ushort4v o;
    o.x = bf16_rne(v.x); o.y = bf16_rne(v.y);
    o.z = bf16_rne(v.z); o.w = bf16_rne(v.w);
    *(ushort4v*)&t[k][nc] = o;
  }
  __syncthreads();
  int nr = tid >> 3, kc = (tid & 7) * 8;
  #pragma unroll
  for (int pass=0; pass<2; pass++){
    int n = nr + pass*32;
    unsigned short buf[8];
    #pragma unroll
    for (int j=0;j<8;j++) buf[j] = t[kc+j][n];
    *(short8*)(Wt + (size_t)(n0+n)*K + k0 + kc) = *(short8*)&buf[0];
  }
}

// ---------------------------------------------------------------------------
// mod-rmsnorm: out = bf16( x * rsqrt(mean(x^2)+1e-6) * (1+scale[col]) )
// ---------------------------------------------------------------------------
template<int D>
__global__ __launch_bounds__(256) void modnorm(
    const float* __restrict__ X, const float* __restrict__ scale,
    unsigned short* __restrict__ out)
{
  int row = blockIdx.x;
  const float4* xv = (const float4*)(X + (size_t)row*D);
  float ss = 0.f;
  for (int i = threadIdx.x; i < D/4; i += 256){
    float4 v = xv[i];
    ss += v.x*v.x + v.y*v.y + v.z*v.z + v.w*v.w;
  }
  #pragma unroll
  for (int d=1; d<64; d<<=1) ss += __shfl_xor(ss, d);
  __shared__ float wsum[4];
  if ((threadIdx.x & 63) == 0) wsum[threadIdx.x >> 6] = ss;
  __syncthreads();
  float tot = wsum[0] + wsum[1] + wsum[2] + wsum[3];
  float rn = rsqrtf(tot*(1.0f/(float)D) + 1e-6f);
  const float4* sv = (const float4*)scale;
  for (int i = threadIdx.x; i < D/4; i += 256){
    float4 v = xv[i]; float4 s4 = sv[i];
    ushort4v o;
    o.x = bf16_rne(v.x*rn*(1.f+s4.x));
    o.y = bf16_rne(v.y*rn*(1.f+s4.y));
    o.z = bf16_rne(v.z*rn*(1.f+s4.z));
    o.w = bf16_rne(v.w*rn*(1.f+s4.w));
    *(ushort4v*)(out + (size_t)row*D + i*4) = o;
  }
}

// ---------------------------------------------------------------------------
// 256^2-tile 8-phase GEMM, dual-problem: grid rows [0,gy-1) = problem X
// (M=256*(gy-1), strides K), row gy-1 = problem Y (M=256, strides K2).
// bf16 out + bias for both. K, K2 % 128 == 0.
// ---------------------------------------------------------------------------
__global__ __launch_bounds__(512, 2) void gemm_8ph(
    const unsigned short* __restrict__ A, const unsigned short* __restrict__ BT,
    const float* __restrict__ bias, unsigned short* __restrict__ C,
    int K, int ldc,
    const unsigned short* __restrict__ A2, const unsigned short* __restrict__ BT2,
    const float* __restrict__ bias2, unsigned short* __restrict__ C2, int K2)
{
  __shared__ unsigned short lds[8][8192];

  int tid = threadIdx.x, wave = tid>>6, lane = tid&63;
  int l16 = lane&15, g = lane>>4;
  int wr = wave>>2, wc = wave&3;

  int nwg = gridDim.x*gridDim.y;
  int orig = blockIdx.y*gridDim.x + blockIdx.x;
  int neo = xcd_swizzle(orig, nwg);
  int bx = neo / gridDim.y, by = neo % gridDim.y;

  bool ybl = (by == (int)gridDim.y - 1);
  const unsigned short* Ap  = ybl ? A2 : A;
  const unsigned short* Bp  = ybl ? BT2 : BT;
  const float* bp           = ybl ? bias2 : bias;
  unsigned short* Cp        = ybl ? C2 : C;
  int Kl = ybl ? K2 : K;
  int bm = ybl ? 0 : by*256;
  int bn = bx*256;

  const int NT = Kl >> 6;

  auto STAGE = [&](int t, int op, int half, int b){
    int tc = t < NT ? t : NT-1;
    const unsigned short* src = op ? Bp : Ap;
    int base_row = (op ? bn : bm) + half*128;
    int k0 = tc << 6;
    #pragma unroll
    for (int j=0;j<2;j++){
      int o = (j*8 + wave)*1024 + lane*16;
      int row = o>>7, slot = (o>>4)&7;
      int sk = (slot ^ (row&7))*8;
      gload16(src + (size_t)(base_row+row)*Kl + k0 + sk,
              (char*)&lds[(b<<2)|(op<<1)|half][0] + (j*8+wave)*1024);
    }
  };

  short8 afr[4], bfr[8];
  auto LDA = [&](int b, int p){
    const char* basep = (const char*)&lds[(b<<2)|wr][0];
    #pragma unroll
    for (int mm=0;mm<2;mm++){
      int row = (p*2+mm)*16 + l16;
      #pragma unroll
      for (int kk=0;kk<2;kk++)
        afr[mm*2+kk] = *(const short8*)(basep + row*128 + (((kk*4+g) ^ (row&7))<<4));
    }
  };
  auto LDB = [&](int b){
    const char* basep = (const char*)&lds[(b<<2)|2|(wc>>1)][0];
    int rbase = (wc&1)*64;
    #pragma unroll
    for (int n=0;n<4;n++){
      int row = rbase + n*16 + l16;
      #pragma unroll
      for (int kk=0;kk<2;kk++)
        bfr[n*2+kk] = *(const short8*)(basep + row*128 + (((kk*4+g) ^ (row&7))<<4));
    }
  };

  f32x4 acc[8][4] = {};

  STAGE(0,1,0,0); STAGE(0,1,1,0); STAGE(0,0,0,0); STAGE(0,0,1,0);
  STAGE(1,1,0,1); STAGE(1,1,1,1); STAGE(1,0,0,1);
  asm volatile("s_waitcnt vmcnt(6)" ::: "memory");
  __builtin_amdgcn_s_barrier();

  int NIT = NT >> 1;
  for (int i=0;i<NIT;i++){
    int T = 2*i;
    #pragma unroll
    for (int p=0;p<4;p++){
      if (p==0) LDB(0);
      LDA(0, p);
      if (p==0)      STAGE(T+1,0,1,1);
      else if (p==1) STAGE(T+2,1,0,0);
      else if (p==2) STAGE(T+2,1,1,0);
      else           STAGE(T+2,0,0,0);
      if (p==0) asm volatile("s_waitcnt lgkmcnt(8)" ::: "memory");
      __builtin_amdgcn_s_barrier();
      asm volatile("s_waitcnt lgkmcnt(0)" ::: "memory");
      __builtin_amdgcn_sched_barrier(0);
      __builtin_amdgcn_s_setprio(1);
      #pragma unroll
      for (int mm=0;mm<2;mm++)
        #pragma unroll
        for (int n=0;n<4;n++)
          #pragma unroll
          for (int kk=0;kk<2;kk++)
            acc[p*2+mm][n] = MFMA_BF16(afr[mm*2+kk], bfr[n*2+kk], acc[p*2+mm][n]);
      __builtin_amdgcn_s_setprio(0);
      if (p==3) asm volatile("s_waitcnt vmcnt(6)" ::: "memory");
      __builtin_amdgcn_s_barrier();
    }
    #pragma unroll
    for (int p=0;p<4;p++){
      if (p==0) LDB(1);
      LDA(1, p);
      if (p==0)      STAGE(T+2,0,1,0);
      else if (p==1) STAGE(T+3,1,0,1);
      else if (p==2) STAGE(T+3,1,1,1);
      else           STAGE(T+3,0,0,1);
      if (p==0) asm volatile("s_waitcnt lgkmcnt(8)" ::: "memory");
      __builtin_amdgcn_s_barrier();
      asm volatile("s_waitcnt lgkmcnt(0)" ::: "memory");
      __builtin_amdgcn_sched_barrier(0);
      __builtin_amdgcn_s_setprio(1);
      #pragma unroll
      for (int mm=0;mm<2;mm++)
        #pragma unroll
        for (int n=0;n<4;n++)
          #pragma unroll
          for (int kk=0;kk<2;kk++)
            acc[p*2+mm][n] = MFMA_BF16(afr[mm*2+kk], bfr[n*2+kk], acc[p*2+mm][n]);
      __builtin_amdgcn_s_setprio(0);
      if (p==3) asm volatile("s_waitcnt vmcnt(6)" ::: "memory");
      __builtin_amdgcn_s_barrier();
    }
  }

  #pragma unroll
  for (int n=0;n<4;n++){
    int col = bn + wc*64 + n*16 + l16;
    float bv = bp[col];
    #pragma unroll
    for (int m=0;m<8;m++){
      int row0 = bm + wr*128 + m*16 + g*4;
      #pragma unroll
      for (int r=0;r<4;r++)
        Cp[(size_t)(row0+r)*ldc + col] = bf16_rne(acc[m][n][r] + bv);
    }
  }
}

// ---------------------------------------------------------------------------
// 128^2-tile dual proj GEMM (m97 structure): grid rows [0,gy-1) = proj_x
// (M=128*(gy-1), N=128*gridDim.x), row gy-1 = proj_y (M=256, N=1536, via
// sub-index bx). K=3072 both; fp32 out + bias.
// ---------------------------------------------------------------------------
__global__ __launch_bounds__(256, 3) void gemm_proj(
    const unsigned short* __restrict__ A, const unsigned short* __restrict__ BT,
    const float* __restrict__ bias, float* __restrict__ C, int ldc,
    const unsigned short* __restrict__ A2, const unsigned short* __restrict__ BT2,
    const float* __restrict__ bias2, float* __restrict__ C2, int ldc2)
{
  __shared__ unsigned short lA[128*32];
  __shared__ unsigned short lB[128*32];
  int tid = threadIdx.x, wave = tid>>6, lane = tid&63;
  int l16 = lane&15, g = lane>>4;
  int wr = wave>>1, wc = wave&1;

  const int K = 3072;
  int nwg = gridDim.x*gridDim.y;
  int orig = blockIdx.y*gridDim.x + blockIdx.x;
  int neo = xcd_swizzle(orig, nwg);
  int bx = neo / gridDim.y, by = neo % gridDim.y;

  bool ybl = (by == (int)gridDim.y - 1);
  const unsigned short* Ap = ybl ? A2 : A;
  const unsigned short* Bp = ybl ? BT2 : BT;
  const float* bp          = ybl ? bias2 : bias;
  float* Cp                = ybl ? C2 : C;
  int ldcl                 = ybl ? ldc2 : ldc;
  int bm, bn;
  if (ybl){ bm = (bx & 1)*128; bn = (bx >> 1)*128; }
  else    { bm = by*128;       bn = bx*128; }

  f32x4 acc[4][4] = {};

  for (int k0 = 0; k0 < K; k0 += 32){
    #pragma unroll
    for (int i=0;i<2;i++){
      int off = i*4096 + wave*1024 + lane*16;
      int row = off>>6;
      int sp  = (off>>4)&3;
      int sk  = (sp ^ (row&3))*8;
      gload16(Ap + (size_t)(bm+row)*K + k0 + sk, (char*)lA + i*4096 + wave*1024);
    }
    #pragma unroll
    for (int i=0;i<2;i++){
      int off = i*4096 + wave*1024 + lane*16;
      int row = off>>6;
      int sp  = (off>>4)&3;
      int sk  = (sp ^ (row&3))*8;
      gload16(Bp + (size_t)(bn+row)*K + k0 + sk, (char*)lB + i*4096 + wave*1024);
    }
    __syncthreads();

    short8 a[4], b[4];
    #pragma unroll
    for (int m=0;m<4;m++){
      int row = wr*64 + m*16 + l16;
      int slot = g ^ (row&3);
      a[m] = *(const short8*)((const char*)lA + row*64 + slot*16);
    }
    #pragma unroll
    for (int n=0;n<4;n++){
      int row = wc*64 + n*16 + l16;
      int slot = g ^ (row&3);
      b[n] = *(const short8*)((const char*)lB + row*64 + slot*16);
    }
    __builtin_amdgcn_s_setprio(1);
    #pragma unroll
    for (int m=0;m<4;m++)
      #pragma unroll
      for (int n=0;n<4;n++)
        acc[m][n] = MFMA_BF16(a[m], b[n], acc[m][n]);
    __builtin_amdgcn_s_setprio(0);
    __syncthreads();
  }

  #pragma unroll
  for (int n=0;n<4;n++){
    int col = bn + wc*64 + n*16 + l16;
    float bv = bp[col];
    #pragma unroll
    for (int m=0;m<4;m++){
      int row0 = bm + wr*64 + m*16 + g*4;
      #pragma unroll
      for (int r=0;r<4;r++)
        Cp[(size_t)(row0+r)*ldcl + col] = acc[m][n][r] + bv;
    }
  }
}

// ---------------------------------------------------------------------------
// qk fixup: 4 waves/block, one (token,head) per wave.
// ---------------------------------------------------------------------------
__global__ __launch_bounds__(256) void fixup_qk(
    const unsigned short* __restrict__ QKV,
    const float* __restrict__ cosT, const float* __restrict__ sinT,
    const float* __restrict__ wqx, const float* __restrict__ wkx,
    const float* __restrict__ wqy, const float* __restrict__ wky,
    unsigned short* __restrict__ Qo, unsigned short* __restrict__ Ko)
{
  int wave = threadIdx.x >> 6, lane = threadIdx.x & 63;
  int bid = blockIdx.x*4 + wave;
  int t = bid / NH, h = bid % NH;
  bool isx = (t < 3072);

  const unsigned short* base = QKV + (size_t)t*9216 + h*128;
  unsigned int qraw = *(const unsigned int*)(base + 2*lane);
  unsigned int kraw = *(const unsigned int*)(base + 3072 + 2*lane);
  float q0 = bf2f((unsigned short)(qraw & 0xffff)), q1 = bf2f((unsigned short)(qraw >> 16));
  float k0 = bf2f((unsigned short)(kraw & 0xffff)), k1 = bf2f((unsigned short)(kraw >> 16));

  float sq = q0*q0 + q1*q1, sk = k0*k0 + k1*k1;
  #pragma unroll
  for (int d=1; d<64; d<<=1){ sq += __shfl_xor(sq, d); sk += __shfl_xor(sk, d); }
  float rq = rsqrtf(sq*(1.0f/128.0f) + 1e-5f);
  float rk = rsqrtf(sk*(1.0f/128.0f) + 1e-5f);

  const float* wq = isx ? wqx : wqy;
  const float* wk = isx ? wkx : wky;
  float a0 = q0*rq*wq[2*lane], a1 = q1*rq*wq[2*lane+1];
  float b0 = k0*rk*wk[2*lane], b1 = k1*rk*wk[2*lane+1];

  if (isx){
    size_t ci = ((size_t)t*NH + h)*64 + lane;
    float c = cosT[ci], s = sinT[ci];
    float t0 = a0*c - a1*s, t1 = a0*s + a1*c; a0 = t0; a1 = t1;
    t0 = b0*c - b1*s; t1 = b0*s + b1*c; b0 = t0; b1 = t1;
  }
  size_t oi = ((size_t)h*SPAD + t)*128 + 2*lane;
  *(unsigned int*)(Qo + oi) = (unsigned int)bf16_rne(a0) | ((unsigned int)bf16_rne(a1) << 16);
  *(unsigned int*)(Ko + oi) = (unsigned int)bf16_rne(b0) | ((unsigned int)bf16_rne(b1) << 16);
}

// ---------------------------------------------------------------------------
// V transpose: qkv v-section (token,128) -> VT (H, 128, SPAD) bf16
// ---------------------------------------------------------------------------
__global__ __launch_bounds__(256) void v_transpose(
    const unsigned short* __restrict__ QKV, unsigned short* __restrict__ VT)
{
  __shared__ unsigned short t[64][136];
  int h = blockIdx.x;
  int t0 = blockIdx.y*64;
  int tid = threadIdx.x;
  #pragma unroll
  for (int it=0; it<4; it++){
    int chunk = it*256 + tid;
    int r = chunk >> 4, c = chunk & 15;
    short8 v = *(const short8*)(QKV + (size_t)(t0 + r)*9216 + 6144 + h*128 + c*8);
    *(short8*)&t[r][c*8] = v;
  }
  __syncthreads();
  int d = tid >> 1, half = tid & 1;
  size_t ob = (size_t)(h*128 + d)*SPAD + t0 + half*32;
  #pragma unroll
  for (int j=0;j<32;j+=2){
    unsigned int v = (unsigned int)t[half*32 + j][d] | ((unsigned int)t[half*32 + j + 1][d] << 16);
    *(unsigned int*)(VT + ob + j) = v;
  }
}

// ---------------------------------------------------------------------------
// Flash attention, fixed-max softmax. QBLK=128 (4 waves x 32 q-rows),
// KVBLK=32, K/V double-buffered (counted vmcnt(4), raw s_barrier).
// ---------------------------------------------------------------------------
__global__ __launch_bounds__(256, 3) void attn_fwd(
    const unsigned short* __restrict__ Q, const unsigned short* __restrict__ Kb,
    const unsigned short* __restrict__ VT, unsigned short* __restrict__ O)
{
  __shared__ unsigned short lK[2][32*128];   // 2 x 8KB
  __shared__ unsigned short lV[2][128*32];   // 2 x 8KB
  __shared__ unsigned short lP[4][32*72];    // 18KB

  int tid = threadIdx.x, wave = tid>>6, lane = tid&63;
  int l16 = lane&15, g = lane>>4;
  int h = blockIdx.x, qt = blockIdx.y;
  int q0 = qt*128 + wave*32;

  auto STAGE = [&](int kt, int b){
    #pragma unroll
    for (int i=0;i<2;i++){
      int off = (i*4 + wave)*1024 + lane*16;
      int row = off>>8;
      int sp  = (off>>4)&15;
      int ssp = sp ^ (row&7);
      gload16(Kb + ((size_t)h*SPAD + kt*32 + row)*128 + ssp*8,
              (char*)&lK[b][0] + (i*4 + wave)*1024);
    }
    #pragma unroll
    for (int i=0;i<2;i++){
      int off = (i*4 + wave)*1024 + lane*16;
      int row = off>>6;
      int sp  = (off>>4)&3;
      int ssp = sp ^ ((row>>1)&3);            // 2-way-free swizzle
      gload16(VT + ((size_t)(h*128 + row))*SPAD + kt*32 + ssp*8,
              (char*)&lV[b][0] + (i*4 + wave)*1024);
    }
  };

  short8 qf[2][4];
  const unsigned short* qbase = Q + (size_t)h*SPAD*128;
  #pragma unroll
  for (int mt=0;mt<2;mt++){
    int row = q0 + mt*16 + l16;
    #pragma unroll
    for (int ks=0;ks<4;ks++)
      qf[mt][ks] = *(const short8*)(qbase + (size_t)row*128 + ks*32 + g*8);
  }

  f32x4 oacc[2][8] = {};
  float lsum[2][4] = {};

  unsigned short* lPw = &lP[wave][0];
  const float sc2 = 0.08838834764831845f * 1.4426950408889634f; // sc*log2(e)
  const float C2  = -12.0f * 1.4426950408889634f;

  STAGE(0, 0);

  for (int kt=0; kt<104; kt++){
    int cur = kt & 1;
    int nxt = (kt+1 < 104) ? kt+1 : 103;
    STAGE(nxt, cur ^ 1);
    asm volatile("s_waitcnt vmcnt(4)" ::: "memory");
    __builtin_amdgcn_s_barrier();

    const char* lKc = (const char*)&lK[cur][0];
    const char* lVc = (const char*)&lV[cur][0];

    // ---- QK^T (32 keys: nt = 0,1) ----
    f32x4 s[2][2] = {};
    #pragma unroll
    for (int ks=0;ks<4;ks++){
      short8 bfrag[2];
      #pragma unroll
      for (int nt=0;nt<2;nt++){
        int row = nt*16 + l16;
        int slot = (ks*4 + g) ^ (row&7);
        bfrag[nt] = *(const short8*)(lKc + row*256 + slot*16);
      }
      __builtin_amdgcn_s_setprio(1);
      #pragma unroll
      for (int mt=0;mt<2;mt++)
        #pragma unroll
        for (int nt=0;nt<2;nt++)
          s[mt][nt] = MFMA_BF16(qf[mt][ks], bfrag[nt], s[mt][nt]);
      __builtin_amdgcn_s_setprio(0);
    }

    // ---- fixed-max softmax: p = exp2(s*sc2 + C2) == exp(s*sc - 12) ----
    bool edge = (kt >= 102);
    #pragma unroll
    for (int mt=0;mt<2;mt++)
      #pragma unroll
      for (int nt=0;nt<2;nt++){
        #pragma unroll
        for (int r=0;r<4;r++){
          float p = __builtin_amdgcn_exp2f(fmaf(s[mt][nt][r], sc2, C2));
          if (edge){
            int key = kt*32 + nt*16 + l16;
            if (key >= SVAL) p = 0.f;
          }
          lsum[mt][r] += p;
          lPw[(mt*16 + g*4 + r)*72 + nt*16 + l16] = bf16_rne(p);
        }
      }

    asm volatile("s_waitcnt lgkmcnt(0)" ::: "memory");

    // ---- PV (single 32-key slab) ----
    {
      short8 pa[2];
      #pragma unroll
      for (int mt=0;mt<2;mt++)
        pa[mt] = *(const short8*)(lPw + (mt*16 + l16)*72 + g*8);
      __builtin_amdgcn_s_setprio(1);
      #pragma unroll
      for (int dt=0;dt<8;dt++){
        int row = dt*16 + l16;
        int slot = g ^ ((row>>1)&3);
        short8 vb = *(const short8*)(lVc + row*64 + slot*16);
        #pragma unroll
        for (int mt=0;mt<2;mt++)
          oacc[mt][dt] = MFMA_BF16(pa[mt], vb, oacc[mt][dt]);
      }
      __builtin_amdgcn_s_setprio(0);
    }
    __builtin_amdgcn_s_barrier();
  }

  #pragma unroll
  for (int mt=0;mt<2;mt++){
    float inv[4];
    #pragma unroll
    for (int r=0;r<4;r++){
      float v = lsum[mt][r];
      v += __shfl_xor(v, 1); v += __shfl_xor(v, 2);
      v += __shfl_xor(v, 4); v += __shfl_xor(v, 8);
      inv[r] = 1.0f / v;
    }
    #pragma unroll
    for (int dt=0;dt<8;dt++)
      #pragma unroll
      for (int r=0;r<4;r++){
        int row = q0 + mt*16 + g*4 + r;
        if (row < SVAL)
          O[(size_t)row*3072 + h*128 + dt*16 + l16] = bf16_rne(oacc[mt][dt][r]*inv[r]);
      }
  }
}

// ---------------------------------------------------------------------------
// Workspace layout (bytes).
// ---------------------------------------------------------------------------
static const size_t OFF_WT_QKV_X  = 0;                 // 9216*3072*2
static const size_t OFF_WT_QKV_Y  = 56623104;          // 9216*1536*2
static const size_t OFF_WT_PROJ_X = 84934656;          // 3072*3072*2
static const size_t OFF_WT_PROJ_Y = 103809024;         // 1536*3072*2
static const size_t OFF_XM        = 113246208;         // 3072*3072*2
static const size_t OFF_YM        = 132120576;         // 256*1536*2
static const size_t OFF_QKV       = 132907008;         // 3328*9216*2
static const size_t OFF_Q         = 194248704;         // 24*3328*128*2
static const size_t OFF_K         = 214695936;
static const size_t OFF_VT        = 235143168;
static const size_t WS_NEEDED     = 255590400;
static const size_t OFF_AO        = 0;                 // 3328*3072*2 (alias Wt_qkv_x)

extern "C" void kernel_launch(void* const* d_in, const int* in_sizes, int n_in,
                              void* d_out, int out_size, void* d_ws, size_t ws_size,
                              hipStream_t stream) {
  if (ws_size < WS_NEEDED) return;

  const float* x        = (const float*)d_in[0];
  const float* y        = (const float*)d_in[1];
  const float* scale_x  = (const float*)d_in[2];
  const float* scale_y  = (const float*)d_in[3];
  const float* rope_cos = (const float*)d_in[4];
  const float* rope_sin = (const float*)d_in[5];
  const float* W_qkv_x  = (const float*)d_in[6];
  const float* b_qkv_x  = (const float*)d_in[7];
  const float* W_qkv_y  = (const float*)d_in[8];
  const float* b_qkv_y  = (const float*)d_in[9];
  const float* w_qn_x   = (const float*)d_in[10];
  const float* w_kn_x   = (const float*)d_in[11];
  const float* w_qn_y   = (const float*)d_in[12];
  const float* w_kn_y   = (const float*)d_in[13];
  const float* W_proj_x = (const float*)d_in[14];
  const float* b_proj_x = (const float*)d_in[15];
  const float* W_proj_y = (const float*)d_in[16];
  const float* b_proj_y = (const float*)d_in[17];

  float* out_x = (float*)d_out;
  float* out_y = out_x + (size_t)3072*3072;

  char* ws = (char*)d_ws;
  unsigned short* Wt_qkv_x  = (unsigned short*)(ws + OFF_WT_QKV_X);
  unsigned short* Wt_qkv_y  = (unsigned short*)(ws + OFF_WT_QKV_Y);
  unsigned short* Wt_proj_x = (unsigned short*)(ws + OFF_WT_PROJ_X);
  unsigned short* Wt_proj_y = (unsigned short*)(ws + OFF_WT_PROJ_Y);
  unsigned short* xm        = (unsigned short*)(ws + OFF_XM);
  unsigned short* ym        = (unsigned short*)(ws + OFF_YM);
  unsigned short* qkv       = (unsigned short*)(ws + OFF_QKV);
  unsigned short* Qb        = (unsigned short*)(ws + OFF_Q);
  unsigned short* Kb        = (unsigned short*)(ws + OFF_K);
  unsigned short* VTb       = (unsigned short*)(ws + OFF_VT);
  unsigned short* attnout   = (unsigned short*)(ws + OFF_AO);

  transpose_w<<<dim3(9216/64, 3072/64), 256, 0, stream>>>(W_qkv_x,  Wt_qkv_x,  3072, 9216);
  transpose_w<<<dim3(9216/64, 1536/64), 256, 0, stream>>>(W_qkv_y,  Wt_qkv_y,  1536, 9216);
  transpose_w<<<dim3(3072/64, 3072/64), 256, 0, stream>>>(W_proj_x, Wt_proj_x, 3072, 3072);
  transpose_w<<<dim3(1536/64, 3072/64), 256, 0, stream>>>(W_proj_y, Wt_proj_y, 3072, 1536);

  modnorm<3072><<<3072, 256, 0, stream>>>(x, scale_x, xm);
  modnorm<1536><<<256,  256, 0, stream>>>(y, scale_y, ym);

  // qkv_x (3072x9216x3072) + qkv_y (256x9216x1536) fused: grid row 12 = y
  gemm_8ph<<<dim3(36, 13), 512, 0, stream>>>(
      xm, Wt_qkv_x, b_qkv_x, qkv, 3072, 9216,
      ym, Wt_qkv_y, b_qkv_y, qkv + (size_t)3072*9216, 1536);

  fixup_qk<<<SVAL*NH/4, 256, 0, stream>>>(qkv, rope_cos, rope_sin,
                                          w_qn_x, w_kn_x, w_qn_y, w_kn_y, Qb, Kb);
  v_transpose<<<dim3(NH, SPAD/64), 256, 0, stream>>>(qkv, VTb);

  (void)hipMemsetAsync(attnout + (size_t)SVAL*3072, 0,
                       (size_t)(SPAD - SVAL)*3072*2, stream);

  attn_fwd<<<dim3(NH, SPAD/128), 256, 0, stream>>>(Qb, Kb, VTb, attnout);

  // proj_x (3072x3072x3072) + proj_y (256x1536x3072) fused: grid row 24 = y
  gemm_proj<<<dim3(24, 25), 256, 0, stream>>>(
      attnout, Wt_proj_x, b_proj_x, out_x, 3072,
      attnout + (size_t)3072*3072, Wt_proj_y, b_proj_y, out_y, 1536);
}

// Round 11
// 539.347 us; speedup vs baseline: 1.1692x; 1.0233x over previous
//
#include <hip/hip_runtime.h>

// ---------------------------------------------------------------------------
// AsymmetricAttention fused pipeline for MI355X (gfx950), bf16 MFMA throughout.
// R11: attn XCD-head-grouping (each XCD owns ~3 heads -> K/V L2-resident for
//      staging); 4 transpose_w launches fused into 1; v_transpose fused into
//      fixup_qk. GEMMs unchanged from R10.
// ---------------------------------------------------------------------------

typedef short short8 __attribute__((ext_vector_type(8)));
typedef float f32x4 __attribute__((ext_vector_type(4)));
typedef unsigned short ushort4v __attribute__((ext_vector_type(4)));

#define MFMA_BF16(a,b,c) __builtin_amdgcn_mfma_f32_16x16x32_bf16((a),(b),(c),0,0,0)

#define NH 24
#define SPAD 3328   // padded token count (104*32)
#define SVAL 3272   // valid tokens (3072 x + 200 y)

__device__ __forceinline__ unsigned short bf16_rne(float f){
  unsigned int u = __builtin_bit_cast(unsigned int, f);
  u += 0x7FFFu + ((u >> 16) & 1u);
  return (unsigned short)(u >> 16);
}
__device__ __forceinline__ float bf2f(unsigned short h){
  unsigned int u = ((unsigned int)h) << 16;
  return __builtin_bit_cast(float, u);
}
__device__ __forceinline__ void gload16(const void* g, void* l){
  __builtin_amdgcn_global_load_lds(
      (const __attribute__((address_space(1))) unsigned int*)g,
      (__attribute__((address_space(3))) unsigned int*)l, 16, 0, 0);
}
// m204 bijective XCD swizzle (works for any nwg)
__device__ __forceinline__ int xcd_swizzle(int orig, int nwg){
  int q = nwg >> 3, r = nwg & 7;
  int xcd = orig & 7, loc = orig >> 3;
  return (xcd < r ? xcd*(q+1) : r*(q+1) + (xcd-r)*q) + loc;
}

// ---------------------------------------------------------------------------
// Fused W transposes: all four (K x N) fp32 -> (N x K) bf16, 64x64 tiles,
// one dispatch, segment decode by flat block id.
// ---------------------------------------------------------------------------
__global__ __launch_bounds__(256) void transpose_all(
    const float* __restrict__ W0, unsigned short* __restrict__ T0,   // 3072x9216
    const float* __restrict__ W1, unsigned short* __restrict__ T1,   // 1536x9216
    const float* __restrict__ W2, unsigned short* __restrict__ T2,   // 3072x3072
    const float* __restrict__ W3, unsigned short* __restrict__ T3)   // 3072x1536
{
  __shared__ unsigned short t[64][66];
  int f = blockIdx.x;
  const float* W; unsigned short* Wt; int K, N, lid;
  if      (f < 6912)             { W=W0; Wt=T0; K=3072; N=9216; lid=f; }
  else if (f < 6912+3456)        { W=W1; Wt=T1; K=1536; N=9216; lid=f-6912; }
  else if (f < 6912+3456+2304)   { W=W2; Wt=T2; K=3072; N=3072; lid=f-10368; }
  else                           { W=W3; Wt=T3; K=3072; N=1536; lid=f-12672; }
  int ntiles = N >> 6;
  int n0 = (lid % ntiles)*64, k0 = (lid / ntiles)*64;

  int tid = threadIdx.x;
  int kr = tid >> 4, nc = (tid & 15) * 4;
  #pragma unroll
  for (int pass=0; pass<4; pass++){
    int k = kr + pass*16;
    float4 v = *(const float4*)(W + (size_t)(k0+k)*N + n0 + nc);
    ushort4v o;
    o.x = bf16_rne(v.x); o.y = bf16_rne(v.y);
    o.z = bf16_rne(v.z); o.w = bf16_rne(v.w);
    *(ushort4v*)&t[k][nc] = o;
  }
  __syncthreads();
  int nr = tid >> 3, kc = (tid & 7) * 8;
  #pragma unroll
  for (int pass=0; pass<2; pass++){
    int n = nr + pass*32;
    unsigned short buf[8];
    #pragma unroll
    for (int j=0;j<8;j++) buf[j] = t[kc+j][n];
    *(short8*)(Wt + (size_t)(n0+n)*K + k0 + kc) = *(short8*)&buf[0];
  }
}

// ---------------------------------------------------------------------------
// mod-rmsnorm: out = bf16( x * rsqrt(mean(x^2)+1e-6) * (1+scale[col]) )
// ---------------------------------------------------------------------------
template<int D>
__global__ __launch_bounds__(256) void modnorm(
    const float* __restrict__ X, const float* __restrict__ scale,
    unsigned short* __restrict__ out)
{
  int row = blockIdx.x;
  const float4* xv = (const float4*)(X + (size_t)row*D);
  float ss = 0.f;
  for (int i = threadIdx.x; i < D/4; i += 256){
    float4 v = xv[i];
    ss += v.x*v.x + v.y*v.y + v.z*v.z + v.w*v.w;
  }
  #pragma unroll
  for (int d=1; d<64; d<<=1) ss += __shfl_xor(ss, d);
  __shared__ float wsum[4];
  if ((threadIdx.x & 63) == 0) wsum[threadIdx.x >> 6] = ss;
  __syncthreads();
  float tot = wsum[0] + wsum[1] + wsum[2] + wsum[3];
  float rn = rsqrtf(tot*(1.0f/(float)D) + 1e-6f);
  const float4* sv = (const float4*)scale;
  for (int i = threadIdx.x; i < D/4; i += 256){
    float4 v = xv[i]; float4 s4 = sv[i];
    ushort4v o;
    o.x = bf16_rne(v.x*rn*(1.f+s4.x));
    o.y = bf16_rne(v.y*rn*(1.f+s4.y));
    o.z = bf16_rne(v.z*rn*(1.f+s4.z));
    o.w = bf16_rne(v.w*rn*(1.f+s4.w));
    *(ushort4v*)(out + (size_t)row*D + i*4) = o;
  }
}

// ---------------------------------------------------------------------------
// 256^2-tile 8-phase GEMM, dual-problem (unchanged from R10).
// ---------------------------------------------------------------------------
__global__ __launch_bounds__(512, 2) void gemm_8ph(
    const unsigned short* __restrict__ A, const unsigned short* __restrict__ BT,
    const float* __restrict__ bias, unsigned short* __restrict__ C,
    int K, int ldc,
    const unsigned short* __restrict__ A2, const unsigned short* __restrict__ BT2,
    const float* __restrict__ bias2, unsigned short* __restrict__ C2, int K2)
{
  __shared__ unsigned short lds[8][8192];

  int tid = threadIdx.x, wave = tid>>6, lane = tid&63;
  int l16 = lane&15, g = lane>>4;
  int wr = wave>>2, wc = wave&3;

  int nwg = gridDim.x*gridDim.y;
  int orig = blockIdx.y*gridDim.x + blockIdx.x;
  int neo = xcd_swizzle(orig, nwg);
  int bx = neo / gridDim.y, by = neo % gridDim.y;

  bool ybl = (by == (int)gridDim.y - 1);
  const unsigned short* Ap  = ybl ? A2 : A;
  const unsigned short* Bp  = ybl ? BT2 : BT;
  const float* bp           = ybl ? bias2 : bias;
  unsigned short* Cp        = ybl ? C2 : C;
  int Kl = ybl ? K2 : K;
  int bm = ybl ? 0 : by*256;
  int bn = bx*256;

  const int NT = Kl >> 6;

  auto STAGE = [&](int t, int op, int half, int b){
    int tc = t < NT ? t : NT-1;
    const unsigned short* src = op ? Bp : Ap;
    int base_row = (op ? bn : bm) + half*128;
    int k0 = tc << 6;
    #pragma unroll
    for (int j=0;j<2;j++){
      int o = (j*8 + wave)*1024 + lane*16;
      int row = o>>7, slot = (o>>4)&7;
      int sk = (slot ^ (row&7))*8;
      gload16(src + (size_t)(base_row+row)*Kl + k0 + sk,
              (char*)&lds[(b<<2)|(op<<1)|half][0] + (j*8+wave)*1024);
    }
  };

  short8 afr[4], bfr[8];
  auto LDA = [&](int b, int p){
    const char* basep = (const char*)&lds[(b<<2)|wr][0];
    #pragma unroll
    for (int mm=0;mm<2;mm++){
      int row = (p*2+mm)*16 + l16;
      #pragma unroll
      for (int kk=0;kk<2;kk++)
        afr[mm*2+kk] = *(const short8*)(basep + row*128 + (((kk*4+g) ^ (row&7))<<4));
    }
  };
  auto LDB = [&](int b){
    const char* basep = (const char*)&lds[(b<<2)|2|(wc>>1)][0];
    int rbase = (wc&1)*64;
    #pragma unroll
    for (int n=0;n<4;n++){
      int row = rbase + n*16 + l16;
      #pragma unroll
      for (int kk=0;kk<2;kk++)
        bfr[n*2+kk] = *(const short8*)(basep + row*128 + (((kk*4+g) ^ (row&7))<<4));
    }
  };

  f32x4 acc[8][4] = {};

  STAGE(0,1,0,0); STAGE(0,1,1,0); STAGE(0,0,0,0); STAGE(0,0,1,0);
  STAGE(1,1,0,1); STAGE(1,1,1,1); STAGE(1,0,0,1);
  asm volatile("s_waitcnt vmcnt(6)" ::: "memory");
  __builtin_amdgcn_s_barrier();

  int NIT = NT >> 1;
  for (int i=0;i<NIT;i++){
    int T = 2*i;
    #pragma unroll
    for (int p=0;p<4;p++){
      if (p==0) LDB(0);
      LDA(0, p);
      if (p==0)      STAGE(T+1,0,1,1);
      else if (p==1) STAGE(T+2,1,0,0);
      else if (p==2) STAGE(T+2,1,1,0);
      else           STAGE(T+2,0,0,0);
      if (p==0) asm volatile("s_waitcnt lgkmcnt(8)" ::: "memory");
      __builtin_amdgcn_s_barrier();
      asm volatile("s_waitcnt lgkmcnt(0)" ::: "memory");
      __builtin_amdgcn_sched_barrier(0);
      __builtin_amdgcn_s_setprio(1);
      #pragma unroll
      for (int mm=0;mm<2;mm++)
        #pragma unroll
        for (int n=0;n<4;n++)
          #pragma unroll
          for (int kk=0;kk<2;kk++)
            acc[p*2+mm][n] = MFMA_BF16(afr[mm*2+kk], bfr[n*2+kk], acc[p*2+mm][n]);
      __builtin_amdgcn_s_setprio(0);
      if (p==3) asm volatile("s_waitcnt vmcnt(6)" ::: "memory");
      __builtin_amdgcn_s_barrier();
    }
    #pragma unroll
    for (int p=0;p<4;p++){
      if (p==0) LDB(1);
      LDA(1, p);
      if (p==0)      STAGE(T+2,0,1,0);
      else if (p==1) STAGE(T+3,1,0,1);
      else if (p==2) STAGE(T+3,1,1,1);
      else           STAGE(T+3,0,0,1);
      if (p==0) asm volatile("s_waitcnt lgkmcnt(8)" ::: "memory");
      __builtin_amdgcn_s_barrier();
      asm volatile("s_waitcnt lgkmcnt(0)" ::: "memory");
      __builtin_amdgcn_sched_barrier(0);
      __builtin_amdgcn_s_setprio(1);
      #pragma unroll
      for (int mm=0;mm<2;mm++)
        #pragma unroll
        for (int n=0;n<4;n++)
          #pragma unroll
          for (int kk=0;kk<2;kk++)
            acc[p*2+mm][n] = MFMA_BF16(afr[mm*2+kk], bfr[n*2+kk], acc[p*2+mm][n]);
      __builtin_amdgcn_s_setprio(0);
      if (p==3) asm volatile("s_waitcnt vmcnt(6)" ::: "memory");
      __builtin_amdgcn_s_barrier();
    }
  }

  #pragma unroll
  for (int n=0;n<4;n++){
    int col = bn + wc*64 + n*16 + l16;
    float bv = bp[col];
    #pragma unroll
    for (int m=0;m<8;m++){
      int row0 = bm + wr*128 + m*16 + g*4;
      #pragma unroll
      for (int r=0;r<4;r++)
        Cp[(size_t)(row0+r)*ldc + col] = bf16_rne(acc[m][n][r] + bv);
    }
  }
}

// ---------------------------------------------------------------------------
// 128^2-tile dual proj GEMM (unchanged from R10).
// ---------------------------------------------------------------------------
__global__ __launch_bounds__(256, 3) void gemm_proj(
    const unsigned short* __restrict__ A, const unsigned short* __restrict__ BT,
    const float* __restrict__ bias, float* __restrict__ C, int ldc,
    const unsigned short* __restrict__ A2, const unsigned short* __restrict__ BT2,
    const float* __restrict__ bias2, float* __restrict__ C2, int ldc2)
{
  __shared__ unsigned short lA[128*32];
  __shared__ unsigned short lB[128*32];
  int tid = threadIdx.x, wave = tid>>6, lane = tid&63;
  int l16 = lane&15, g = lane>>4;
  int wr = wave>>1, wc = wave&1;

  const int K = 3072;
  int nwg = gridDim.x*gridDim.y;
  int orig = blockIdx.y*gridDim.x + blockIdx.x;
  int neo = xcd_swizzle(orig, nwg);
  int bx = neo / gridDim.y, by = neo % gridDim.y;

  bool ybl = (by == (int)gridDim.y - 1);
  const unsigned short* Ap = ybl ? A2 : A;
  const unsigned short* Bp = ybl ? BT2 : BT;
  const float* bp          = ybl ? bias2 : bias;
  float* Cp                = ybl ? C2 : C;
  int ldcl                 = ybl ? ldc2 : ldc;
  int bm, bn;
  if (ybl){ bm = (bx & 1)*128; bn = (bx >> 1)*128; }
  else    { bm = by*128;       bn = bx*128; }

  f32x4 acc[4][4] = {};

  for (int k0 = 0; k0 < K; k0 += 32){
    #pragma unroll
    for (int i=0;i<2;i++){
      int off = i*4096 + wave*1024 + lane*16;
      int row = off>>6;
      int sp  = (off>>4)&3;
      int sk  = (sp ^ (row&3))*8;
      gload16(Ap + (size_t)(bm+row)*K + k0 + sk, (char*)lA + i*4096 + wave*1024);
    }
    #pragma unroll
    for (int i=0;i<2;i++){
      int off = i*4096 + wave*1024 + lane*16;
      int row = off>>6;
      int sp  = (off>>4)&3;
      int sk  = (sp ^ (row&3))*8;
      gload16(Bp + (size_t)(bn+row)*K + k0 + sk, (char*)lB + i*4096 + wave*1024);
    }
    __syncthreads();

    short8 a[4], b[4];
    #pragma unroll
    for (int m=0;m<4;m++){
      int row = wr*64 + m*16 + l16;
      int slot = g ^ (row&3);
      a[m] = *(const short8*)((const char*)lA + row*64 + slot*16);
    }
    #pragma unroll
    for (int n=0;n<4;n++){
      int row = wc*64 + n*16 + l16;
      int slot = g ^ (row&3);
      b[n] = *(const short8*)((const char*)lB + row*64 + slot*16);
    }
    __builtin_amdgcn_s_setprio(1);
    #pragma unroll
    for (int m=0;m<4;m++)
      #pragma unroll
      for (int n=0;n<4;n++)
        acc[m][n] = MFMA_BF16(a[m], b[n], acc[m][n]);
    __builtin_amdgcn_s_setprio(0);
    __syncthreads();
  }

  #pragma unroll
  for (int n=0;n<4;n++){
    int col = bn + wc*64 + n*16 + l16;
    float bv = bp[col];
    #pragma unroll
    for (int m=0;m<4;m++){
      int row0 = bm + wr*64 + m*16 + g*4;
      #pragma unroll
      for (int r=0;r<4;r++)
        Cp[(size_t)(row0+r)*ldcl + col] = acc[m][n][r] + bv;
    }
  }
}

// ---------------------------------------------------------------------------
// Fused qk fixup + V transpose: blocks [0, 19632) do fixup (4 waves, one
// (token,head) each); blocks [19632, 20880) do V transpose.
// ---------------------------------------------------------------------------
__global__ __launch_bounds__(256) void fixup_qkv(
    const unsigned short* __restrict__ QKV,
    const float* __restrict__ cosT, const float* __restrict__ sinT,
    const float* __restrict__ wqx, const float* __restrict__ wkx,
    const float* __restrict__ wqy, const float* __restrict__ wky,
    unsigned short* __restrict__ Qo, unsigned short* __restrict__ Ko,
    unsigned short* __restrict__ VT)
{
  __shared__ unsigned short tt[64][136];
  if (blockIdx.x < 19632){
    int wave = threadIdx.x >> 6, lane = threadIdx.x & 63;
    int bid = blockIdx.x*4 + wave;
    int t = bid / NH, h = bid % NH;
    bool isx = (t < 3072);

    const unsigned short* base = QKV + (size_t)t*9216 + h*128;
    unsigned int qraw = *(const unsigned int*)(base + 2*lane);
    unsigned int kraw = *(const unsigned int*)(base + 3072 + 2*lane);
    float q0 = bf2f((unsigned short)(qraw & 0xffff)), q1 = bf2f((unsigned short)(qraw >> 16));
    float k0 = bf2f((unsigned short)(kraw & 0xffff)), k1 = bf2f((unsigned short)(kraw >> 16));

    float sq = q0*q0 + q1*q1, sk = k0*k0 + k1*k1;
    #pragma unroll
    for (int d=1; d<64; d<<=1){ sq += __shfl_xor(sq, d); sk += __shfl_xor(sk, d); }
    float rq = rsqrtf(sq*(1.0f/128.0f) + 1e-5f);
    float rk = rsqrtf(sk*(1.0f/128.0f) + 1e-5f);

    const float* wq = isx ? wqx : wqy;
    const float* wk = isx ? wkx : wky;
    float a0 = q0*rq*wq[2*lane], a1 = q1*rq*wq[2*lane+1];
    float b0 = k0*rk*wk[2*lane], b1 = k1*rk*wk[2*lane+1];

    if (isx){
      size_t ci = ((size_t)t*NH + h)*64 + lane;
      float c = cosT[ci], s = sinT[ci];
      float t0 = a0*c - a1*s, t1 = a0*s + a1*c; a0 = t0; a1 = t1;
      t0 = b0*c - b1*s; t1 = b0*s + b1*c; b0 = t0; b1 = t1;
    }
    size_t oi = ((size_t)h*SPAD + t)*128 + 2*lane;
    *(unsigned int*)(Qo + oi) = (unsigned int)bf16_rne(a0) | ((unsigned int)bf16_rne(a1) << 16);
    *(unsigned int*)(Ko + oi) = (unsigned int)bf16_rne(b0) | ((unsigned int)bf16_rne(b1) << 16);
  } else {
    int lid = blockIdx.x - 19632;
    int h = lid % NH;
    int t0 = (lid / NH)*64;
    int tid = threadIdx.x;
    #pragma unroll
    for (int it=0; it<4; it++){
      int chunk = it*256 + tid;
      int r = chunk >> 4, c = chunk & 15;
      short8 v = *(const short8*)(QKV + (size_t)(t0 + r)*9216 + 6144 + h*128 + c*8);
      *(short8*)&tt[r][c*8] = v;
    }
    __syncthreads();
    int d = tid >> 1, half = tid & 1;
    size_t ob = (size_t)(h*128 + d)*SPAD + t0 + half*32;
    #pragma unroll
    for (int j=0;j<32;j+=2){
      unsigned int v = (unsigned int)tt[half*32 + j][d] | ((unsigned int)tt[half*32 + j + 1][d] << 16);
      *(unsigned int*)(VT + ob + j) = v;
    }
  }
}

// ---------------------------------------------------------------------------
// Flash attention (R9 core) + XCD-head-grouping: flat 1D grid, chunked
// swizzle puts each XCD on ~3 heads so K/V stays L2-resident for staging.
// ---------------------------------------------------------------------------
__global__ __launch_bounds__(256, 3) void attn_fwd(
    const unsigned short* __restrict__ Q, const unsigned short* __restrict__ Kb,
    const unsigned short* __restrict__ VT, unsigned short* __restrict__ O)
{
  __shared__ unsigned short lK[2][32*128];   // 2 x 8KB
  __shared__ unsigned short lV[2][128*32];   // 2 x 8KB
  __shared__ unsigned short lP[4][32*72];    // 18KB

  int tid = threadIdx.x, wave = tid>>6, lane = tid&63;
  int l16 = lane&15, g = lane>>4;
  int swz = xcd_swizzle(blockIdx.x, NH*(SPAD/128));  // 624 = 8*78, bijective
  int h = swz / (SPAD/128), qt = swz % (SPAD/128);
  int q0 = qt*128 + wave*32;

  auto STAGE = [&](int kt, int b){
    #pragma unroll
    for (int i=0;i<2;i++){
      int off = (i*4 + wave)*1024 + lane*16;
      int row = off>>8;
      int sp  = (off>>4)&15;
      int ssp = sp ^ (row&7);
      gload16(Kb + ((size_t)h*SPAD + kt*32 + row)*128 + ssp*8,
              (char*)&lK[b][0] + (i*4 + wave)*1024);
    }
    #pragma unroll
    for (int i=0;i<2;i++){
      int off = (i*4 + wave)*1024 + lane*16;
      int row = off>>6;
      int sp  = (off>>4)&3;
      int ssp = sp ^ ((row>>1)&3);            // 2-way-free swizzle
      gload16(VT + ((size_t)(h*128 + row))*SPAD + kt*32 + ssp*8,
              (char*)&lV[b][0] + (i*4 + wave)*1024);
    }
  };

  short8 qf[2][4];
  const unsigned short* qbase = Q + (size_t)h*SPAD*128;
  #pragma unroll
  for (int mt=0;mt<2;mt++){
    int row = q0 + mt*16 + l16;
    #pragma unroll
    for (int ks=0;ks<4;ks++)
      qf[mt][ks] = *(const short8*)(qbase + (size_t)row*128 + ks*32 + g*8);
  }

  f32x4 oacc[2][8] = {};
  float lsum[2][4] = {};

  unsigned short* lPw = &lP[wave][0];
  const float sc2 = 0.08838834764831845f * 1.4426950408889634f; // sc*log2(e)
  const float C2  = -12.0f * 1.4426950408889634f;

  STAGE(0, 0);

  for (int kt=0; kt<104; kt++){
    int cur = kt & 1;
    int nxt = (kt+1 < 104) ? kt+1 : 103;
    STAGE(nxt, cur ^ 1);
    asm volatile("s_waitcnt vmcnt(4)" ::: "memory");
    __builtin_amdgcn_s_barrier();

    const char* lKc = (const char*)&lK[cur][0];
    const char* lVc = (const char*)&lV[cur][0];

    // ---- QK^T (32 keys) ----
    f32x4 s[2][2] = {};
    #pragma unroll
    for (int ks=0;ks<4;ks++){
      short8 bfrag[2];
      #pragma unroll
      for (int nt=0;nt<2;nt++){
        int row = nt*16 + l16;
        int slot = (ks*4 + g) ^ (row&7);
        bfrag[nt] = *(const short8*)(lKc + row*256 + slot*16);
      }
      __builtin_amdgcn_s_setprio(1);
      #pragma unroll
      for (int mt=0;mt<2;mt++)
        #pragma unroll
        for (int nt=0;nt<2;nt++)
          s[mt][nt] = MFMA_BF16(qf[mt][ks], bfrag[nt], s[mt][nt]);
      __builtin_amdgcn_s_setprio(0);
    }

    // ---- fixed-max softmax: p = exp2(s*sc2 + C2) == exp(s*sc - 12) ----
    bool edge = (kt >= 102);
    #pragma unroll
    for (int mt=0;mt<2;mt++)
      #pragma unroll
      for (int nt=0;nt<2;nt++){
        #pragma unroll
        for (int r=0;r<4;r++){
          float p = __builtin_amdgcn_exp2f(fmaf(s[mt][nt][r], sc2, C2));
          if (edge){
            int key = kt*32 + nt*16 + l16;
            if (key >= SVAL) p = 0.f;
          }
          lsum[mt][r] += p;
          lPw[(mt*16 + g*4 + r)*72 + nt*16 + l16] = bf16_rne(p);
        }
      }

    asm volatile("s_waitcnt lgkmcnt(0)" ::: "memory");

    // ---- PV (single 32-key slab) ----
    {
      short8 pa[2];
      #pragma unroll
      for (int mt=0;mt<2;mt++)
        pa[mt] = *(const short8*)(lPw + (mt*16 + l16)*72 + g*8);
      __builtin_amdgcn_s_setprio(1);
      #pragma unroll
      for (int dt=0;dt<8;dt++){
        int row = dt*16 + l16;
        int slot = g ^ ((row>>1)&3);
        short8 vb = *(const short8*)(lVc + row*64 + slot*16);
        #pragma unroll
        for (int mt=0;mt<2;mt++)
          oacc[mt][dt] = MFMA_BF16(pa[mt], vb, oacc[mt][dt]);
      }
      __builtin_amdgcn_s_setprio(0);
    }
    __builtin_amdgcn_s_barrier();
  }

  #pragma unroll
  for (int mt=0;mt<2;mt++){
    float inv[4];
    #pragma unroll
    for (int r=0;r<4;r++){
      float v = lsum[mt][r];
      v += __shfl_xor(v, 1); v += __shfl_xor(v, 2);
      v += __shfl_xor(v, 4); v += __shfl_xor(v, 8);
      inv[r] = 1.0f / v;
    }
    #pragma unroll
    for (int dt=0;dt<8;dt++)
      #pragma unroll
      for (int r=0;r<4;r++){
        int row = q0 + mt*16 + g*4 + r;
        if (row < SVAL)
          O[(size_t)row*3072 + h*128 + dt*16 + l16] = bf16_rne(oacc[mt][dt][r]*inv[r]);
      }
  }
}

// ---------------------------------------------------------------------------
// Workspace layout (bytes).
// ---------------------------------------------------------------------------
static const size_t OFF_WT_QKV_X  = 0;                 // 9216*3072*2
static const size_t OFF_WT_QKV_Y  = 56623104;          // 9216*1536*2
static const size_t OFF_WT_PROJ_X = 84934656;          // 3072*3072*2
static const size_t OFF_WT_PROJ_Y = 103809024;         // 1536*3072*2
static const size_t OFF_XM        = 113246208;         // 3072*3072*2
static const size_t OFF_YM        = 132120576;         // 256*1536*2
static const size_t OFF_QKV       = 132907008;         // 3328*9216*2
static const size_t OFF_Q         = 194248704;         // 24*3328*128*2
static const size_t OFF_K         = 214695936;
static const size_t OFF_VT        = 235143168;
static const size_t WS_NEEDED     = 255590400;
static const size_t OFF_AO        = 0;                 // 3328*3072*2 (alias Wt_qkv_x)

extern "C" void kernel_launch(void* const* d_in, const int* in_sizes, int n_in,
                              void* d_out, int out_size, void* d_ws, size_t ws_size,
                              hipStream_t stream) {
  if (ws_size < WS_NEEDED) return;

  const float* x        = (const float*)d_in[0];
  const float* y        = (const float*)d_in[1];
  const float* scale_x  = (const float*)d_in[2];
  const float* scale_y  = (const float*)d_in[3];
  const float* rope_cos = (const float*)d_in[4];
  const float* rope_sin = (const float*)d_in[5];
  const float* W_qkv_x  = (const float*)d_in[6];
  const float* b_qkv_x  = (const float*)d_in[7];
  const float* W_qkv_y  = (const float*)d_in[8];
  const float* b_qkv_y  = (const float*)d_in[9];
  const float* w_qn_x   = (const float*)d_in[10];
  const float* w_kn_x   = (const float*)d_in[11];
  const float* w_qn_y   = (const float*)d_in[12];
  const float* w_kn_y   = (const float*)d_in[13];
  const float* W_proj_x = (const float*)d_in[14];
  const float* b_proj_x = (const float*)d_in[15];
  const float* W_proj_y = (const float*)d_in[16];
  const float* b_proj_y = (const float*)d_in[17];

  float* out_x = (float*)d_out;
  float* out_y = out_x + (size_t)3072*3072;

  char* ws = (char*)d_ws;
  unsigned short* Wt_qkv_x  = (unsigned short*)(ws + OFF_WT_QKV_X);
  unsigned short* Wt_qkv_y  = (unsigned short*)(ws + OFF_WT_QKV_Y);
  unsigned short* Wt_proj_x = (unsigned short*)(ws + OFF_WT_PROJ_X);
  unsigned short* Wt_proj_y = (unsigned short*)(ws + OFF_WT_PROJ_Y);
  unsigned short* xm        = (unsigned short*)(ws + OFF_XM);
  unsigned short* ym        = (unsigned short*)(ws + OFF_YM);
  unsigned short* qkv       = (unsigned short*)(ws + OFF_QKV);
  unsigned short* Qb        = (unsigned short*)(ws + OFF_Q);
  unsigned short* Kb        = (unsigned short*)(ws + OFF_K);
  unsigned short* VTb       = (unsigned short*)(ws + OFF_VT);
  unsigned short* attnout   = (unsigned short*)(ws + OFF_AO);

  transpose_all<<<13824, 256, 0, stream>>>(
      W_qkv_x, Wt_qkv_x, W_qkv_y, Wt_qkv_y, W_proj_x, Wt_proj_x, W_proj_y, Wt_proj_y);

  modnorm<3072><<<3072, 256, 0, stream>>>(x, scale_x, xm);
  modnorm<1536><<<256,  256, 0, stream>>>(y, scale_y, ym);

  // qkv_x (3072x9216x3072) + qkv_y (256x9216x1536) fused: grid row 12 = y
  gemm_8ph<<<dim3(36, 13), 512, 0, stream>>>(
      xm, Wt_qkv_x, b_qkv_x, qkv, 3072, 9216,
      ym, Wt_qkv_y, b_qkv_y, qkv + (size_t)3072*9216, 1536);

  // fused qk fixup (19632 blocks) + v transpose (1248 blocks)
  fixup_qkv<<<19632 + NH*(SPAD/64), 256, 0, stream>>>(
      qkv, rope_cos, rope_sin, w_qn_x, w_kn_x, w_qn_y, w_kn_y, Qb, Kb, VTb);

  (void)hipMemsetAsync(attnout + (size_t)SVAL*3072, 0,
                       (size_t)(SPAD - SVAL)*3072*2, stream);

  attn_fwd<<<NH*(SPAD/128), 256, 0, stream>>>(Qb, Kb, VTb, attnout);

  // proj_x (3072x3072x3072) + proj_y (256x1536x3072) fused: grid row 24 = y
  gemm_proj<<<dim3(24, 25), 256, 0, stream>>>(
      attnout, Wt_proj_x, b_proj_x, out_x, 3072,
      attnout + (size_t)3072*3072, Wt_proj_y, b_proj_y, out_y, 1536);
}

// Round 12
// 527.402 us; speedup vs baseline: 1.1957x; 1.0226x over previous
//
#include <hip/hip_runtime.h>

// ---------------------------------------------------------------------------
// AsymmetricAttention fused pipeline for MI355X (gfx950), bf16 MFMA throughout.
// R12: attn P-store via v_cvt_pk_bf16_f32 pairs (R8 proved cvt_pk was not the
//      R7 regression - exp2f-OCML was); pad rows zero-written in attn epilogue
//      (memset dispatch dropped); modnorm fused into transpose_all.
// ---------------------------------------------------------------------------

typedef short short8 __attribute__((ext_vector_type(8)));
typedef float f32x4 __attribute__((ext_vector_type(4)));
typedef unsigned short ushort4v __attribute__((ext_vector_type(4)));

#define MFMA_BF16(a,b,c) __builtin_amdgcn_mfma_f32_16x16x32_bf16((a),(b),(c),0,0,0)

#define NH 24
#define SPAD 3328   // padded token count (104*32)
#define SVAL 3272   // valid tokens (3072 x + 200 y)

__device__ __forceinline__ unsigned short bf16_rne(float f){
  unsigned int u = __builtin_bit_cast(unsigned int, f);
  u += 0x7FFFu + ((u >> 16) & 1u);
  return (unsigned short)(u >> 16);
}
__device__ __forceinline__ float bf2f(unsigned short h){
  unsigned int u = ((unsigned int)h) << 16;
  return __builtin_bit_cast(float, u);
}
__device__ __forceinline__ unsigned int cvt_pk_bf16(float lo, float hi){
  unsigned int r;
  asm("v_cvt_pk_bf16_f32 %0, %1, %2" : "=v"(r) : "v"(lo), "v"(hi));
  return r;
}
__device__ __forceinline__ void gload16(const void* g, void* l){
  __builtin_amdgcn_global_load_lds(
      (const __attribute__((address_space(1))) unsigned int*)g,
      (__attribute__((address_space(3))) unsigned int*)l, 16, 0, 0);
}
// m204 bijective XCD swizzle (works for any nwg)
__device__ __forceinline__ int xcd_swizzle(int orig, int nwg){
  int q = nwg >> 3, r = nwg & 7;
  int xcd = orig & 7, loc = orig >> 3;
  return (xcd < r ? xcd*(q+1) : r*(q+1) + (xcd-r)*q) + loc;
}

// ---------------------------------------------------------------------------
// Fused preprocessing: W transposes (blocks [0,13824)) + mod-rmsnorm of x
// (blocks [13824,16896)) + mod-rmsnorm of y (blocks [16896,17152)).
// ---------------------------------------------------------------------------
__global__ __launch_bounds__(256) void prep_all(
    const float* __restrict__ W0, unsigned short* __restrict__ T0,   // 3072x9216
    const float* __restrict__ W1, unsigned short* __restrict__ T1,   // 1536x9216
    const float* __restrict__ W2, unsigned short* __restrict__ T2,   // 3072x3072
    const float* __restrict__ W3, unsigned short* __restrict__ T3,   // 3072x1536
    const float* __restrict__ x,  const float* __restrict__ scale_x,
    unsigned short* __restrict__ xm,
    const float* __restrict__ y,  const float* __restrict__ scale_y,
    unsigned short* __restrict__ ym)
{
  __shared__ unsigned short t[64][66];
  int f = blockIdx.x;
  int tid = threadIdx.x;

  if (f < 13824){
    const float* W; unsigned short* Wt; int K, N, lid;
    if      (f < 6912)           { W=W0; Wt=T0; K=3072; N=9216; lid=f; }
    else if (f < 10368)          { W=W1; Wt=T1; K=1536; N=9216; lid=f-6912; }
    else if (f < 12672)          { W=W2; Wt=T2; K=3072; N=3072; lid=f-10368; }
    else                         { W=W3; Wt=T3; K=3072; N=1536; lid=f-12672; }
    int ntiles = N >> 6;
    int n0 = (lid % ntiles)*64, k0 = (lid / ntiles)*64;

    int kr = tid >> 4, nc = (tid & 15) * 4;
    #pragma unroll
    for (int pass=0; pass<4; pass++){
      int k = kr + pass*16;
      float4 v = *(const float4*)(W + (size_t)(k0+k)*N + n0 + nc);
      ushort4v o;
      o.x = bf16_rne(v.x); o.y = bf16_rne(v.y);
      o.z = bf16_rne(v.z); o.w = bf16_rne(v.w);
      *(ushort4v*)&t[k][nc] = o;
    }
    __syncthreads();
    int nr = tid >> 3, kc = (tid & 7) * 8;
    #pragma unroll
    for (int pass=0; pass<2; pass++){
      int n = nr + pass*32;
      unsigned short buf[8];
      #pragma unroll
      for (int j=0;j<8;j++) buf[j] = t[kc+j][n];
      *(short8*)(Wt + (size_t)(n0+n)*K + k0 + kc) = *(short8*)&buf[0];
    }
  } else {
    const float* X; const float* scale; unsigned short* out; int D, row;
    if (f < 16896){ X=x; scale=scale_x; out=xm; D=3072; row=f-13824; }
    else          { X=y; scale=scale_y; out=ym; D=1536; row=f-16896; }
    const float4* xv = (const float4*)(X + (size_t)row*D);
    float ss = 0.f;
    for (int i = tid; i < D/4; i += 256){
      float4 v = xv[i];
      ss += v.x*v.x + v.y*v.y + v.z*v.z + v.w*v.w;
    }
    #pragma unroll
    for (int d=1; d<64; d<<=1) ss += __shfl_xor(ss, d);
    __shared__ float wsum[4];
    if ((tid & 63) == 0) wsum[tid >> 6] = ss;
    __syncthreads();
    float tot = wsum[0] + wsum[1] + wsum[2] + wsum[3];
    float rn = rsqrtf(tot*(1.0f/(float)D) + 1e-6f);
    const float4* sv = (const float4*)scale;
    for (int i = tid; i < D/4; i += 256){
      float4 v = xv[i]; float4 s4 = sv[i];
      ushort4v o;
      o.x = bf16_rne(v.x*rn*(1.f+s4.x));
      o.y = bf16_rne(v.y*rn*(1.f+s4.y));
      o.z = bf16_rne(v.z*rn*(1.f+s4.z));
      o.w = bf16_rne(v.w*rn*(1.f+s4.w));
      *(ushort4v*)(out + (size_t)row*D + i*4) = o;
    }
  }
}

// ---------------------------------------------------------------------------
// 256^2-tile 8-phase GEMM, dual-problem (unchanged from R10/R11).
// ---------------------------------------------------------------------------
__global__ __launch_bounds__(512, 2) void gemm_8ph(
    const unsigned short* __restrict__ A, const unsigned short* __restrict__ BT,
    const float* __restrict__ bias, unsigned short* __restrict__ C,
    int K, int ldc,
    const unsigned short* __restrict__ A2, const unsigned short* __restrict__ BT2,
    const float* __restrict__ bias2, unsigned short* __restrict__ C2, int K2)
{
  __shared__ unsigned short lds[8][8192];

  int tid = threadIdx.x, wave = tid>>6, lane = tid&63;
  int l16 = lane&15, g = lane>>4;
  int wr = wave>>2, wc = wave&3;

  int nwg = gridDim.x*gridDim.y;
  int orig = blockIdx.y*gridDim.x + blockIdx.x;
  int neo = xcd_swizzle(orig, nwg);
  int bx = neo / gridDim.y, by = neo % gridDim.y;

  bool ybl = (by == (int)gridDim.y - 1);
  const unsigned short* Ap  = ybl ? A2 : A;
  const unsigned short* Bp  = ybl ? BT2 : BT;
  const float* bp           = ybl ? bias2 : bias;
  unsigned short* Cp        = ybl ? C2 : C;
  int Kl = ybl ? K2 : K;
  int bm = ybl ? 0 : by*256;
  int bn = bx*256;

  const int NT = Kl >> 6;

  auto STAGE = [&](int t, int op, int half, int b){
    int tc = t < NT ? t : NT-1;
    const unsigned short* src = op ? Bp : Ap;
    int base_row = (op ? bn : bm) + half*128;
    int k0 = tc << 6;
    #pragma unroll
    for (int j=0;j<2;j++){
      int o = (j*8 + wave)*1024 + lane*16;
      int row = o>>7, slot = (o>>4)&7;
      int sk = (slot ^ (row&7))*8;
      gload16(src + (size_t)(base_row+row)*Kl + k0 + sk,
              (char*)&lds[(b<<2)|(op<<1)|half][0] + (j*8+wave)*1024);
    }
  };

  short8 afr[4], bfr[8];
  auto LDA = [&](int b, int p){
    const char* basep = (const char*)&lds[(b<<2)|wr][0];
    #pragma unroll
    for (int mm=0;mm<2;mm++){
      int row = (p*2+mm)*16 + l16;
      #pragma unroll
      for (int kk=0;kk<2;kk++)
        afr[mm*2+kk] = *(const short8*)(basep + row*128 + (((kk*4+g) ^ (row&7))<<4));
    }
  };
  auto LDB = [&](int b){
    const char* basep = (const char*)&lds[(b<<2)|2|(wc>>1)][0];
    int rbase = (wc&1)*64;
    #pragma unroll
    for (int n=0;n<4;n++){
      int row = rbase + n*16 + l16;
      #pragma unroll
      for (int kk=0;kk<2;kk++)
        bfr[n*2+kk] = *(const short8*)(basep + row*128 + (((kk*4+g) ^ (row&7))<<4));
    }
  };

  f32x4 acc[8][4] = {};

  STAGE(0,1,0,0); STAGE(0,1,1,0); STAGE(0,0,0,0); STAGE(0,0,1,0);
  STAGE(1,1,0,1); STAGE(1,1,1,1); STAGE(1,0,0,1);
  asm volatile("s_waitcnt vmcnt(6)" ::: "memory");
  __builtin_amdgcn_s_barrier();

  int NIT = NT >> 1;
  for (int i=0;i<NIT;i++){
    int T = 2*i;
    #pragma unroll
    for (int p=0;p<4;p++){
      if (p==0) LDB(0);
      LDA(0, p);
      if (p==0)      STAGE(T+1,0,1,1);
      else if (p==1) STAGE(T+2,1,0,0);
      else if (p==2) STAGE(T+2,1,1,0);
      else           STAGE(T+2,0,0,0);
      if (p==0) asm volatile("s_waitcnt lgkmcnt(8)" ::: "memory");
      __builtin_amdgcn_s_barrier();
      asm volatile("s_waitcnt lgkmcnt(0)" ::: "memory");
      __builtin_amdgcn_sched_barrier(0);
      __builtin_amdgcn_s_setprio(1);
      #pragma unroll
      for (int mm=0;mm<2;mm++)
        #pragma unroll
        for (int n=0;n<4;n++)
          #pragma unroll
          for (int kk=0;kk<2;kk++)
            acc[p*2+mm][n] = MFMA_BF16(afr[mm*2+kk], bfr[n*2+kk], acc[p*2+mm][n]);
      __builtin_amdgcn_s_setprio(0);
      if (p==3) asm volatile("s_waitcnt vmcnt(6)" ::: "memory");
      __builtin_amdgcn_s_barrier();
    }
    #pragma unroll
    for (int p=0;p<4;p++){
      if (p==0) LDB(1);
      LDA(1, p);
      if (p==0)      STAGE(T+2,0,1,0);
      else if (p==1) STAGE(T+3,1,0,1);
      else if (p==2) STAGE(T+3,1,1,1);
      else           STAGE(T+3,0,0,1);
      if (p==0) asm volatile("s_waitcnt lgkmcnt(8)" ::: "memory");
      __builtin_amdgcn_s_barrier();
      asm volatile("s_waitcnt lgkmcnt(0)" ::: "memory");
      __builtin_amdgcn_sched_barrier(0);
      __builtin_amdgcn_s_setprio(1);
      #pragma unroll
      for (int mm=0;mm<2;mm++)
        #pragma unroll
        for (int n=0;n<4;n++)
          #pragma unroll
          for (int kk=0;kk<2;kk++)
            acc[p*2+mm][n] = MFMA_BF16(afr[mm*2+kk], bfr[n*2+kk], acc[p*2+mm][n]);
      __builtin_amdgcn_s_setprio(0);
      if (p==3) asm volatile("s_waitcnt vmcnt(6)" ::: "memory");
      __builtin_amdgcn_s_barrier();
    }
  }

  #pragma unroll
  for (int n=0;n<4;n++){
    int col = bn + wc*64 + n*16 + l16;
    float bv = bp[col];
    #pragma unroll
    for (int m=0;m<8;m++){
      int row0 = bm + wr*128 + m*16 + g*4;
      #pragma unroll
      for (int r=0;r<4;r++)
        Cp[(size_t)(row0+r)*ldc + col] = bf16_rne(acc[m][n][r] + bv);
    }
  }
}

// ---------------------------------------------------------------------------
// 128^2-tile dual proj GEMM (unchanged).
// ---------------------------------------------------------------------------
__global__ __launch_bounds__(256, 3) void gemm_proj(
    const unsigned short* __restrict__ A, const unsigned short* __restrict__ BT,
    const float* __restrict__ bias, float* __restrict__ C, int ldc,
    const unsigned short* __restrict__ A2, const unsigned short* __restrict__ BT2,
    const float* __restrict__ bias2, float* __restrict__ C2, int ldc2)
{
  __shared__ unsigned short lA[128*32];
  __shared__ unsigned short lB[128*32];
  int tid = threadIdx.x, wave = tid>>6, lane = tid&63;
  int l16 = lane&15, g = lane>>4;
  int wr = wave>>1, wc = wave&1;

  const int K = 3072;
  int nwg = gridDim.x*gridDim.y;
  int orig = blockIdx.y*gridDim.x + blockIdx.x;
  int neo = xcd_swizzle(orig, nwg);
  int bx = neo / gridDim.y, by = neo % gridDim.y;

  bool ybl = (by == (int)gridDim.y - 1);
  const unsigned short* Ap = ybl ? A2 : A;
  const unsigned short* Bp = ybl ? BT2 : BT;
  const float* bp          = ybl ? bias2 : bias;
  float* Cp                = ybl ? C2 : C;
  int ldcl                 = ybl ? ldc2 : ldc;
  int bm, bn;
  if (ybl){ bm = (bx & 1)*128; bn = (bx >> 1)*128; }
  else    { bm = by*128;       bn = bx*128; }

  f32x4 acc[4][4] = {};

  for (int k0 = 0; k0 < K; k0 += 32){
    #pragma unroll
    for (int i=0;i<2;i++){
      int off = i*4096 + wave*1024 + lane*16;
      int row = off>>6;
      int sp  = (off>>4)&3;
      int sk  = (sp ^ (row&3))*8;
      gload16(Ap + (size_t)(bm+row)*K + k0 + sk, (char*)lA + i*4096 + wave*1024);
    }
    #pragma unroll
    for (int i=0;i<2;i++){
      int off = i*4096 + wave*1024 + lane*16;
      int row = off>>6;
      int sp  = (off>>4)&3;
      int sk  = (sp ^ (row&3))*8;
      gload16(Bp + (size_t)(bn+row)*K + k0 + sk, (char*)lB + i*4096 + wave*1024);
    }
    __syncthreads();

    short8 a[4], b[4];
    #pragma unroll
    for (int m=0;m<4;m++){
      int row = wr*64 + m*16 + l16;
      int slot = g ^ (row&3);
      a[m] = *(const short8*)((const char*)lA + row*64 + slot*16);
    }
    #pragma unroll
    for (int n=0;n<4;n++){
      int row = wc*64 + n*16 + l16;
      int slot = g ^ (row&3);
      b[n] = *(const short8*)((const char*)lB + row*64 + slot*16);
    }
    __builtin_amdgcn_s_setprio(1);
    #pragma unroll
    for (int m=0;m<4;m++)
      #pragma unroll
      for (int n=0;n<4;n++)
        acc[m][n] = MFMA_BF16(a[m], b[n], acc[m][n]);
    __builtin_amdgcn_s_setprio(0);
    __syncthreads();
  }

  #pragma unroll
  for (int n=0;n<4;n++){
    int col = bn + wc*64 + n*16 + l16;
    float bv = bp[col];
    #pragma unroll
    for (int m=0;m<4;m++){
      int row0 = bm + wr*64 + m*16 + g*4;
      #pragma unroll
      for (int r=0;r<4;r++)
        Cp[(size_t)(row0+r)*ldcl + col] = acc[m][n][r] + bv;
    }
  }
}

// ---------------------------------------------------------------------------
// Fused qk fixup + V transpose (unchanged from R11).
// ---------------------------------------------------------------------------
__global__ __launch_bounds__(256) void fixup_qkv(
    const unsigned short* __restrict__ QKV,
    const float* __restrict__ cosT, const float* __restrict__ sinT,
    const float* __restrict__ wqx, const float* __restrict__ wkx,
    const float* __restrict__ wqy, const float* __restrict__ wky,
    unsigned short* __restrict__ Qo, unsigned short* __restrict__ Ko,
    unsigned short* __restrict__ VT)
{
  __shared__ unsigned short tt[64][136];
  if (blockIdx.x < 19632){
    int wave = threadIdx.x >> 6, lane = threadIdx.x & 63;
    int bid = blockIdx.x*4 + wave;
    int t = bid / NH, h = bid % NH;
    bool isx = (t < 3072);

    const unsigned short* base = QKV + (size_t)t*9216 + h*128;
    unsigned int qraw = *(const unsigned int*)(base + 2*lane);
    unsigned int kraw = *(const unsigned int*)(base + 3072 + 2*lane);
    float q0 = bf2f((unsigned short)(qraw & 0xffff)), q1 = bf2f((unsigned short)(qraw >> 16));
    float k0 = bf2f((unsigned short)(kraw & 0xffff)), k1 = bf2f((unsigned short)(kraw >> 16));

    float sq = q0*q0 + q1*q1, sk = k0*k0 + k1*k1;
    #pragma unroll
    for (int d=1; d<64; d<<=1){ sq += __shfl_xor(sq, d); sk += __shfl_xor(sk, d); }
    float rq = rsqrtf(sq*(1.0f/128.0f) + 1e-5f);
    float rk = rsqrtf(sk*(1.0f/128.0f) + 1e-5f);

    const float* wq = isx ? wqx : wqy;
    const float* wk = isx ? wkx : wky;
    float a0 = q0*rq*wq[2*lane], a1 = q1*rq*wq[2*lane+1];
    float b0 = k0*rk*wk[2*lane], b1 = k1*rk*wk[2*lane+1];

    if (isx){
      size_t ci = ((size_t)t*NH + h)*64 + lane;
      float c = cosT[ci], s = sinT[ci];
      float t0 = a0*c - a1*s, t1 = a0*s + a1*c; a0 = t0; a1 = t1;
      t0 = b0*c - b1*s; t1 = b0*s + b1*c; b0 = t0; b1 = t1;
    }
    size_t oi = ((size_t)h*SPAD + t)*128 + 2*lane;
    *(unsigned int*)(Qo + oi) = (unsigned int)bf16_rne(a0) | ((unsigned int)bf16_rne(a1) << 16);
    *(unsigned int*)(Ko + oi) = (unsigned int)bf16_rne(b0) | ((unsigned int)bf16_rne(b1) << 16);
  } else {
    int lid = blockIdx.x - 19632;
    int h = lid % NH;
    int t0 = (lid / NH)*64;
    int tid = threadIdx.x;
    #pragma unroll
    for (int it=0; it<4; it++){
      int chunk = it*256 + tid;
      int r = chunk >> 4, c = chunk & 15;
      short8 v = *(const short8*)(QKV + (size_t)(t0 + r)*9216 + 6144 + h*128 + c*8);
      *(short8*)&tt[r][c*8] = v;
    }
    __syncthreads();
    int d = tid >> 1, half = tid & 1;
    size_t ob = (size_t)(h*128 + d)*SPAD + t0 + half*32;
    #pragma unroll
    for (int j=0;j<32;j+=2){
      unsigned int v = (unsigned int)tt[half*32 + j][d] | ((unsigned int)tt[half*32 + j + 1][d] << 16);
      *(unsigned int*)(VT + ob + j) = v;
    }
  }
}

// ---------------------------------------------------------------------------
// Flash attention (R11 core): XCD-head-grouping, fixed-max softmax with
// native exp2, cvt_pk P-store, pad rows zero-written (replaces memset).
// ---------------------------------------------------------------------------
__global__ __launch_bounds__(256, 3) void attn_fwd(
    const unsigned short* __restrict__ Q, const unsigned short* __restrict__ Kb,
    const unsigned short* __restrict__ VT, unsigned short* __restrict__ O)
{
  __shared__ unsigned short lK[2][32*128];   // 2 x 8KB
  __shared__ unsigned short lV[2][128*32];   // 2 x 8KB
  __shared__ unsigned short lP[4][32*72];    // 18KB

  int tid = threadIdx.x, wave = tid>>6, lane = tid&63;
  int l16 = lane&15, g = lane>>4;
  int swz = xcd_swizzle(blockIdx.x, NH*(SPAD/128));  // 624, bijective
  int h = swz / (SPAD/128), qt = swz % (SPAD/128);
  int q0 = qt*128 + wave*32;

  auto STAGE = [&](int kt, int b){
    #pragma unroll
    for (int i=0;i<2;i++){
      int off = (i*4 + wave)*1024 + lane*16;
      int row = off>>8;
      int sp  = (off>>4)&15;
      int ssp = sp ^ (row&7);
      gload16(Kb + ((size_t)h*SPAD + kt*32 + row)*128 + ssp*8,
              (char*)&lK[b][0] + (i*4 + wave)*1024);
    }
    #pragma unroll
    for (int i=0;i<2;i++){
      int off = (i*4 + wave)*1024 + lane*16;
      int row = off>>6;
      int sp  = (off>>4)&3;
      int ssp = sp ^ ((row>>1)&3);            // 2-way-free swizzle
      gload16(VT + ((size_t)(h*128 + row))*SPAD + kt*32 + ssp*8,
              (char*)&lV[b][0] + (i*4 + wave)*1024);
    }
  };

  short8 qf[2][4];
  const unsigned short* qbase = Q + (size_t)h*SPAD*128;
  #pragma unroll
  for (int mt=0;mt<2;mt++){
    int row = q0 + mt*16 + l16;
    #pragma unroll
    for (int ks=0;ks<4;ks++)
      qf[mt][ks] = *(const short8*)(qbase + (size_t)row*128 + ks*32 + g*8);
  }

  f32x4 oacc[2][8] = {};
  float lsum[2][4] = {};

  unsigned short* lPw = &lP[wave][0];
  const float sc2 = 0.08838834764831845f * 1.4426950408889634f; // sc*log2(e)
  const float C2  = -12.0f * 1.4426950408889634f;

  STAGE(0, 0);

  for (int kt=0; kt<104; kt++){
    int cur = kt & 1;
    int nxt = (kt+1 < 104) ? kt+1 : 103;
    STAGE(nxt, cur ^ 1);
    asm volatile("s_waitcnt vmcnt(4)" ::: "memory");
    __builtin_amdgcn_s_barrier();

    const char* lKc = (const char*)&lK[cur][0];
    const char* lVc = (const char*)&lV[cur][0];

    // ---- QK^T (32 keys) ----
    f32x4 s[2][2] = {};
    #pragma unroll
    for (int ks=0;ks<4;ks++){
      short8 bfrag[2];
      #pragma unroll
      for (int nt=0;nt<2;nt++){
        int row = nt*16 + l16;
        int slot = (ks*4 + g) ^ (row&7);
        bfrag[nt] = *(const short8*)(lKc + row*256 + slot*16);
      }
      __builtin_amdgcn_s_setprio(1);
      #pragma unroll
      for (int mt=0;mt<2;mt++)
        #pragma unroll
        for (int nt=0;nt<2;nt++)
          s[mt][nt] = MFMA_BF16(qf[mt][ks], bfrag[nt], s[mt][nt]);
      __builtin_amdgcn_s_setprio(0);
    }

    // ---- fixed-max softmax: p = exp2(s*sc2 + C2); cvt_pk paired store ----
    bool edge = (kt >= 102);
    #pragma unroll
    for (int mt=0;mt<2;mt++)
      #pragma unroll
      for (int nt=0;nt<2;nt++){
        float p[4];
        #pragma unroll
        for (int r=0;r<4;r++)
          p[r] = __builtin_amdgcn_exp2f(fmaf(s[mt][nt][r], sc2, C2));
        if (edge){
          int key = kt*32 + nt*16 + l16;
          if (key >= SVAL){ p[0]=0.f; p[1]=0.f; p[2]=0.f; p[3]=0.f; }
        }
        #pragma unroll
        for (int r=0;r<4;r++) lsum[mt][r] += p[r];
        unsigned int pk01 = cvt_pk_bf16(p[0], p[1]);
        unsigned int pk23 = cvt_pk_bf16(p[2], p[3]);
        unsigned short* pb = lPw + (mt*16 + g*4)*72 + nt*16 + l16;
        pb[0]     = (unsigned short)pk01;
        pb[72]    = (unsigned short)(pk01 >> 16);
        pb[144]   = (unsigned short)pk23;
        pb[216]   = (unsigned short)(pk23 >> 16);
      }

    asm volatile("s_waitcnt lgkmcnt(0)" ::: "memory");

    // ---- PV (single 32-key slab) ----
    {
      short8 pa[2];
      #pragma unroll
      for (int mt=0;mt<2;mt++)
        pa[mt] = *(const short8*)(lPw + (mt*16 + l16)*72 + g*8);
      __builtin_amdgcn_s_setprio(1);
      #pragma unroll
      for (int dt=0;dt<8;dt++){
        int row = dt*16 + l16;
        int slot = g ^ ((row>>1)&3);
        short8 vb = *(const short8*)(lVc + row*64 + slot*16);
        #pragma unroll
        for (int mt=0;mt<2;mt++)
          oacc[mt][dt] = MFMA_BF16(pa[mt], vb, oacc[mt][dt]);
      }
      __builtin_amdgcn_s_setprio(0);
    }
    __builtin_amdgcn_s_barrier();
  }

  #pragma unroll
  for (int mt=0;mt<2;mt++){
    float inv[4];
    #pragma unroll
    for (int r=0;r<4;r++){
      float v = lsum[mt][r];
      v += __shfl_xor(v, 1); v += __shfl_xor(v, 2);
      v += __shfl_xor(v, 4); v += __shfl_xor(v, 8);
      inv[r] = 1.0f / v;
    }
    #pragma unroll
    for (int dt=0;dt<8;dt++)
      #pragma unroll
      for (int r=0;r<4;r++){
        int row = q0 + mt*16 + g*4 + r;
        // pad rows written as exact 0 (replaces the memset dispatch)
        unsigned short val = (row < SVAL) ? bf16_rne(oacc[mt][dt][r]*inv[r])
                                          : (unsigned short)0;
        O[(size_t)row*3072 + h*128 + dt*16 + l16] = val;
      }
  }
}

// ---------------------------------------------------------------------------
// Workspace layout (bytes).
// ---------------------------------------------------------------------------
static const size_t OFF_WT_QKV_X  = 0;                 // 9216*3072*2
static const size_t OFF_WT_QKV_Y  = 56623104;          // 9216*1536*2
static const size_t OFF_WT_PROJ_X = 84934656;          // 3072*3072*2
static const size_t OFF_WT_PROJ_Y = 103809024;         // 1536*3072*2
static const size_t OFF_XM        = 113246208;         // 3072*3072*2
static const size_t OFF_YM        = 132120576;         // 256*1536*2
static const size_t OFF_QKV       = 132907008;         // 3328*9216*2
static const size_t OFF_Q         = 194248704;         // 24*3328*128*2
static const size_t OFF_K         = 214695936;
static const size_t OFF_VT        = 235143168;
static const size_t WS_NEEDED     = 255590400;
static const size_t OFF_AO        = 0;                 // 3328*3072*2 (alias Wt_qkv_x)

extern "C" void kernel_launch(void* const* d_in, const int* in_sizes, int n_in,
                              void* d_out, int out_size, void* d_ws, size_t ws_size,
                              hipStream_t stream) {
  if (ws_size < WS_NEEDED) return;

  const float* x        = (const float*)d_in[0];
  const float* y        = (const float*)d_in[1];
  const float* scale_x  = (const float*)d_in[2];
  const float* scale_y  = (const float*)d_in[3];
  const float* rope_cos = (const float*)d_in[4];
  const float* rope_sin = (const float*)d_in[5];
  const float* W_qkv_x  = (const float*)d_in[6];
  const float* b_qkv_x  = (const float*)d_in[7];
  const float* W_qkv_y  = (const float*)d_in[8];
  const float* b_qkv_y  = (const float*)d_in[9];
  const float* w_qn_x   = (const float*)d_in[10];
  const float* w_kn_x   = (const float*)d_in[11];
  const float* w_qn_y   = (const float*)d_in[12];
  const float* w_kn_y   = (const float*)d_in[13];
  const float* W_proj_x = (const float*)d_in[14];
  const float* b_proj_x = (const float*)d_in[15];
  const float* W_proj_y = (const float*)d_in[16];
  const float* b_proj_y = (const float*)d_in[17];

  float* out_x = (float*)d_out;
  float* out_y = out_x + (size_t)3072*3072;

  char* ws = (char*)d_ws;
  unsigned short* Wt_qkv_x  = (unsigned short*)(ws + OFF_WT_QKV_X);
  unsigned short* Wt_qkv_y  = (unsigned short*)(ws + OFF_WT_QKV_Y);
  unsigned short* Wt_proj_x = (unsigned short*)(ws + OFF_WT_PROJ_X);
  unsigned short* Wt_proj_y = (unsigned short*)(ws + OFF_WT_PROJ_Y);
  unsigned short* xm        = (unsigned short*)(ws + OFF_XM);
  unsigned short* ym        = (unsigned short*)(ws + OFF_YM);
  unsigned short* qkv       = (unsigned short*)(ws + OFF_QKV);
  unsigned short* Qb        = (unsigned short*)(ws + OFF_Q);
  unsigned short* Kb        = (unsigned short*)(ws + OFF_K);
  unsigned short* VTb       = (unsigned short*)(ws + OFF_VT);
  unsigned short* attnout   = (unsigned short*)(ws + OFF_AO);

  // transposes + modnorms, one dispatch
  prep_all<<<17152, 256, 0, stream>>>(
      W_qkv_x, Wt_qkv_x, W_qkv_y, Wt_qkv_y, W_proj_x, Wt_proj_x, W_proj_y, Wt_proj_y,
      x, scale_x, xm, y, scale_y, ym);

  // qkv_x (3072x9216x3072) + qkv_y (256x9216x1536) fused: grid row 12 = y
  gemm_8ph<<<dim3(36, 13), 512, 0, stream>>>(
      xm, Wt_qkv_x, b_qkv_x, qkv, 3072, 9216,
      ym, Wt_qkv_y, b_qkv_y, qkv + (size_t)3072*9216, 1536);

  // fused qk fixup (19632 blocks) + v transpose (1248 blocks)
  fixup_qkv<<<19632 + NH*(SPAD/64), 256, 0, stream>>>(
      qkv, rope_cos, rope_sin, w_qn_x, w_kn_x, w_qn_y, w_kn_y, Qb, Kb, VTb);

  attn_fwd<<<NH*(SPAD/128), 256, 0, stream>>>(Qb, Kb, VTb, attnout);

  // proj_x (3072x3072x3072) + proj_y (256x1536x3072) fused: grid row 24 = y
  gemm_proj<<<dim3(24, 25), 256, 0, stream>>>(
      attnout, Wt_proj_x, b_proj_x, out_x, 3072,
      attnout + (size_t)3072*3072, Wt_proj_y, b_proj_y, out_y, 1536);
}

// Round 13
// 525.657 us; speedup vs baseline: 1.1997x; 1.0033x over previous
//
#include <hip/hip_runtime.h>

// ---------------------------------------------------------------------------
// AsymmetricAttention fused pipeline for MI355X (gfx950), bf16 MFMA throughout.
// R13: gemm_8ph de-pinned — removed sched_barrier(0) + manual lgkmcnt(0)/(8)
//      from the phase loop (rule #18 applies only to inline-asm ds_reads;
//      compiler emits fine-grained lgkmcnt for its own reads, m97/m141).
//      Everything else unchanged from R12.
// ---------------------------------------------------------------------------

typedef short short8 __attribute__((ext_vector_type(8)));
typedef float f32x4 __attribute__((ext_vector_type(4)));
typedef unsigned short ushort4v __attribute__((ext_vector_type(4)));

#define MFMA_BF16(a,b,c) __builtin_amdgcn_mfma_f32_16x16x32_bf16((a),(b),(c),0,0,0)

#define NH 24
#define SPAD 3328   // padded token count (104*32)
#define SVAL 3272   // valid tokens (3072 x + 200 y)

__device__ __forceinline__ unsigned short bf16_rne(float f){
  unsigned int u = __builtin_bit_cast(unsigned int, f);
  u += 0x7FFFu + ((u >> 16) & 1u);
  return (unsigned short)(u >> 16);
}
__device__ __forceinline__ float bf2f(unsigned short h){
  unsigned int u = ((unsigned int)h) << 16;
  return __builtin_bit_cast(float, u);
}
__device__ __forceinline__ unsigned int cvt_pk_bf16(float lo, float hi){
  unsigned int r;
  asm("v_cvt_pk_bf16_f32 %0, %1, %2" : "=v"(r) : "v"(lo), "v"(hi));
  return r;
}
__device__ __forceinline__ void gload16(const void* g, void* l){
  __builtin_amdgcn_global_load_lds(
      (const __attribute__((address_space(1))) unsigned int*)g,
      (__attribute__((address_space(3))) unsigned int*)l, 16, 0, 0);
}
// m204 bijective XCD swizzle (works for any nwg)
__device__ __forceinline__ int xcd_swizzle(int orig, int nwg){
  int q = nwg >> 3, r = nwg & 7;
  int xcd = orig & 7, loc = orig >> 3;
  return (xcd < r ? xcd*(q+1) : r*(q+1) + (xcd-r)*q) + loc;
}

// ---------------------------------------------------------------------------
// Fused preprocessing: W transposes (blocks [0,13824)) + mod-rmsnorm of x
// (blocks [13824,16896)) + mod-rmsnorm of y (blocks [16896,17152)).
// ---------------------------------------------------------------------------
__global__ __launch_bounds__(256) void prep_all(
    const float* __restrict__ W0, unsigned short* __restrict__ T0,   // 3072x9216
    const float* __restrict__ W1, unsigned short* __restrict__ T1,   // 1536x9216
    const float* __restrict__ W2, unsigned short* __restrict__ T2,   // 3072x3072
    const float* __restrict__ W3, unsigned short* __restrict__ T3,   // 3072x1536
    const float* __restrict__ x,  const float* __restrict__ scale_x,
    unsigned short* __restrict__ xm,
    const float* __restrict__ y,  const float* __restrict__ scale_y,
    unsigned short* __restrict__ ym)
{
  __shared__ unsigned short t[64][66];
  int f = blockIdx.x;
  int tid = threadIdx.x;

  if (f < 13824){
    const float* W; unsigned short* Wt; int K, N, lid;
    if      (f < 6912)           { W=W0; Wt=T0; K=3072; N=9216; lid=f; }
    else if (f < 10368)          { W=W1; Wt=T1; K=1536; N=9216; lid=f-6912; }
    else if (f < 12672)          { W=W2; Wt=T2; K=3072; N=3072; lid=f-10368; }
    else                         { W=W3; Wt=T3; K=3072; N=1536; lid=f-12672; }
    int ntiles = N >> 6;
    int n0 = (lid % ntiles)*64, k0 = (lid / ntiles)*64;

    int kr = tid >> 4, nc = (tid & 15) * 4;
    #pragma unroll
    for (int pass=0; pass<4; pass++){
      int k = kr + pass*16;
      float4 v = *(const float4*)(W + (size_t)(k0+k)*N + n0 + nc);
      ushort4v o;
      o.x = bf16_rne(v.x); o.y = bf16_rne(v.y);
      o.z = bf16_rne(v.z); o.w = bf16_rne(v.w);
      *(ushort4v*)&t[k][nc] = o;
    }
    __syncthreads();
    int nr = tid >> 3, kc = (tid & 7) * 8;
    #pragma unroll
    for (int pass=0; pass<2; pass++){
      int n = nr + pass*32;
      unsigned short buf[8];
      #pragma unroll
      for (int j=0;j<8;j++) buf[j] = t[kc+j][n];
      *(short8*)(Wt + (size_t)(n0+n)*K + k0 + kc) = *(short8*)&buf[0];
    }
  } else {
    const float* X; const float* scale; unsigned short* out; int D, row;
    if (f < 16896){ X=x; scale=scale_x; out=xm; D=3072; row=f-13824; }
    else          { X=y; scale=scale_y; out=ym; D=1536; row=f-16896; }
    const float4* xv = (const float4*)(X + (size_t)row*D);
    float ss = 0.f;
    for (int i = tid; i < D/4; i += 256){
      float4 v = xv[i];
      ss += v.x*v.x + v.y*v.y + v.z*v.z + v.w*v.w;
    }
    #pragma unroll
    for (int d=1; d<64; d<<=1) ss += __shfl_xor(ss, d);
    __shared__ float wsum[4];
    if ((tid & 63) == 0) wsum[tid >> 6] = ss;
    __syncthreads();
    float tot = wsum[0] + wsum[1] + wsum[2] + wsum[3];
    float rn = rsqrtf(tot*(1.0f/(float)D) + 1e-6f);
    const float4* sv = (const float4*)scale;
    for (int i = tid; i < D/4; i += 256){
      float4 v = xv[i]; float4 s4 = sv[i];
      ushort4v o;
      o.x = bf16_rne(v.x*rn*(1.f+s4.x));
      o.y = bf16_rne(v.y*rn*(1.f+s4.y));
      o.z = bf16_rne(v.z*rn*(1.f+s4.z));
      o.w = bf16_rne(v.w*rn*(1.f+s4.w));
      *(ushort4v*)(out + (size_t)row*D + i*4) = o;
    }
  }
}

// ---------------------------------------------------------------------------
// 256^2-tile 8-phase GEMM, dual-problem. R13: manual lgkmcnt/sched_barrier
// pins removed — compiler schedules ds_read->MFMA deps itself.
// ---------------------------------------------------------------------------
__global__ __launch_bounds__(512, 2) void gemm_8ph(
    const unsigned short* __restrict__ A, const unsigned short* __restrict__ BT,
    const float* __restrict__ bias, unsigned short* __restrict__ C,
    int K, int ldc,
    const unsigned short* __restrict__ A2, const unsigned short* __restrict__ BT2,
    const float* __restrict__ bias2, unsigned short* __restrict__ C2, int K2)
{
  __shared__ unsigned short lds[8][8192];

  int tid = threadIdx.x, wave = tid>>6, lane = tid&63;
  int l16 = lane&15, g = lane>>4;
  int wr = wave>>2, wc = wave&3;

  int nwg = gridDim.x*gridDim.y;
  int orig = blockIdx.y*gridDim.x + blockIdx.x;
  int neo = xcd_swizzle(orig, nwg);
  int bx = neo / gridDim.y, by = neo % gridDim.y;

  bool ybl = (by == (int)gridDim.y - 1);
  const unsigned short* Ap  = ybl ? A2 : A;
  const unsigned short* Bp  = ybl ? BT2 : BT;
  const float* bp           = ybl ? bias2 : bias;
  unsigned short* Cp        = ybl ? C2 : C;
  int Kl = ybl ? K2 : K;
  int bm = ybl ? 0 : by*256;
  int bn = bx*256;

  const int NT = Kl >> 6;

  auto STAGE = [&](int t, int op, int half, int b){
    int tc = t < NT ? t : NT-1;
    const unsigned short* src = op ? Bp : Ap;
    int base_row = (op ? bn : bm) + half*128;
    int k0 = tc << 6;
    #pragma unroll
    for (int j=0;j<2;j++){
      int o = (j*8 + wave)*1024 + lane*16;
      int row = o>>7, slot = (o>>4)&7;
      int sk = (slot ^ (row&7))*8;
      gload16(src + (size_t)(base_row+row)*Kl + k0 + sk,
              (char*)&lds[(b<<2)|(op<<1)|half][0] + (j*8+wave)*1024);
    }
  };

  short8 afr[4], bfr[8];
  auto LDA = [&](int b, int p){
    const char* basep = (const char*)&lds[(b<<2)|wr][0];
    #pragma unroll
    for (int mm=0;mm<2;mm++){
      int row = (p*2+mm)*16 + l16;
      #pragma unroll
      for (int kk=0;kk<2;kk++)
        afr[mm*2+kk] = *(const short8*)(basep + row*128 + (((kk*4+g) ^ (row&7))<<4));
    }
  };
  auto LDB = [&](int b){
    const char* basep = (const char*)&lds[(b<<2)|2|(wc>>1)][0];
    int rbase = (wc&1)*64;
    #pragma unroll
    for (int n=0;n<4;n++){
      int row = rbase + n*16 + l16;
      #pragma unroll
      for (int kk=0;kk<2;kk++)
        bfr[n*2+kk] = *(const short8*)(basep + row*128 + (((kk*4+g) ^ (row&7))<<4));
    }
  };

  f32x4 acc[8][4] = {};

  STAGE(0,1,0,0); STAGE(0,1,1,0); STAGE(0,0,0,0); STAGE(0,0,1,0);
  STAGE(1,1,0,1); STAGE(1,1,1,1); STAGE(1,0,0,1);
  asm volatile("s_waitcnt vmcnt(6)" ::: "memory");
  __builtin_amdgcn_s_barrier();

  int NIT = NT >> 1;
  for (int i=0;i<NIT;i++){
    int T = 2*i;
    #pragma unroll
    for (int p=0;p<4;p++){
      if (p==0) LDB(0);
      LDA(0, p);
      if (p==0)      STAGE(T+1,0,1,1);
      else if (p==1) STAGE(T+2,1,0,0);
      else if (p==2) STAGE(T+2,1,1,0);
      else           STAGE(T+2,0,0,0);
      __builtin_amdgcn_s_barrier();
      __builtin_amdgcn_s_setprio(1);
      #pragma unroll
      for (int mm=0;mm<2;mm++)
        #pragma unroll
        for (int n=0;n<4;n++)
          #pragma unroll
          for (int kk=0;kk<2;kk++)
            acc[p*2+mm][n] = MFMA_BF16(afr[mm*2+kk], bfr[n*2+kk], acc[p*2+mm][n]);
      __builtin_amdgcn_s_setprio(0);
      if (p==3) asm volatile("s_waitcnt vmcnt(6)" ::: "memory");
      __builtin_amdgcn_s_barrier();
    }
    #pragma unroll
    for (int p=0;p<4;p++){
      if (p==0) LDB(1);
      LDA(1, p);
      if (p==0)      STAGE(T+2,0,1,0);
      else if (p==1) STAGE(T+3,1,0,1);
      else if (p==2) STAGE(T+3,1,1,1);
      else           STAGE(T+3,0,0,1);
      __builtin_amdgcn_s_barrier();
      __builtin_amdgcn_s_setprio(1);
      #pragma unroll
      for (int mm=0;mm<2;mm++)
        #pragma unroll
        for (int n=0;n<4;n++)
          #pragma unroll
          for (int kk=0;kk<2;kk++)
            acc[p*2+mm][n] = MFMA_BF16(afr[mm*2+kk], bfr[n*2+kk], acc[p*2+mm][n]);
      __builtin_amdgcn_s_setprio(0);
      if (p==3) asm volatile("s_waitcnt vmcnt(6)" ::: "memory");
      __builtin_amdgcn_s_barrier();
    }
  }

  #pragma unroll
  for (int n=0;n<4;n++){
    int col = bn + wc*64 + n*16 + l16;
    float bv = bp[col];
    #pragma unroll
    for (int m=0;m<8;m++){
      int row0 = bm + wr*128 + m*16 + g*4;
      #pragma unroll
      for (int r=0;r<4;r++)
        Cp[(size_t)(row0+r)*ldc + col] = bf16_rne(acc[m][n][r] + bv);
    }
  }
}

// ---------------------------------------------------------------------------
// 128^2-tile dual proj GEMM (unchanged).
// ---------------------------------------------------------------------------
__global__ __launch_bounds__(256, 3) void gemm_proj(
    const unsigned short* __restrict__ A, const unsigned short* __restrict__ BT,
    const float* __restrict__ bias, float* __restrict__ C, int ldc,
    const unsigned short* __restrict__ A2, const unsigned short* __restrict__ BT2,
    const float* __restrict__ bias2, float* __restrict__ C2, int ldc2)
{
  __shared__ unsigned short lA[128*32];
  __shared__ unsigned short lB[128*32];
  int tid = threadIdx.x, wave = tid>>6, lane = tid&63;
  int l16 = lane&15, g = lane>>4;
  int wr = wave>>1, wc = wave&1;

  const int K = 3072;
  int nwg = gridDim.x*gridDim.y;
  int orig = blockIdx.y*gridDim.x + blockIdx.x;
  int neo = xcd_swizzle(orig, nwg);
  int bx = neo / gridDim.y, by = neo % gridDim.y;

  bool ybl = (by == (int)gridDim.y - 1);
  const unsigned short* Ap = ybl ? A2 : A;
  const unsigned short* Bp = ybl ? BT2 : BT;
  const float* bp          = ybl ? bias2 : bias;
  float* Cp                = ybl ? C2 : C;
  int ldcl                 = ybl ? ldc2 : ldc;
  int bm, bn;
  if (ybl){ bm = (bx & 1)*128; bn = (bx >> 1)*128; }
  else    { bm = by*128;       bn = bx*128; }

  f32x4 acc[4][4] = {};

  for (int k0 = 0; k0 < K; k0 += 32){
    #pragma unroll
    for (int i=0;i<2;i++){
      int off = i*4096 + wave*1024 + lane*16;
      int row = off>>6;
      int sp  = (off>>4)&3;
      int sk  = (sp ^ (row&3))*8;
      gload16(Ap + (size_t)(bm+row)*K + k0 + sk, (char*)lA + i*4096 + wave*1024);
    }
    #pragma unroll
    for (int i=0;i<2;i++){
      int off = i*4096 + wave*1024 + lane*16;
      int row = off>>6;
      int sp  = (off>>4)&3;
      int sk  = (sp ^ (row&3))*8;
      gload16(Bp + (size_t)(bn+row)*K + k0 + sk, (char*)lB + i*4096 + wave*1024);
    }
    __syncthreads();

    short8 a[4], b[4];
    #pragma unroll
    for (int m=0;m<4;m++){
      int row = wr*64 + m*16 + l16;
      int slot = g ^ (row&3);
      a[m] = *(const short8*)((const char*)lA + row*64 + slot*16);
    }
    #pragma unroll
    for (int n=0;n<4;n++){
      int row = wc*64 + n*16 + l16;
      int slot = g ^ (row&3);
      b[n] = *(const short8*)((const char*)lB + row*64 + slot*16);
    }
    __builtin_amdgcn_s_setprio(1);
    #pragma unroll
    for (int m=0;m<4;m++)
      #pragma unroll
      for (int n=0;n<4;n++)
        acc[m][n] = MFMA_BF16(a[m], b[n], acc[m][n]);
    __builtin_amdgcn_s_setprio(0);
    __syncthreads();
  }

  #pragma unroll
  for (int n=0;n<4;n++){
    int col = bn + wc*64 + n*16 + l16;
    float bv = bp[col];
    #pragma unroll
    for (int m=0;m<4;m++){
      int row0 = bm + wr*64 + m*16 + g*4;
      #pragma unroll
      for (int r=0;r<4;r++)
        Cp[(size_t)(row0+r)*ldcl + col] = acc[m][n][r] + bv;
    }
  }
}

// ---------------------------------------------------------------------------
// Fused qk fixup + V transpose (unchanged).
// ---------------------------------------------------------------------------
__global__ __launch_bounds__(256) void fixup_qkv(
    const unsigned short* __restrict__ QKV,
    const float* __restrict__ cosT, const float* __restrict__ sinT,
    const float* __restrict__ wqx, const float* __restrict__ wkx,
    const float* __restrict__ wqy, const float* __restrict__ wky,
    unsigned short* __restrict__ Qo, unsigned short* __restrict__ Ko,
    unsigned short* __restrict__ VT)
{
  __shared__ unsigned short tt[64][136];
  if (blockIdx.x < 19632){
    int wave = threadIdx.x >> 6, lane = threadIdx.x & 63;
    int bid = blockIdx.x*4 + wave;
    int t = bid / NH, h = bid % NH;
    bool isx = (t < 3072);

    const unsigned short* base = QKV + (size_t)t*9216 + h*128;
    unsigned int qraw = *(const unsigned int*)(base + 2*lane);
    unsigned int kraw = *(const unsigned int*)(base + 3072 + 2*lane);
    float q0 = bf2f((unsigned short)(qraw & 0xffff)), q1 = bf2f((unsigned short)(qraw >> 16));
    float k0 = bf2f((unsigned short)(kraw & 0xffff)), k1 = bf2f((unsigned short)(kraw >> 16));

    float sq = q0*q0 + q1*q1, sk = k0*k0 + k1*k1;
    #pragma unroll
    for (int d=1; d<64; d<<=1){ sq += __shfl_xor(sq, d); sk += __shfl_xor(sk, d); }
    float rq = rsqrtf(sq*(1.0f/128.0f) + 1e-5f);
    float rk = rsqrtf(sk*(1.0f/128.0f) + 1e-5f);

    const float* wq = isx ? wqx : wqy;
    const float* wk = isx ? wkx : wky;
    float a0 = q0*rq*wq[2*lane], a1 = q1*rq*wq[2*lane+1];
    float b0 = k0*rk*wk[2*lane], b1 = k1*rk*wk[2*lane+1];

    if (isx){
      size_t ci = ((size_t)t*NH + h)*64 + lane;
      float c = cosT[ci], s = sinT[ci];
      float t0 = a0*c - a1*s, t1 = a0*s + a1*c; a0 = t0; a1 = t1;
      t0 = b0*c - b1*s; t1 = b0*s + b1*c; b0 = t0; b1 = t1;
    }
    size_t oi = ((size_t)h*SPAD + t)*128 + 2*lane;
    *(unsigned int*)(Qo + oi) = (unsigned int)bf16_rne(a0) | ((unsigned int)bf16_rne(a1) << 16);
    *(unsigned int*)(Ko + oi) = (unsigned int)bf16_rne(b0) | ((unsigned int)bf16_rne(b1) << 16);
  } else {
    int lid = blockIdx.x - 19632;
    int h = lid % NH;
    int t0 = (lid / NH)*64;
    int tid = threadIdx.x;
    #pragma unroll
    for (int it=0; it<4; it++){
      int chunk = it*256 + tid;
      int r = chunk >> 4, c = chunk & 15;
      short8 v = *(const short8*)(QKV + (size_t)(t0 + r)*9216 + 6144 + h*128 + c*8);
      *(short8*)&tt[r][c*8] = v;
    }
    __syncthreads();
    int d = tid >> 1, half = tid & 1;
    size_t ob = (size_t)(h*128 + d)*SPAD + t0 + half*32;
    #pragma unroll
    for (int j=0;j<32;j+=2){
      unsigned int v = (unsigned int)tt[half*32 + j][d] | ((unsigned int)tt[half*32 + j + 1][d] << 16);
      *(unsigned int*)(VT + ob + j) = v;
    }
  }
}

// ---------------------------------------------------------------------------
// Flash attention (unchanged from R12).
// ---------------------------------------------------------------------------
__global__ __launch_bounds__(256, 3) void attn_fwd(
    const unsigned short* __restrict__ Q, const unsigned short* __restrict__ Kb,
    const unsigned short* __restrict__ VT, unsigned short* __restrict__ O)
{
  __shared__ unsigned short lK[2][32*128];   // 2 x 8KB
  __shared__ unsigned short lV[2][128*32];   // 2 x 8KB
  __shared__ unsigned short lP[4][32*72];    // 18KB

  int tid = threadIdx.x, wave = tid>>6, lane = tid&63;
  int l16 = lane&15, g = lane>>4;
  int swz = xcd_swizzle(blockIdx.x, NH*(SPAD/128));  // 624, bijective
  int h = swz / (SPAD/128), qt = swz % (SPAD/128);
  int q0 = qt*128 + wave*32;

  auto STAGE = [&](int kt, int b){
    #pragma unroll
    for (int i=0;i<2;i++){
      int off = (i*4 + wave)*1024 + lane*16;
      int row = off>>8;
      int sp  = (off>>4)&15;
      int ssp = sp ^ (row&7);
      gload16(Kb + ((size_t)h*SPAD + kt*32 + row)*128 + ssp*8,
              (char*)&lK[b][0] + (i*4 + wave)*1024);
    }
    #pragma unroll
    for (int i=0;i<2;i++){
      int off = (i*4 + wave)*1024 + lane*16;
      int row = off>>6;
      int sp  = (off>>4)&3;
      int ssp = sp ^ ((row>>1)&3);            // 2-way-free swizzle
      gload16(VT + ((size_t)(h*128 + row))*SPAD + kt*32 + ssp*8,
              (char*)&lV[b][0] + (i*4 + wave)*1024);
    }
  };

  short8 qf[2][4];
  const unsigned short* qbase = Q + (size_t)h*SPAD*128;
  #pragma unroll
  for (int mt=0;mt<2;mt++){
    int row = q0 + mt*16 + l16;
    #pragma unroll
    for (int ks=0;ks<4;ks++)
      qf[mt][ks] = *(const short8*)(qbase + (size_t)row*128 + ks*32 + g*8);
  }

  f32x4 oacc[2][8] = {};
  float lsum[2][4] = {};

  unsigned short* lPw = &lP[wave][0];
  const float sc2 = 0.08838834764831845f * 1.4426950408889634f; // sc*log2(e)
  const float C2  = -12.0f * 1.4426950408889634f;

  STAGE(0, 0);

  for (int kt=0; kt<104; kt++){
    int cur = kt & 1;
    int nxt = (kt+1 < 104) ? kt+1 : 103;
    STAGE(nxt, cur ^ 1);
    asm volatile("s_waitcnt vmcnt(4)" ::: "memory");
    __builtin_amdgcn_s_barrier();

    const char* lKc = (const char*)&lK[cur][0];
    const char* lVc = (const char*)&lV[cur][0];

    // ---- QK^T (32 keys) ----
    f32x4 s[2][2] = {};
    #pragma unroll
    for (int ks=0;ks<4;ks++){
      short8 bfrag[2];
      #pragma unroll
      for (int nt=0;nt<2;nt++){
        int row = nt*16 + l16;
        int slot = (ks*4 + g) ^ (row&7);
        bfrag[nt] = *(const short8*)(lKc + row*256 + slot*16);
      }
      __builtin_amdgcn_s_setprio(1);
      #pragma unroll
      for (int mt=0;mt<2;mt++)
        #pragma unroll
        for (int nt=0;nt<2;nt++)
          s[mt][nt] = MFMA_BF16(qf[mt][ks], bfrag[nt], s[mt][nt]);
      __builtin_amdgcn_s_setprio(0);
    }

    // ---- fixed-max softmax: p = exp2(s*sc2 + C2); cvt_pk paired store ----
    bool edge = (kt >= 102);
    #pragma unroll
    for (int mt=0;mt<2;mt++)
      #pragma unroll
      for (int nt=0;nt<2;nt++){
        float p[4];
        #pragma unroll
        for (int r=0;r<4;r++)
          p[r] = __builtin_amdgcn_exp2f(fmaf(s[mt][nt][r], sc2, C2));
        if (edge){
          int key = kt*32 + nt*16 + l16;
          if (key >= SVAL){ p[0]=0.f; p[1]=0.f; p[2]=0.f; p[3]=0.f; }
        }
        #pragma unroll
        for (int r=0;r<4;r++) lsum[mt][r] += p[r];
        unsigned int pk01 = cvt_pk_bf16(p[0], p[1]);
        unsigned int pk23 = cvt_pk_bf16(p[2], p[3]);
        unsigned short* pb = lPw + (mt*16 + g*4)*72 + nt*16 + l16;
        pb[0]     = (unsigned short)pk01;
        pb[72]    = (unsigned short)(pk01 >> 16);
        pb[144]   = (unsigned short)pk23;
        pb[216]   = (unsigned short)(pk23 >> 16);
      }

    asm volatile("s_waitcnt lgkmcnt(0)" ::: "memory");

    // ---- PV (single 32-key slab) ----
    {
      short8 pa[2];
      #pragma unroll
      for (int mt=0;mt<2;mt++)
        pa[mt] = *(const short8*)(lPw + (mt*16 + l16)*72 + g*8);
      __builtin_amdgcn_s_setprio(1);
      #pragma unroll
      for (int dt=0;dt<8;dt++){
        int row = dt*16 + l16;
        int slot = g ^ ((row>>1)&3);
        short8 vb = *(const short8*)(lVc + row*64 + slot*16);
        #pragma unroll
        for (int mt=0;mt<2;mt++)
          oacc[mt][dt] = MFMA_BF16(pa[mt], vb, oacc[mt][dt]);
      }
      __builtin_amdgcn_s_setprio(0);
    }
    __builtin_amdgcn_s_barrier();
  }

  #pragma unroll
  for (int mt=0;mt<2;mt++){
    float inv[4];
    #pragma unroll
    for (int r=0;r<4;r++){
      float v = lsum[mt][r];
      v += __shfl_xor(v, 1); v += __shfl_xor(v, 2);
      v += __shfl_xor(v, 4); v += __shfl_xor(v, 8);
      inv[r] = 1.0f / v;
    }
    #pragma unroll
    for (int dt=0;dt<8;dt++)
      #pragma unroll
      for (int r=0;r<4;r++){
        int row = q0 + mt*16 + g*4 + r;
        unsigned short val = (row < SVAL) ? bf16_rne(oacc[mt][dt][r]*inv[r])
                                          : (unsigned short)0;
        O[(size_t)row*3072 + h*128 + dt*16 + l16] = val;
      }
  }
}

// ---------------------------------------------------------------------------
// Workspace layout (bytes).
// ---------------------------------------------------------------------------
static const size_t OFF_WT_QKV_X  = 0;                 // 9216*3072*2
static const size_t OFF_WT_QKV_Y  = 56623104;          // 9216*1536*2
static const size_t OFF_WT_PROJ_X = 84934656;          // 3072*3072*2
static const size_t OFF_WT_PROJ_Y = 103809024;         // 1536*3072*2
static const size_t OFF_XM        = 113246208;         // 3072*3072*2
static const size_t OFF_YM        = 132120576;         // 256*1536*2
static const size_t OFF_QKV       = 132907008;         // 3328*9216*2
static const size_t OFF_Q         = 194248704;         // 24*3328*128*2
static const size_t OFF_K         = 214695936;
static const size_t OFF_VT        = 235143168;
static const size_t WS_NEEDED     = 255590400;
static const size_t OFF_AO        = 0;                 // 3328*3072*2 (alias Wt_qkv_x)

extern "C" void kernel_launch(void* const* d_in, const int* in_sizes, int n_in,
                              void* d_out, int out_size, void* d_ws, size_t ws_size,
                              hipStream_t stream) {
  if (ws_size < WS_NEEDED) return;

  const float* x        = (const float*)d_in[0];
  const float* y        = (const float*)d_in[1];
  const float* scale_x  = (const float*)d_in[2];
  const float* scale_y  = (const float*)d_in[3];
  const float* rope_cos = (const float*)d_in[4];
  const float* rope_sin = (const float*)d_in[5];
  const float* W_qkv_x  = (const float*)d_in[6];
  const float* b_qkv_x  = (const float*)d_in[7];
  const float* W_qkv_y  = (const float*)d_in[8];
  const float* b_qkv_y  = (const float*)d_in[9];
  const float* w_qn_x   = (const float*)d_in[10];
  const float* w_kn_x   = (const float*)d_in[11];
  const float* w_qn_y   = (const float*)d_in[12];
  const float* w_kn_y   = (const float*)d_in[13];
  const float* W_proj_x = (const float*)d_in[14];
  const float* b_proj_x = (const float*)d_in[15];
  const float* W_proj_y = (const float*)d_in[16];
  const float* b_proj_y = (const float*)d_in[17];

  float* out_x = (float*)d_out;
  float* out_y = out_x + (size_t)3072*3072;

  char* ws = (char*)d_ws;
  unsigned short* Wt_qkv_x  = (unsigned short*)(ws + OFF_WT_QKV_X);
  unsigned short* Wt_qkv_y  = (unsigned short*)(ws + OFF_WT_QKV_Y);
  unsigned short* Wt_proj_x = (unsigned short*)(ws + OFF_WT_PROJ_X);
  unsigned short* Wt_proj_y = (unsigned short*)(ws + OFF_WT_PROJ_Y);
  unsigned short* xm        = (unsigned short*)(ws + OFF_XM);
  unsigned short* ym        = (unsigned short*)(ws + OFF_YM);
  unsigned short* qkv       = (unsigned short*)(ws + OFF_QKV);
  unsigned short* Qb        = (unsigned short*)(ws + OFF_Q);
  unsigned short* Kb        = (unsigned short*)(ws + OFF_K);
  unsigned short* VTb       = (unsigned short*)(ws + OFF_VT);
  unsigned short* attnout   = (unsigned short*)(ws + OFF_AO);

  prep_all<<<17152, 256, 0, stream>>>(
      W_qkv_x, Wt_qkv_x, W_qkv_y, Wt_qkv_y, W_proj_x, Wt_proj_x, W_proj_y, Wt_proj_y,
      x, scale_x, xm, y, scale_y, ym);

  gemm_8ph<<<dim3(36, 13), 512, 0, stream>>>(
      xm, Wt_qkv_x, b_qkv_x, qkv, 3072, 9216,
      ym, Wt_qkv_y, b_qkv_y, qkv + (size_t)3072*9216, 1536);

  fixup_qkv<<<19632 + NH*(SPAD/64), 256, 0, stream>>>(
      qkv, rope_cos, rope_sin, w_qn_x, w_kn_x, w_qn_y, w_kn_y, Qb, Kb, VTb);

  attn_fwd<<<NH*(SPAD/128), 256, 0, stream>>>(Qb, Kb, VTb, attnout);

  gemm_proj<<<dim3(24, 25), 256, 0, stream>>>(
      attnout, Wt_proj_x, b_proj_x, out_x, 3072,
      attnout + (size_t)3072*3072, Wt_proj_y, b_proj_y, out_y, 1536);
}

// Round 14
// 524.727 us; speedup vs baseline: 1.2018x; 1.0018x over previous
//
#include <hip/hip_runtime.h>

// ---------------------------------------------------------------------------
// AsymmetricAttention fused pipeline for MI355X (gfx950), bf16 MFMA throughout.
// R14: gemm_8ph block remap — 36 half-length y-blocks dispatched FIRST so the
//      work-conserving scheduler packs them into round-1 and x-blocks fill
//      behind (wall 2t -> ~1.76t). Mapping-only change; rest = R13.
// ---------------------------------------------------------------------------

typedef short short8 __attribute__((ext_vector_type(8)));
typedef float f32x4 __attribute__((ext_vector_type(4)));
typedef unsigned short ushort4v __attribute__((ext_vector_type(4)));

#define MFMA_BF16(a,b,c) __builtin_amdgcn_mfma_f32_16x16x32_bf16((a),(b),(c),0,0,0)

#define NH 24
#define SPAD 3328   // padded token count (104*32)
#define SVAL 3272   // valid tokens (3072 x + 200 y)

__device__ __forceinline__ unsigned short bf16_rne(float f){
  unsigned int u = __builtin_bit_cast(unsigned int, f);
  u += 0x7FFFu + ((u >> 16) & 1u);
  return (unsigned short)(u >> 16);
}
__device__ __forceinline__ float bf2f(unsigned short h){
  unsigned int u = ((unsigned int)h) << 16;
  return __builtin_bit_cast(float, u);
}
__device__ __forceinline__ unsigned int cvt_pk_bf16(float lo, float hi){
  unsigned int r;
  asm("v_cvt_pk_bf16_f32 %0, %1, %2" : "=v"(r) : "v"(lo), "v"(hi));
  return r;
}
__device__ __forceinline__ void gload16(const void* g, void* l){
  __builtin_amdgcn_global_load_lds(
      (const __attribute__((address_space(1))) unsigned int*)g,
      (__attribute__((address_space(3))) unsigned int*)l, 16, 0, 0);
}
// m204 bijective XCD swizzle (works for any nwg)
__device__ __forceinline__ int xcd_swizzle(int orig, int nwg){
  int q = nwg >> 3, r = nwg & 7;
  int xcd = orig & 7, loc = orig >> 3;
  return (xcd < r ? xcd*(q+1) : r*(q+1) + (xcd-r)*q) + loc;
}

// ---------------------------------------------------------------------------
// Fused preprocessing: W transposes (blocks [0,13824)) + mod-rmsnorm of x
// (blocks [13824,16896)) + mod-rmsnorm of y (blocks [16896,17152)).
// ---------------------------------------------------------------------------
__global__ __launch_bounds__(256) void prep_all(
    const float* __restrict__ W0, unsigned short* __restrict__ T0,   // 3072x9216
    const float* __restrict__ W1, unsigned short* __restrict__ T1,   // 1536x9216
    const float* __restrict__ W2, unsigned short* __restrict__ T2,   // 3072x3072
    const float* __restrict__ W3, unsigned short* __restrict__ T3,   // 3072x1536
    const float* __restrict__ x,  const float* __restrict__ scale_x,
    unsigned short* __restrict__ xm,
    const float* __restrict__ y,  const float* __restrict__ scale_y,
    unsigned short* __restrict__ ym)
{
  __shared__ unsigned short t[64][66];
  int f = blockIdx.x;
  int tid = threadIdx.x;

  if (f < 13824){
    const float* W; unsigned short* Wt; int K, N, lid;
    if      (f < 6912)           { W=W0; Wt=T0; K=3072; N=9216; lid=f; }
    else if (f < 10368)          { W=W1; Wt=T1; K=1536; N=9216; lid=f-6912; }
    else if (f < 12672)          { W=W2; Wt=T2; K=3072; N=3072; lid=f-10368; }
    else                         { W=W3; Wt=T3; K=3072; N=1536; lid=f-12672; }
    int ntiles = N >> 6;
    int n0 = (lid % ntiles)*64, k0 = (lid / ntiles)*64;

    int kr = tid >> 4, nc = (tid & 15) * 4;
    #pragma unroll
    for (int pass=0; pass<4; pass++){
      int k = kr + pass*16;
      float4 v = *(const float4*)(W + (size_t)(k0+k)*N + n0 + nc);
      ushort4v o;
      o.x = bf16_rne(v.x); o.y = bf16_rne(v.y);
      o.z = bf16_rne(v.z); o.w = bf16_rne(v.w);
      *(ushort4v*)&t[k][nc] = o;
    }
    __syncthreads();
    int nr = tid >> 3, kc = (tid & 7) * 8;
    #pragma unroll
    for (int pass=0; pass<2; pass++){
      int n = nr + pass*32;
      unsigned short buf[8];
      #pragma unroll
      for (int j=0;j<8;j++) buf[j] = t[kc+j][n];
      *(short8*)(Wt + (size_t)(n0+n)*K + k0 + kc) = *(short8*)&buf[0];
    }
  } else {
    const float* X; const float* scale; unsigned short* out; int D, row;
    if (f < 16896){ X=x; scale=scale_x; out=xm; D=3072; row=f-13824; }
    else          { X=y; scale=scale_y; out=ym; D=1536; row=f-16896; }
    const float4* xv = (const float4*)(X + (size_t)row*D);
    float ss = 0.f;
    for (int i = tid; i < D/4; i += 256){
      float4 v = xv[i];
      ss += v.x*v.x + v.y*v.y + v.z*v.z + v.w*v.w;
    }
    #pragma unroll
    for (int d=1; d<64; d<<=1) ss += __shfl_xor(ss, d);
    __shared__ float wsum[4];
    if ((tid & 63) == 0) wsum[tid >> 6] = ss;
    __syncthreads();
    float tot = wsum[0] + wsum[1] + wsum[2] + wsum[3];
    float rn = rsqrtf(tot*(1.0f/(float)D) + 1e-6f);
    const float4* sv = (const float4*)scale;
    for (int i = tid; i < D/4; i += 256){
      float4 v = xv[i]; float4 s4 = sv[i];
      ushort4v o;
      o.x = bf16_rne(v.x*rn*(1.f+s4.x));
      o.y = bf16_rne(v.y*rn*(1.f+s4.y));
      o.z = bf16_rne(v.z*rn*(1.f+s4.z));
      o.w = bf16_rne(v.w*rn*(1.f+s4.w));
      *(ushort4v*)(out + (size_t)row*D + i*4) = o;
    }
  }
}

// ---------------------------------------------------------------------------
// 256^2-tile 8-phase GEMM, dual-problem. R14: y-blocks (half K) mapped to
// the FIRST 36 dispatch ids so the scheduler packs them; x-blocks follow
// with bijective XCD swizzle over 432.
// ---------------------------------------------------------------------------
__global__ __launch_bounds__(512, 2) void gemm_8ph(
    const unsigned short* __restrict__ A, const unsigned short* __restrict__ BT,
    const float* __restrict__ bias, unsigned short* __restrict__ C,
    int K, int ldc,
    const unsigned short* __restrict__ A2, const unsigned short* __restrict__ BT2,
    const float* __restrict__ bias2, unsigned short* __restrict__ C2, int K2)
{
  __shared__ unsigned short lds[8][8192];

  int tid = threadIdx.x, wave = tid>>6, lane = tid&63;
  int l16 = lane&15, g = lane>>4;
  int wr = wave>>2, wc = wave&3;

  int orig = blockIdx.y*gridDim.x + blockIdx.x;
  int NYB = (int)gridDim.x;                 // 36 y-blocks (one grid row)
  bool ybl = (orig < NYB);

  const unsigned short* Ap  = ybl ? A2 : A;
  const unsigned short* Bp  = ybl ? BT2 : BT;
  const float* bp           = ybl ? bias2 : bias;
  unsigned short* Cp        = ybl ? C2 : C;
  int Kl = ybl ? K2 : K;
  int bm, bn;
  if (ybl){
    bm = 0; bn = orig*256;
  } else {
    int xid = orig - NYB;                   // 0..431, 432 % 8 == 0 -> bijective
    int neo = xcd_swizzle(xid, (int)(gridDim.x*gridDim.y) - NYB);
    int bx = neo / ((int)gridDim.y - 1), by = neo % ((int)gridDim.y - 1);
    bm = by*256; bn = bx*256;
  }

  const int NT = Kl >> 6;

  auto STAGE = [&](int t, int op, int half, int b){
    int tc = t < NT ? t : NT-1;
    const unsigned short* src = op ? Bp : Ap;
    int base_row = (op ? bn : bm) + half*128;
    int k0 = tc << 6;
    #pragma unroll
    for (int j=0;j<2;j++){
      int o = (j*8 + wave)*1024 + lane*16;
      int row = o>>7, slot = (o>>4)&7;
      int sk = (slot ^ (row&7))*8;
      gload16(src + (size_t)(base_row+row)*Kl + k0 + sk,
              (char*)&lds[(b<<2)|(op<<1)|half][0] + (j*8+wave)*1024);
    }
  };

  short8 afr[4], bfr[8];
  auto LDA = [&](int b, int p){
    const char* basep = (const char*)&lds[(b<<2)|wr][0];
    #pragma unroll
    for (int mm=0;mm<2;mm++){
      int row = (p*2+mm)*16 + l16;
      #pragma unroll
      for (int kk=0;kk<2;kk++)
        afr[mm*2+kk] = *(const short8*)(basep + row*128 + (((kk*4+g) ^ (row&7))<<4));
    }
  };
  auto LDB = [&](int b){
    const char* basep = (const char*)&lds[(b<<2)|2|(wc>>1)][0];
    int rbase = (wc&1)*64;
    #pragma unroll
    for (int n=0;n<4;n++){
      int row = rbase + n*16 + l16;
      #pragma unroll
      for (int kk=0;kk<2;kk++)
        bfr[n*2+kk] = *(const short8*)(basep + row*128 + (((kk*4+g) ^ (row&7))<<4));
    }
  };

  f32x4 acc[8][4] = {};

  STAGE(0,1,0,0); STAGE(0,1,1,0); STAGE(0,0,0,0); STAGE(0,0,1,0);
  STAGE(1,1,0,1); STAGE(1,1,1,1); STAGE(1,0,0,1);
  asm volatile("s_waitcnt vmcnt(6)" ::: "memory");
  __builtin_amdgcn_s_barrier();

  int NIT = NT >> 1;
  for (int i=0;i<NIT;i++){
    int T = 2*i;
    #pragma unroll
    for (int p=0;p<4;p++){
      if (p==0) LDB(0);
      LDA(0, p);
      if (p==0)      STAGE(T+1,0,1,1);
      else if (p==1) STAGE(T+2,1,0,0);
      else if (p==2) STAGE(T+2,1,1,0);
      else           STAGE(T+2,0,0,0);
      __builtin_amdgcn_s_barrier();
      __builtin_amdgcn_s_setprio(1);
      #pragma unroll
      for (int mm=0;mm<2;mm++)
        #pragma unroll
        for (int n=0;n<4;n++)
          #pragma unroll
          for (int kk=0;kk<2;kk++)
            acc[p*2+mm][n] = MFMA_BF16(afr[mm*2+kk], bfr[n*2+kk], acc[p*2+mm][n]);
      __builtin_amdgcn_s_setprio(0);
      if (p==3) asm volatile("s_waitcnt vmcnt(6)" ::: "memory");
      __builtin_amdgcn_s_barrier();
    }
    #pragma unroll
    for (int p=0;p<4;p++){
      if (p==0) LDB(1);
      LDA(1, p);
      if (p==0)      STAGE(T+2,0,1,0);
      else if (p==1) STAGE(T+3,1,0,1);
      else if (p==2) STAGE(T+3,1,1,1);
      else           STAGE(T+3,0,0,1);
      __builtin_amdgcn_s_barrier();
      __builtin_amdgcn_s_setprio(1);
      #pragma unroll
      for (int mm=0;mm<2;mm++)
        #pragma unroll
        for (int n=0;n<4;n++)
          #pragma unroll
          for (int kk=0;kk<2;kk++)
            acc[p*2+mm][n] = MFMA_BF16(afr[mm*2+kk], bfr[n*2+kk], acc[p*2+mm][n]);
      __builtin_amdgcn_s_setprio(0);
      if (p==3) asm volatile("s_waitcnt vmcnt(6)" ::: "memory");
      __builtin_amdgcn_s_barrier();
    }
  }

  #pragma unroll
  for (int n=0;n<4;n++){
    int col = bn + wc*64 + n*16 + l16;
    float bv = bp[col];
    #pragma unroll
    for (int m=0;m<8;m++){
      int row0 = bm + wr*128 + m*16 + g*4;
      #pragma unroll
      for (int r=0;r<4;r++)
        Cp[(size_t)(row0+r)*ldc + col] = bf16_rne(acc[m][n][r] + bv);
    }
  }
}

// ---------------------------------------------------------------------------
// 128^2-tile dual proj GEMM (unchanged).
// ---------------------------------------------------------------------------
__global__ __launch_bounds__(256, 3) void gemm_proj(
    const unsigned short* __restrict__ A, const unsigned short* __restrict__ BT,
    const float* __restrict__ bias, float* __restrict__ C, int ldc,
    const unsigned short* __restrict__ A2, const unsigned short* __restrict__ BT2,
    const float* __restrict__ bias2, float* __restrict__ C2, int ldc2)
{
  __shared__ unsigned short lA[128*32];
  __shared__ unsigned short lB[128*32];
  int tid = threadIdx.x, wave = tid>>6, lane = tid&63;
  int l16 = lane&15, g = lane>>4;
  int wr = wave>>1, wc = wave&1;

  const int K = 3072;
  int nwg = gridDim.x*gridDim.y;
  int orig = blockIdx.y*gridDim.x + blockIdx.x;
  int neo = xcd_swizzle(orig, nwg);
  int bx = neo / gridDim.y, by = neo % gridDim.y;

  bool ybl = (by == (int)gridDim.y - 1);
  const unsigned short* Ap = ybl ? A2 : A;
  const unsigned short* Bp = ybl ? BT2 : BT;
  const float* bp          = ybl ? bias2 : bias;
  float* Cp                = ybl ? C2 : C;
  int ldcl                 = ybl ? ldc2 : ldc;
  int bm, bn;
  if (ybl){ bm = (bx & 1)*128; bn = (bx >> 1)*128; }
  else    { bm = by*128;       bn = bx*128; }

  f32x4 acc[4][4] = {};

  for (int k0 = 0; k0 < K; k0 += 32){
    #pragma unroll
    for (int i=0;i<2;i++){
      int off = i*4096 + wave*1024 + lane*16;
      int row = off>>6;
      int sp  = (off>>4)&3;
      int sk  = (sp ^ (row&3))*8;
      gload16(Ap + (size_t)(bm+row)*K + k0 + sk, (char*)lA + i*4096 + wave*1024);
    }
    #pragma unroll
    for (int i=0;i<2;i++){
      int off = i*4096 + wave*1024 + lane*16;
      int row = off>>6;
      int sp  = (off>>4)&3;
      int sk  = (sp ^ (row&3))*8;
      gload16(Bp + (size_t)(bn+row)*K + k0 + sk, (char*)lB + i*4096 + wave*1024);
    }
    __syncthreads();

    short8 a[4], b[4];
    #pragma unroll
    for (int m=0;m<4;m++){
      int row = wr*64 + m*16 + l16;
      int slot = g ^ (row&3);
      a[m] = *(const short8*)((const char*)lA + row*64 + slot*16);
    }
    #pragma unroll
    for (int n=0;n<4;n++){
      int row = wc*64 + n*16 + l16;
      int slot = g ^ (row&3);
      b[n] = *(const short8*)((const char*)lB + row*64 + slot*16);
    }
    __builtin_amdgcn_s_setprio(1);
    #pragma unroll
    for (int m=0;m<4;m++)
      #pragma unroll
      for (int n=0;n<4;n++)
        acc[m][n] = MFMA_BF16(a[m], b[n], acc[m][n]);
    __builtin_amdgcn_s_setprio(0);
    __syncthreads();
  }

  #pragma unroll
  for (int n=0;n<4;n++){
    int col = bn + wc*64 + n*16 + l16;
    float bv = bp[col];
    #pragma unroll
    for (int m=0;m<4;m++){
      int row0 = bm + wr*64 + m*16 + g*4;
      #pragma unroll
      for (int r=0;r<4;r++)
        Cp[(size_t)(row0+r)*ldcl + col] = acc[m][n][r] + bv;
    }
  }
}

// ---------------------------------------------------------------------------
// Fused qk fixup + V transpose (unchanged).
// ---------------------------------------------------------------------------
__global__ __launch_bounds__(256) void fixup_qkv(
    const unsigned short* __restrict__ QKV,
    const float* __restrict__ cosT, const float* __restrict__ sinT,
    const float* __restrict__ wqx, const float* __restrict__ wkx,
    const float* __restrict__ wqy, const float* __restrict__ wky,
    unsigned short* __restrict__ Qo, unsigned short* __restrict__ Ko,
    unsigned short* __restrict__ VT)
{
  __shared__ unsigned short tt[64][136];
  if (blockIdx.x < 19632){
    int wave = threadIdx.x >> 6, lane = threadIdx.x & 63;
    int bid = blockIdx.x*4 + wave;
    int t = bid / NH, h = bid % NH;
    bool isx = (t < 3072);

    const unsigned short* base = QKV + (size_t)t*9216 + h*128;
    unsigned int qraw = *(const unsigned int*)(base + 2*lane);
    unsigned int kraw = *(const unsigned int*)(base + 3072 + 2*lane);
    float q0 = bf2f((unsigned short)(qraw & 0xffff)), q1 = bf2f((unsigned short)(qraw >> 16));
    float k0 = bf2f((unsigned short)(kraw & 0xffff)), k1 = bf2f((unsigned short)(kraw >> 16));

    float sq = q0*q0 + q1*q1, sk = k0*k0 + k1*k1;
    #pragma unroll
    for (int d=1; d<64; d<<=1){ sq += __shfl_xor(sq, d); sk += __shfl_xor(sk, d); }
    float rq = rsqrtf(sq*(1.0f/128.0f) + 1e-5f);
    float rk = rsqrtf(sk*(1.0f/128.0f) + 1e-5f);

    const float* wq = isx ? wqx : wqy;
    const float* wk = isx ? wkx : wky;
    float a0 = q0*rq*wq[2*lane], a1 = q1*rq*wq[2*lane+1];
    float b0 = k0*rk*wk[2*lane], b1 = k1*rk*wk[2*lane+1];

    if (isx){
      size_t ci = ((size_t)t*NH + h)*64 + lane;
      float c = cosT[ci], s = sinT[ci];
      float t0 = a0*c - a1*s, t1 = a0*s + a1*c; a0 = t0; a1 = t1;
      t0 = b0*c - b1*s; t1 = b0*s + b1*c; b0 = t0; b1 = t1;
    }
    size_t oi = ((size_t)h*SPAD + t)*128 + 2*lane;
    *(unsigned int*)(Qo + oi) = (unsigned int)bf16_rne(a0) | ((unsigned int)bf16_rne(a1) << 16);
    *(unsigned int*)(Ko + oi) = (unsigned int)bf16_rne(b0) | ((unsigned int)bf16_rne(b1) << 16);
  } else {
    int lid = blockIdx.x - 19632;
    int h = lid % NH;
    int t0 = (lid / NH)*64;
    int tid = threadIdx.x;
    #pragma unroll
    for (int it=0; it<4; it++){
      int chunk = it*256 + tid;
      int r = chunk >> 4, c = chunk & 15;
      short8 v = *(const short8*)(QKV + (size_t)(t0 + r)*9216 + 6144 + h*128 + c*8);
      *(short8*)&tt[r][c*8] = v;
    }
    __syncthreads();
    int d = tid >> 1, half = tid & 1;
    size_t ob = (size_t)(h*128 + d)*SPAD + t0 + half*32;
    #pragma unroll
    for (int j=0;j<32;j+=2){
      unsigned int v = (unsigned int)tt[half*32 + j][d] | ((unsigned int)tt[half*32 + j + 1][d] << 16);
      *(unsigned int*)(VT + ob + j) = v;
    }
  }
}

// ---------------------------------------------------------------------------
// Flash attention (unchanged from R13).
// ---------------------------------------------------------------------------
__global__ __launch_bounds__(256, 3) void attn_fwd(
    const unsigned short* __restrict__ Q, const unsigned short* __restrict__ Kb,
    const unsigned short* __restrict__ VT, unsigned short* __restrict__ O)
{
  __shared__ unsigned short lK[2][32*128];   // 2 x 8KB
  __shared__ unsigned short lV[2][128*32];   // 2 x 8KB
  __shared__ unsigned short lP[4][32*72];    // 18KB

  int tid = threadIdx.x, wave = tid>>6, lane = tid&63;
  int l16 = lane&15, g = lane>>4;
  int swz = xcd_swizzle(blockIdx.x, NH*(SPAD/128));  // 624, bijective
  int h = swz / (SPAD/128), qt = swz % (SPAD/128);
  int q0 = qt*128 + wave*32;

  auto STAGE = [&](int kt, int b){
    #pragma unroll
    for (int i=0;i<2;i++){
      int off = (i*4 + wave)*1024 + lane*16;
      int row = off>>8;
      int sp  = (off>>4)&15;
      int ssp = sp ^ (row&7);
      gload16(Kb + ((size_t)h*SPAD + kt*32 + row)*128 + ssp*8,
              (char*)&lK[b][0] + (i*4 + wave)*1024);
    }
    #pragma unroll
    for (int i=0;i<2;i++){
      int off = (i*4 + wave)*1024 + lane*16;
      int row = off>>6;
      int sp  = (off>>4)&3;
      int ssp = sp ^ ((row>>1)&3);            // 2-way-free swizzle
      gload16(VT + ((size_t)(h*128 + row))*SPAD + kt*32 + ssp*8,
              (char*)&lV[b][0] + (i*4 + wave)*1024);
    }
  };

  short8 qf[2][4];
  const unsigned short* qbase = Q + (size_t)h*SPAD*128;
  #pragma unroll
  for (int mt=0;mt<2;mt++){
    int row = q0 + mt*16 + l16;
    #pragma unroll
    for (int ks=0;ks<4;ks++)
      qf[mt][ks] = *(const short8*)(qbase + (size_t)row*128 + ks*32 + g*8);
  }

  f32x4 oacc[2][8] = {};
  float lsum[2][4] = {};

  unsigned short* lPw = &lP[wave][0];
  const float sc2 = 0.08838834764831845f * 1.4426950408889634f; // sc*log2(e)
  const float C2  = -12.0f * 1.4426950408889634f;

  STAGE(0, 0);

  for (int kt=0; kt<104; kt++){
    int cur = kt & 1;
    int nxt = (kt+1 < 104) ? kt+1 : 103;
    STAGE(nxt, cur ^ 1);
    asm volatile("s_waitcnt vmcnt(4)" ::: "memory");
    __builtin_amdgcn_s_barrier();

    const char* lKc = (const char*)&lK[cur][0];
    const char* lVc = (const char*)&lV[cur][0];

    // ---- QK^T (32 keys) ----
    f32x4 s[2][2] = {};
    #pragma unroll
    for (int ks=0;ks<4;ks++){
      short8 bfrag[2];
      #pragma unroll
      for (int nt=0;nt<2;nt++){
        int row = nt*16 + l16;
        int slot = (ks*4 + g) ^ (row&7);
        bfrag[nt] = *(const short8*)(lKc + row*256 + slot*16);
      }
      __builtin_amdgcn_s_setprio(1);
      #pragma unroll
      for (int mt=0;mt<2;mt++)
        #pragma unroll
        for (int nt=0;nt<2;nt++)
          s[mt][nt] = MFMA_BF16(qf[mt][ks], bfrag[nt], s[mt][nt]);
      __builtin_amdgcn_s_setprio(0);
    }

    // ---- fixed-max softmax: p = exp2(s*sc2 + C2); cvt_pk paired store ----
    bool edge = (kt >= 102);
    #pragma unroll
    for (int mt=0;mt<2;mt++)
      #pragma unroll
      for (int nt=0;nt<2;nt++){
        float p[4];
        #pragma unroll
        for (int r=0;r<4;r++)
          p[r] = __builtin_amdgcn_exp2f(fmaf(s[mt][nt][r], sc2, C2));
        if (edge){
          int key = kt*32 + nt*16 + l16;
          if (key >= SVAL){ p[0]=0.f; p[1]=0.f; p[2]=0.f; p[3]=0.f; }
        }
        #pragma unroll
        for (int r=0;r<4;r++) lsum[mt][r] += p[r];
        unsigned int pk01 = cvt_pk_bf16(p[0], p[1]);
        unsigned int pk23 = cvt_pk_bf16(p[2], p[3]);
        unsigned short* pb = lPw + (mt*16 + g*4)*72 + nt*16 + l16;
        pb[0]     = (unsigned short)pk01;
        pb[72]    = (unsigned short)(pk01 >> 16);
        pb[144]   = (unsigned short)pk23;
        pb[216]   = (unsigned short)(pk23 >> 16);
      }

    asm volatile("s_waitcnt lgkmcnt(0)" ::: "memory");

    // ---- PV (single 32-key slab) ----
    {
      short8 pa[2];
      #pragma unroll
      for (int mt=0;mt<2;mt++)
        pa[mt] = *(const short8*)(lPw + (mt*16 + l16)*72 + g*8);
      __builtin_amdgcn_s_setprio(1);
      #pragma unroll
      for (int dt=0;dt<8;dt++){
        int row = dt*16 + l16;
        int slot = g ^ ((row>>1)&3);
        short8 vb = *(const short8*)(lVc + row*64 + slot*16);
        #pragma unroll
        for (int mt=0;mt<2;mt++)
          oacc[mt][dt] = MFMA_BF16(pa[mt], vb, oacc[mt][dt]);
      }
      __builtin_amdgcn_s_setprio(0);
    }
    __builtin_amdgcn_s_barrier();
  }

  #pragma unroll
  for (int mt=0;mt<2;mt++){
    float inv[4];
    #pragma unroll
    for (int r=0;r<4;r++){
      float v = lsum[mt][r];
      v += __shfl_xor(v, 1); v += __shfl_xor(v, 2);
      v += __shfl_xor(v, 4); v += __shfl_xor(v, 8);
      inv[r] = 1.0f / v;
    }
    #pragma unroll
    for (int dt=0;dt<8;dt++)
      #pragma unroll
      for (int r=0;r<4;r++){
        int row = q0 + mt*16 + g*4 + r;
        unsigned short val = (row < SVAL) ? bf16_rne(oacc[mt][dt][r]*inv[r])
                                          : (unsigned short)0;
        O[(size_t)row*3072 + h*128 + dt*16 + l16] = val;
      }
  }
}

// ---------------------------------------------------------------------------
// Workspace layout (bytes).
// ---------------------------------------------------------------------------
static const size_t OFF_WT_QKV_X  = 0;                 // 9216*3072*2
static const size_t OFF_WT_QKV_Y  = 56623104;          // 9216*1536*2
static const size_t OFF_WT_PROJ_X = 84934656;          // 3072*3072*2
static const size_t OFF_WT_PROJ_Y = 103809024;         // 1536*3072*2
static const size_t OFF_XM        = 113246208;         // 3072*3072*2
static const size_t OFF_YM        = 132120576;         // 256*1536*2
static const size_t OFF_QKV       = 132907008;         // 3328*9216*2
static const size_t OFF_Q         = 194248704;         // 24*3328*128*2
static const size_t OFF_K         = 214695936;
static const size_t OFF_VT        = 235143168;
static const size_t WS_NEEDED     = 255590400;
static const size_t OFF_AO        = 0;                 // 3328*3072*2 (alias Wt_qkv_x)

extern "C" void kernel_launch(void* const* d_in, const int* in_sizes, int n_in,
                              void* d_out, int out_size, void* d_ws, size_t ws_size,
                              hipStream_t stream) {
  if (ws_size < WS_NEEDED) return;

  const float* x        = (const float*)d_in[0];
  const float* y        = (const float*)d_in[1];
  const float* scale_x  = (const float*)d_in[2];
  const float* scale_y  = (const float*)d_in[3];
  const float* rope_cos = (const float*)d_in[4];
  const float* rope_sin = (const float*)d_in[5];
  const float* W_qkv_x  = (const float*)d_in[6];
  const float* b_qkv_x  = (const float*)d_in[7];
  const float* W_qkv_y  = (const float*)d_in[8];
  const float* b_qkv_y  = (const float*)d_in[9];
  const float* w_qn_x   = (const float*)d_in[10];
  const float* w_kn_x   = (const float*)d_in[11];
  const float* w_qn_y   = (const float*)d_in[12];
  const float* w_kn_y   = (const float*)d_in[13];
  const float* W_proj_x = (const float*)d_in[14];
  const float* b_proj_x = (const float*)d_in[15];
  const float* W_proj_y = (const float*)d_in[16];
  const float* b_proj_y = (const float*)d_in[17];

  float* out_x = (float*)d_out;
  float* out_y = out_x + (size_t)3072*3072;

  char* ws = (char*)d_ws;
  unsigned short* Wt_qkv_x  = (unsigned short*)(ws + OFF_WT_QKV_X);
  unsigned short* Wt_qkv_y  = (unsigned short*)(ws + OFF_WT_QKV_Y);
  unsigned short* Wt_proj_x = (unsigned short*)(ws + OFF_WT_PROJ_X);
  unsigned short* Wt_proj_y = (unsigned short*)(ws + OFF_WT_PROJ_Y);
  unsigned short* xm        = (unsigned short*)(ws + OFF_XM);
  unsigned short* ym        = (unsigned short*)(ws + OFF_YM);
  unsigned short* qkv       = (unsigned short*)(ws + OFF_QKV);
  unsigned short* Qb        = (unsigned short*)(ws + OFF_Q);
  unsigned short* Kb        = (unsigned short*)(ws + OFF_K);
  unsigned short* VTb       = (unsigned short*)(ws + OFF_VT);
  unsigned short* attnout   = (unsigned short*)(ws + OFF_AO);

  prep_all<<<17152, 256, 0, stream>>>(
      W_qkv_x, Wt_qkv_x, W_qkv_y, Wt_qkv_y, W_proj_x, Wt_proj_x, W_proj_y, Wt_proj_y,
      x, scale_x, xm, y, scale_y, ym);

  // y-blocks (ids 0..35, K=1536) dispatch first; x-blocks (36..467) fill behind
  gemm_8ph<<<dim3(36, 13), 512, 0, stream>>>(
      xm, Wt_qkv_x, b_qkv_x, qkv, 3072, 9216,
      ym, Wt_qkv_y, b_qkv_y, qkv + (size_t)3072*9216, 1536);

  fixup_qkv<<<19632 + NH*(SPAD/64), 256, 0, stream>>>(
      qkv, rope_cos, rope_sin, w_qn_x, w_kn_x, w_qn_y, w_kn_y, Qb, Kb, VTb);

  attn_fwd<<<NH*(SPAD/128), 256, 0, stream>>>(Qb, Kb, VTb, attnout);

  gemm_proj<<<dim3(24, 25), 256, 0, stream>>>(
      attnout, Wt_proj_x, b_proj_x, out_x, 3072,
      attnout + (size_t)3072*3072, Wt_proj_y, b_proj_y, out_y, 1536);
}